// Round 7
// baseline (310.648 us; speedup 1.0000x reference)
//
#include <hip/hip_runtime.h>
#include <cstdint>
#include <cstddef>

#define B_SZ 2
#define N_SEQ 32768
#define NB 2048
#define HD 32
#define LQ 16
#define KCNT 17
#define M_ROWS 65536
#define SCALE_F 0.17677669529663687f /* 32^-0.5 */

typedef __attribute__((ext_vector_type(8))) short sv8;
typedef __attribute__((ext_vector_type(4))) short sv4;
typedef __attribute__((ext_vector_type(4))) float f4;

__device__ __forceinline__ short f2bf(float f) {
  unsigned u = __builtin_bit_cast(unsigned, f);
  u = (u + 0x7FFFu + ((u >> 16) & 1u)) >> 16;
  return (short)u;
}
__device__ __forceinline__ float bf2f(short s) {
  unsigned u = ((unsigned)(unsigned short)s) << 16;
  return __builtin_bit_cast(float, u);
}
__device__ __forceinline__ void split8(const float* __restrict__ p, sv8& hi, sv8& lo) {
  float4 f0 = *(const float4*)p, f1 = *(const float4*)(p + 4);
  float fv[8] = {f0.x, f0.y, f0.z, f0.w, f1.x, f1.y, f1.z, f1.w};
#pragma unroll
  for (int j = 0; j < 8; ++j) {
    short h = f2bf(fv[j]);
    hi[j] = h;
    lo[j] = f2bf(fv[j] - bf2f(h));
  }
}
__device__ __forceinline__ void gload16(const void* g, void* l) {
  __builtin_amdgcn_global_load_lds(
      (const __attribute__((address_space(1))) unsigned int*)g,
      (__attribute__((address_space(3))) unsigned int*)l, 16, 0, 0);
}
__device__ __forceinline__ f4 mfma16(sv8 a, sv8 b, f4 c) {
  return __builtin_amdgcn_mfma_f32_16x16x32_bf16(a, b, c, 0, 0, 0);
}

// fp32 [rows][256] -> bf16 hi|lo [rows][512]
__global__ __launch_bounds__(256) void split256(const float* __restrict__ src,
                                                short* __restrict__ dst, int n4) {
  int i = blockIdx.x * 256 + threadIdx.x;
  if (i >= n4) return;
  float4 v = ((const float4*)src)[i];
  size_t row = (size_t)(i >> 6);
  int c = (i & 63) * 4;
  float fv[4] = {v.x, v.y, v.z, v.w};
  sv4 hi, lo;
#pragma unroll
  for (int j = 0; j < 4; ++j) {
    short h = f2bf(fv[j]);
    hi[j] = h;
    lo[j] = f2bf(fv[j] - bf2f(h));
  }
  *(sv4*)&dst[row * 512 + c] = hi;
  *(sv4*)&dst[row * 512 + 256 + c] = lo;
}

// ---- pre-split GEMM, 2-phase double-buffered (T3-minimum recipe).
// Grid: x = N-tiles (fast-varying -> A-panel stays L2/L3-hot), y = M-tiles.
// K' = 24 steps of 32: hh(0-7) lh(8-15) hl(16-23).
#define GEMM_PRE_BODY                                                          \
  __shared__ __align__(16) short As[2][128][32];                               \
  __shared__ __align__(16) short Bs[2][128][32];                               \
  const int tid = threadIdx.x;                                                 \
  const int w = tid >> 6, l = tid & 63;                                        \
  const int wm = w >> 1, wn = w & 1;                                           \
  const int m0 = blockIdx.y * 128, n0 = blockIdx.x * 128;                      \
  const int lr = l >> 2;                                                       \
  const int lc = (l & 3) * 8;                                                  \
  const int fr = l & 15, kg = (l >> 4) * 8;                                    \
  auto kaof = [](int s) { return ((s >= 8 && s < 16) ? 256 : 0) + (s & 7) * 32; }; \
  auto kbof = [](int s) { return ((s >= 16) ? 256 : 0) + (s & 7) * 32; };      \
  f4 acc[4][4] = {};                                                           \
  _Pragma("unroll") for (int i = 0; i < 2; ++i) {                              \
    const int row = w * 32 + i * 16;                                           \
    gload16(A2 + (size_t)(m0 + row + lr) * 512 + kaof(0) + lc, (void*)&As[0][row][0]); \
    gload16(B2 + (size_t)(n0 + row + lr) * 512 + kbof(0) + lc, (void*)&Bs[0][row][0]); \
  }                                                                            \
  __syncthreads();                                                             \
  int cur = 0;                                                                 \
  for (int s = 0; s < 24; ++s) {                                               \
    if (s < 23) {                                                              \
      const int ka = kaof(s + 1), kb = kbof(s + 1);                            \
      _Pragma("unroll") for (int i = 0; i < 2; ++i) {                          \
        const int row = w * 32 + i * 16;                                       \
        gload16(A2 + (size_t)(m0 + row + lr) * 512 + ka + lc, (void*)&As[cur ^ 1][row][0]); \
        gload16(B2 + (size_t)(n0 + row + lr) * 512 + kb + lc, (void*)&Bs[cur ^ 1][row][0]); \
      }                                                                        \
    }                                                                          \
    sv8 a[4], bb[4];                                                           \
    _Pragma("unroll") for (int t = 0; t < 4; ++t) {                            \
      a[t] = *(const sv8*)&As[cur][wm * 64 + t * 16 + fr][kg];                 \
      bb[t] = *(const sv8*)&Bs[cur][wn * 64 + t * 16 + fr][kg];                \
    }                                                                          \
    _Pragma("unroll") for (int mt = 0; mt < 4; ++mt)                           \
      _Pragma("unroll") for (int nt = 0; nt < 4; ++nt)                         \
        acc[mt][nt] = mfma16(a[mt], bb[nt], acc[mt][nt]);                      \
    __syncthreads();                                                           \
    cur ^= 1;                                                                  \
  }

__global__ __launch_bounds__(256) void gemm_pre_qkv(
    const short* __restrict__ A2, const short* __restrict__ B2,
    const float* __restrict__ bias, float* __restrict__ Qb,
    float* __restrict__ Kb, float* __restrict__ Vb) {
  GEMM_PRE_BODY
  float* dst = (blockIdx.x < 2) ? Qb : ((blockIdx.x < 4) ? Kb : Vb);
  const int r0 = (l >> 4) * 4;
#pragma unroll
  for (int mt = 0; mt < 4; ++mt)
#pragma unroll
    for (int nt = 0; nt < 4; ++nt) {
      const int n = n0 + wn * 64 + nt * 16 + fr;
      const float bv = bias[n];
      const int nn = n & 255;
      const size_t mb = (size_t)(m0 + wm * 64 + mt * 16 + r0);
#pragma unroll
      for (int j = 0; j < 4; ++j) dst[(mb + j) * 256 + nn] = acc[mt][nt][j] + bv;
    }
}

__global__ __launch_bounds__(256) void gemm_pre_out(
    const short* __restrict__ A2, const short* __restrict__ B2,
    const float* __restrict__ bias, float* __restrict__ C) {
  GEMM_PRE_BODY
  const int r0 = (l >> 4) * 4;
#pragma unroll
  for (int mt = 0; mt < 4; ++mt)
#pragma unroll
    for (int nt = 0; nt < 4; ++nt) {
      const int n = n0 + wn * 64 + nt * 16 + fr;
      const float bv = bias[n];
      const size_t mb = (size_t)(m0 + wm * 64 + mt * 16 + r0);
#pragma unroll
      for (int j = 0; j < 4; ++j) C[(mb + j) * 256 + n] = acc[mt][nt][j] + bv;
    }
}

// ---- fallback on-the-fly-split GEMMs (proven round 4) ----
__global__ __launch_bounds__(256) void gemm_qkv(
    const float* __restrict__ X, const float* __restrict__ W,
    const float* __restrict__ bias, float* __restrict__ Qb,
    float* __restrict__ Kb, float* __restrict__ Vb) {
  const int tid = threadIdx.x, w = tid >> 6, l = tid & 63;
  const int wm = w >> 1, wn = w & 1;
  const int m0 = blockIdx.x * 128, n0 = blockIdx.y * 128;
  const int fr = l & 15, kg = (l >> 4) * 8;
  f4 acc[4][4] = {};
  for (int s = 0; s < 8; ++s) {
    const int k0 = s * 32 + kg;
    sv8 ah[4], al[4], bh[4], bl[4];
#pragma unroll
    for (int t = 0; t < 4; ++t) {
      split8(X + (size_t)(m0 + wm * 64 + t * 16 + fr) * 256 + k0, ah[t], al[t]);
      split8(W + (size_t)(n0 + wn * 64 + t * 16 + fr) * 256 + k0, bh[t], bl[t]);
    }
#pragma unroll
    for (int mt = 0; mt < 4; ++mt)
#pragma unroll
      for (int nt = 0; nt < 4; ++nt) {
        f4 a0 = acc[mt][nt];
        a0 = mfma16(ah[mt], bh[nt], a0);
        a0 = mfma16(al[mt], bh[nt], a0);
        a0 = mfma16(ah[mt], bl[nt], a0);
        acc[mt][nt] = a0;
      }
  }
  float* dst = (blockIdx.y < 2) ? Qb : ((blockIdx.y < 4) ? Kb : Vb);
  const int r0 = (l >> 4) * 4;
#pragma unroll
  for (int mt = 0; mt < 4; ++mt)
#pragma unroll
    for (int nt = 0; nt < 4; ++nt) {
      const int n = n0 + wn * 64 + nt * 16 + fr;
      const float bv = bias[n];
      const int nn = n & 255;
      const size_t mb = (size_t)(m0 + wm * 64 + mt * 16 + r0);
#pragma unroll
      for (int j = 0; j < 4; ++j) dst[(mb + j) * 256 + nn] = acc[mt][nt][j] + bv;
    }
}

__global__ __launch_bounds__(256) void gemm_out(
    const short* __restrict__ A2, const float* __restrict__ W,
    const float* __restrict__ bias, float* __restrict__ C) {
  const int tid = threadIdx.x, w = tid >> 6, l = tid & 63;
  const int wm = w >> 1, wn = w & 1;
  const int m0 = blockIdx.x * 128, n0 = blockIdx.y * 128;
  const int fr = l & 15, kg = (l >> 4) * 8;
  f4 acc[4][4] = {};
  for (int s = 0; s < 8; ++s) {
    const int k0 = s * 32 + kg;
    sv8 ah[4], al[4], bh[4], bl[4];
#pragma unroll
    for (int t = 0; t < 4; ++t) {
      const short* ap = A2 + (size_t)(m0 + wm * 64 + t * 16 + fr) * 512 + k0;
      ah[t] = *(const sv8*)ap;
      al[t] = *(const sv8*)(ap + 256);
      split8(W + (size_t)(n0 + wn * 64 + t * 16 + fr) * 256 + k0, bh[t], bl[t]);
    }
#pragma unroll
    for (int mt = 0; mt < 4; ++mt)
#pragma unroll
      for (int nt = 0; nt < 4; ++nt) {
        f4 a0 = acc[mt][nt];
        a0 = mfma16(ah[mt], bh[nt], a0);
        a0 = mfma16(al[mt], bh[nt], a0);
        a0 = mfma16(ah[mt], bl[nt], a0);
        acc[mt][nt] = a0;
      }
  }
  const int r0 = (l >> 4) * 4;
#pragma unroll
  for (int mt = 0; mt < 4; ++mt)
#pragma unroll
    for (int nt = 0; nt < 4; ++nt) {
      const int n = n0 + wn * 64 + nt * 16 + fr;
      const float bv = bias[n];
      const size_t mb = (size_t)(m0 + wm * 64 + mt * 16 + r0);
#pragma unroll
      for (int j = 0; j < 4; ++j) C[(mb + j) * 256 + n] = acc[mt][nt][j] + bv;
    }
}

// LDS pointer with per-row XOR swizzle (float index d at byte 4d ^ ((d>>5&7)<<4));
// bijective per 1 KiB row; kills the fixed-h 8-way read conflict.
__device__ __forceinline__ float* ldsP(float* base, int row, int d) {
  return (float*)((char*)base + row * 1024 + ((4 * d) ^ (((d >> 5) & 7) << 4)));
}

// One block per (b, nb). ONE barrier. Block-node (kc=16) folded analytically:
// dot(q,k16) = mean_t dot(q,K[t]);  comb16*V16 = sum_t (comb16/16)*V[t].
// efeat/mask staged coalesced into LDS. Output hi|lo overlays the Q buffer.
__global__ __launch_bounds__(256, 4) void attn_v4(
    const float* __restrict__ Qb, const float* __restrict__ Kb,
    const float* __restrict__ Vb, const int* __restrict__ amask,
    const float* __restrict__ efeat, const float* __restrict__ Wgate,
    const float* __restrict__ bgate, short* __restrict__ AO2) {
  __shared__ float Ks[16 * 256];   // swizzled, 16 KiB
  __shared__ float Vs[16 * 256];   // swizzled, 16 KiB
  __shared__ float4 Es[LQ * KCNT]; // edge feats, 4.25 KiB
  __shared__ int Ms[LQ * KCNT];    // mask, 1.06 KiB

  const int tid = threadIdx.x, g = blockIdx.x;
  const int b = g >> 11, nb = g & (NB - 1);
  const size_t tok0 = (size_t)(b * N_SEQ + nb * LQ);

  // stage 16 leaf K,V rows (coalesced float4 -> swizzled LDS)
#pragma unroll
  for (int i = 0; i < 4; ++i) {
    const int f = tid + i * 256;
    const int t = f >> 6, c4 = (f & 63) * 4;
    *(float4*)ldsP(Ks, t, c4) = *(const float4*)(Kb + (tok0 + t) * 256 + c4);
    *(float4*)ldsP(Vs, t, c4) = *(const float4*)(Vb + (tok0 + t) * 256 + c4);
  }
  // stage efeat (272 float4) and mask (272 int), coalesced
  {
    const float4* esrc = (const float4*)(efeat + (size_t)nb * LQ * KCNT * 4);
    const int* msrc = amask + (size_t)nb * LQ * KCNT;
    Es[tid] = esrc[tid];
    Ms[tid] = msrc[tid];
    if (tid < LQ * KCNT - 256) {
      Es[256 + tid] = esrc[256 + tid];
      Ms[256 + tid] = msrc[256 + tid];
    }
  }
  __syncthreads();

  // fused phase: thread (q = tid>>4, h = (tid>>1)&7, half = tid&1)
  const int q = tid >> 4, h = (tid >> 1) & 7, half = tid & 1;
  const int d0 = h * HD + half * 16;

  float qh[16];
  {
    const float* qp = Qb + (tok0 + q) * 256 + d0;
#pragma unroll
    for (int j = 0; j < 4; ++j) {
      float4 v = *(const float4*)(qp + j * 4);
      qh[j * 4] = v.x; qh[j * 4 + 1] = v.y;
      qh[j * 4 + 2] = v.z; qh[j * 4 + 3] = v.w;
    }
  }
  const float wg0 = Wgate[h * 4], wg1 = Wgate[h * 4 + 1];
  const float wg2 = Wgate[h * 4 + 2], wg3 = Wgate[h * 4 + 3];
  const float bg = bgate[h];

  float sc[16], gt[16];
  float rawsum = 0.f;
  unsigned vis = 0;
  float mx = -1e30f;
#pragma unroll
  for (int kc = 0; kc < 16; ++kc) {
    float dot = 0.f;
#pragma unroll
    for (int j = 0; j < 4; ++j) {
      float4 kv = *(const float4*)ldsP(Ks, kc, d0 + j * 4);
      dot += qh[j * 4] * kv.x + qh[j * 4 + 1] * kv.y +
             qh[j * 4 + 2] * kv.z + qh[j * 4 + 3] * kv.w;
    }
    dot += __shfl_xor(dot, 1);  // combine the two 16-dim halves
    rawsum += dot;
    float e0, e1, e2, e3;
    if (kc == q) { e0 = e1 = e2 = 0.f; e3 = 1.f; }
    else { float4 e = Es[q * KCNT + kc]; e0 = e.x; e1 = e.y; e2 = e.z; e3 = e.w; }
    const int m = Ms[q * KCNT + kc];
    const float s = dot * SCALE_F + e3;
    sc[kc] = s;
    if (m) { vis |= (1u << kc); mx = fmaxf(mx, s); }
    gt[kc] = m ? (e0 * wg0 + e1 * wg1 + e2 * wg2 + e3 * wg3 + bg) : 0.f;
  }
  // block-node column (kc=16): e = unit, k16 = mean of leaf k rows
  const float s16 = rawsum * 0.0625f * SCALE_F + 1.0f;
  const int m16 = Ms[q * KCNT + 16];
  const float gt16 = m16 ? (wg3 + bg) : 0.f;
  if (m16) mx = fmaxf(mx, s16);

  float den = 0.f;
#pragma unroll
  for (int kc = 0; kc < 16; ++kc) {
    const float pv = (vis & (1u << kc)) ? __expf(sc[kc] - mx) : 0.f;
    sc[kc] = pv;
    den += pv;
  }
  const float p16 = m16 ? __expf(s16 - mx) : 0.f;
  den += p16;
  const float inv = 1.f / den;
  const float cb16 = (p16 * inv + gt16) * 0.0625f;  // folded into leaf coefs
#pragma unroll
  for (int kc = 0; kc < 16; ++kc) sc[kc] = sc[kc] * inv + gt[kc] + cb16;

  float o[16] = {};
#pragma unroll
  for (int kc = 0; kc < 16; ++kc) {
    const float c = sc[kc];
#pragma unroll
    for (int j = 0; j < 4; ++j) {
      float4 vv = *(const float4*)ldsP(Vs, kc, d0 + j * 4);
      o[j * 4] += c * vv.x;
      o[j * 4 + 1] += c * vv.y;
      o[j * 4 + 2] += c * vv.z;
      o[j * 4 + 3] += c * vv.w;
    }
  }
  // hi|lo bf16 output overlays the Q buffer; writers == readers of row tok0+q
  // (same wave, reads precede writes in program order) -> race-free.
  short* ao = AO2 + (tok0 + q) * 512 + d0;
  sv8 hi, lo;
#pragma unroll
  for (int e = 0; e < 8; ++e) {
    const short hb = f2bf(o[e]);
    hi[e] = hb;
    lo[e] = f2bf(o[e] - bf2f(hb));
  }
  *(sv8*)ao = hi;
  *(sv8*)&ao[256] = lo;
#pragma unroll
  for (int e = 0; e < 8; ++e) {
    const short hb = f2bf(o[8 + e]);
    hi[e] = hb;
    lo[e] = f2bf(o[8 + e] - bf2f(hb));
  }
  *(sv8*)&ao[8] = hi;
  *(sv8*)&ao[264] = lo;
}

extern "C" void kernel_launch(void* const* d_in, const int* in_sizes, int n_in,
                              void* d_out, int out_size, void* d_ws, size_t ws_size,
                              hipStream_t stream) {
  const float* x = (const float*)d_in[0];
  const int* amask = (const int*)d_in[1];
  const float* efeat = (const float*)d_in[2];
  const float* Wqkv = (const float*)d_in[3];
  const float* bqkv = (const float*)d_in[4];
  const float* Wproj = (const float*)d_in[5];
  const float* bproj = (const float*)d_in[6];
  const float* Wgate = (const float*)d_in[7];
  const float* bgate = (const float*)d_in[8];
  float* out = (float*)d_out;

  char* ws = (char*)d_ws;
  const size_t QSZ = (size_t)M_ROWS * 256 * 4;  // 64 MiB
  const size_t W2Q_SZ = (size_t)768 * 512 * 2;
  const size_t W2P_SZ = (size_t)256 * 512 * 2;

  if (ws_size >= 3 * QSZ + W2Q_SZ + W2P_SZ) {
    short* X2 = (short*)ws;
    float* Qb = (float*)(ws + QSZ);
    float* Kb = (float*)(ws + 2 * QSZ);
    short* W2Q = (short*)(ws + 3 * QSZ);
    short* W2P = (short*)(ws + 3 * QSZ + W2Q_SZ);
    float* Vb = out;
    split256<<<dim3(M_ROWS * 64 / 256), 256, 0, stream>>>(x, X2, M_ROWS * 64);
    split256<<<dim3(768 * 64 / 256), 256, 0, stream>>>(Wqkv, W2Q, 768 * 64);
    split256<<<dim3(256 * 64 / 256), 256, 0, stream>>>(Wproj, W2P, 256 * 64);
    gemm_pre_qkv<<<dim3(6, M_ROWS / 128), 256, 0, stream>>>(X2, W2Q, bqkv, Qb, Kb, Vb);
    attn_v4<<<dim3(B_SZ * NB), 256, 0, stream>>>(Qb, Kb, Vb, amask, efeat,
                                                 Wgate, bgate, (short*)Qb);
    gemm_pre_out<<<dim3(2, M_ROWS / 128), 256, 0, stream>>>((const short*)Qb,
                                                            W2P, bproj, out);
  } else {
    if (ws_size < 2 * QSZ) return;
    float* Qb = (float*)ws;
    float* Kb = (float*)(ws + QSZ);
    float* Vb = out;
    gemm_qkv<<<dim3(M_ROWS / 128, 6), 256, 0, stream>>>(x, Wqkv, bqkv, Qb, Kb, Vb);
    attn_v4<<<dim3(B_SZ * NB), 256, 0, stream>>>(Qb, Kb, Vb, amask, efeat,
                                                 Wgate, bgate, (short*)Qb);
    gemm_out<<<dim3(M_ROWS / 128, 2), 256, 0, stream>>>((const short*)Qb, Wproj,
                                                        bproj, out);
  }
}

// Round 8
// 298.398 us; speedup vs baseline: 1.0411x; 1.0411x over previous
//
#include <hip/hip_runtime.h>
#include <cstdint>
#include <cstddef>

#define B_SZ 2
#define N_SEQ 32768
#define NB 2048
#define HD 32
#define LQ 16
#define KCNT 17
#define M_ROWS 65536
#define SCALE_F 0.17677669529663687f /* 32^-0.5 */

typedef __attribute__((ext_vector_type(8))) short sv8;
typedef __attribute__((ext_vector_type(4))) short sv4;
typedef __attribute__((ext_vector_type(4))) float f4;

__device__ __forceinline__ short f2bf(float f) {
  unsigned u = __builtin_bit_cast(unsigned, f);
  u = (u + 0x7FFFu + ((u >> 16) & 1u)) >> 16;
  return (short)u;
}
__device__ __forceinline__ float bf2f(short s) {
  unsigned u = ((unsigned)(unsigned short)s) << 16;
  return __builtin_bit_cast(float, u);
}
__device__ __forceinline__ void split8(const float* __restrict__ p, sv8& hi, sv8& lo) {
  float4 f0 = *(const float4*)p, f1 = *(const float4*)(p + 4);
  float fv[8] = {f0.x, f0.y, f0.z, f0.w, f1.x, f1.y, f1.z, f1.w};
#pragma unroll
  for (int j = 0; j < 8; ++j) {
    short h = f2bf(fv[j]);
    hi[j] = h;
    lo[j] = f2bf(fv[j] - bf2f(h));
  }
}
__device__ __forceinline__ void gload16(const void* g, void* l) {
  __builtin_amdgcn_global_load_lds(
      (const __attribute__((address_space(1))) unsigned int*)g,
      (__attribute__((address_space(3))) unsigned int*)l, 16, 0, 0);
}
__device__ __forceinline__ f4 mfma16(sv8 a, sv8 b, f4 c) {
  return __builtin_amdgcn_mfma_f32_16x16x32_bf16(a, b, c, 0, 0, 0);
}

// fp32 [rows][256] -> bf16 hi|lo [rows][512]
__global__ __launch_bounds__(256) void split256(const float* __restrict__ src,
                                                short* __restrict__ dst, int n4) {
  int i = blockIdx.x * 256 + threadIdx.x;
  if (i >= n4) return;
  float4 v = ((const float4*)src)[i];
  size_t row = (size_t)(i >> 6);
  int c = (i & 63) * 4;
  float fv[4] = {v.x, v.y, v.z, v.w};
  sv4 hi, lo;
#pragma unroll
  for (int j = 0; j < 4; ++j) {
    short h = f2bf(fv[j]);
    hi[j] = h;
    lo[j] = f2bf(fv[j] - bf2f(h));
  }
  *(sv4*)&dst[row * 512 + c] = hi;
  *(sv4*)&dst[row * 512 + 256 + c] = lo;
}

// ---- pre-split GEMM, 2-phase double-buffered + bijective XCD-chunked swizzle.
// 1-D grid of NT*512 blocks. lbid = (bid&7)*(nwg/8) + bid>>3 puts an M-panel's
// NT N-tile siblings on the SAME XCD (A-panel fetched once per XCD).
// Logical order: N fastest. K' = 24 steps of 32: hh(0-7) lh(8-15) hl(16-23).
#define GEMM_PRE_BODY(NT)                                                      \
  __shared__ __align__(16) short As[2][128][32];                               \
  __shared__ __align__(16) short Bs[2][128][32];                               \
  const int tid = threadIdx.x;                                                 \
  const int w = tid >> 6, l = tid & 63;                                        \
  const int wm = w >> 1, wn = w & 1;                                           \
  const int bid = blockIdx.x;                                                  \
  const int chunk = (NT * 512) >> 3;                                           \
  const int lbid = (bid & 7) * chunk + (bid >> 3);                             \
  const int nti = lbid % (NT), mti = lbid / (NT);                              \
  const int m0 = mti * 128, n0 = nti * 128;                                    \
  const int lr = l >> 2;                                                       \
  const int lc = (l & 3) * 8;                                                  \
  const int fr = l & 15, kg = (l >> 4) * 8;                                    \
  auto kaof = [](int s) { return ((s >= 8 && s < 16) ? 256 : 0) + (s & 7) * 32; }; \
  auto kbof = [](int s) { return ((s >= 16) ? 256 : 0) + (s & 7) * 32; };      \
  f4 acc[4][4] = {};                                                           \
  _Pragma("unroll") for (int i = 0; i < 2; ++i) {                              \
    const int row = w * 32 + i * 16;                                           \
    gload16(A2 + (size_t)(m0 + row + lr) * 512 + kaof(0) + lc, (void*)&As[0][row][0]); \
    gload16(B2 + (size_t)(n0 + row + lr) * 512 + kbof(0) + lc, (void*)&Bs[0][row][0]); \
  }                                                                            \
  __syncthreads();                                                             \
  int cur = 0;                                                                 \
  for (int s = 0; s < 24; ++s) {                                               \
    if (s < 23) {                                                              \
      const int ka = kaof(s + 1), kb = kbof(s + 1);                            \
      _Pragma("unroll") for (int i = 0; i < 2; ++i) {                          \
        const int row = w * 32 + i * 16;                                       \
        gload16(A2 + (size_t)(m0 + row + lr) * 512 + ka + lc, (void*)&As[cur ^ 1][row][0]); \
        gload16(B2 + (size_t)(n0 + row + lr) * 512 + kb + lc, (void*)&Bs[cur ^ 1][row][0]); \
      }                                                                        \
    }                                                                          \
    sv8 a[4], bb[4];                                                           \
    _Pragma("unroll") for (int t = 0; t < 4; ++t) {                            \
      a[t] = *(const sv8*)&As[cur][wm * 64 + t * 16 + fr][kg];                 \
      bb[t] = *(const sv8*)&Bs[cur][wn * 64 + t * 16 + fr][kg];                \
    }                                                                          \
    _Pragma("unroll") for (int mt = 0; mt < 4; ++mt)                           \
      _Pragma("unroll") for (int nt = 0; nt < 4; ++nt)                         \
        acc[mt][nt] = mfma16(a[mt], bb[nt], acc[mt][nt]);                      \
    __syncthreads();                                                           \
    cur ^= 1;                                                                  \
  }

__global__ __launch_bounds__(256) void gemm_pre_qkv(
    const short* __restrict__ A2, const short* __restrict__ B2,
    const float* __restrict__ bias, float* __restrict__ Qb,
    float* __restrict__ Kb, float* __restrict__ Vb) {
  GEMM_PRE_BODY(6)
  float* dst = (nti < 2) ? Qb : ((nti < 4) ? Kb : Vb);
  const int r0 = (l >> 4) * 4;
#pragma unroll
  for (int mt = 0; mt < 4; ++mt)
#pragma unroll
    for (int nt = 0; nt < 4; ++nt) {
      const int n = n0 + wn * 64 + nt * 16 + fr;
      const float bv = bias[n];
      const int nn = n & 255;
      const size_t mb = (size_t)(m0 + wm * 64 + mt * 16 + r0);
#pragma unroll
      for (int j = 0; j < 4; ++j) dst[(mb + j) * 256 + nn] = acc[mt][nt][j] + bv;
    }
}

__global__ __launch_bounds__(256) void gemm_pre_out(
    const short* __restrict__ A2, const short* __restrict__ B2,
    const float* __restrict__ bias, float* __restrict__ C) {
  GEMM_PRE_BODY(2)
  const int r0 = (l >> 4) * 4;
#pragma unroll
  for (int mt = 0; mt < 4; ++mt)
#pragma unroll
    for (int nt = 0; nt < 4; ++nt) {
      const int n = n0 + wn * 64 + nt * 16 + fr;
      const float bv = bias[n];
      const size_t mb = (size_t)(m0 + wm * 64 + mt * 16 + r0);
#pragma unroll
      for (int j = 0; j < 4; ++j) C[(mb + j) * 256 + n] = acc[mt][nt][j] + bv;
    }
}

// ---- fallback on-the-fly-split GEMMs (proven round 4) ----
__global__ __launch_bounds__(256) void gemm_qkv(
    const float* __restrict__ X, const float* __restrict__ W,
    const float* __restrict__ bias, float* __restrict__ Qb,
    float* __restrict__ Kb, float* __restrict__ Vb) {
  const int tid = threadIdx.x, w = tid >> 6, l = tid & 63;
  const int wm = w >> 1, wn = w & 1;
  const int m0 = blockIdx.x * 128, n0 = blockIdx.y * 128;
  const int fr = l & 15, kg = (l >> 4) * 8;
  f4 acc[4][4] = {};
  for (int s = 0; s < 8; ++s) {
    const int k0 = s * 32 + kg;
    sv8 ah[4], al[4], bh[4], bl[4];
#pragma unroll
    for (int t = 0; t < 4; ++t) {
      split8(X + (size_t)(m0 + wm * 64 + t * 16 + fr) * 256 + k0, ah[t], al[t]);
      split8(W + (size_t)(n0 + wn * 64 + t * 16 + fr) * 256 + k0, bh[t], bl[t]);
    }
#pragma unroll
    for (int mt = 0; mt < 4; ++mt)
#pragma unroll
      for (int nt = 0; nt < 4; ++nt) {
        f4 a0 = acc[mt][nt];
        a0 = mfma16(ah[mt], bh[nt], a0);
        a0 = mfma16(al[mt], bh[nt], a0);
        a0 = mfma16(ah[mt], bl[nt], a0);
        acc[mt][nt] = a0;
      }
  }
  float* dst = (blockIdx.y < 2) ? Qb : ((blockIdx.y < 4) ? Kb : Vb);
  const int r0 = (l >> 4) * 4;
#pragma unroll
  for (int mt = 0; mt < 4; ++mt)
#pragma unroll
    for (int nt = 0; nt < 4; ++nt) {
      const int n = n0 + wn * 64 + nt * 16 + fr;
      const float bv = bias[n];
      const int nn = n & 255;
      const size_t mb = (size_t)(m0 + wm * 64 + mt * 16 + r0);
#pragma unroll
      for (int j = 0; j < 4; ++j) dst[(mb + j) * 256 + nn] = acc[mt][nt][j] + bv;
    }
}

__global__ __launch_bounds__(256) void gemm_out(
    const short* __restrict__ A2, const float* __restrict__ W,
    const float* __restrict__ bias, float* __restrict__ C) {
  const int tid = threadIdx.x, w = tid >> 6, l = tid & 63;
  const int wm = w >> 1, wn = w & 1;
  const int m0 = blockIdx.x * 128, n0 = blockIdx.y * 128;
  const int fr = l & 15, kg = (l >> 4) * 8;
  f4 acc[4][4] = {};
  for (int s = 0; s < 8; ++s) {
    const int k0 = s * 32 + kg;
    sv8 ah[4], al[4], bh[4], bl[4];
#pragma unroll
    for (int t = 0; t < 4; ++t) {
      const short* ap = A2 + (size_t)(m0 + wm * 64 + t * 16 + fr) * 512 + k0;
      ah[t] = *(const sv8*)ap;
      al[t] = *(const sv8*)(ap + 256);
      split8(W + (size_t)(n0 + wn * 64 + t * 16 + fr) * 256 + k0, bh[t], bl[t]);
    }
#pragma unroll
    for (int mt = 0; mt < 4; ++mt)
#pragma unroll
      for (int nt = 0; nt < 4; ++nt) {
        f4 a0 = acc[mt][nt];
        a0 = mfma16(ah[mt], bh[nt], a0);
        a0 = mfma16(al[mt], bh[nt], a0);
        a0 = mfma16(ah[mt], bl[nt], a0);
        acc[mt][nt] = a0;
      }
  }
  const int r0 = (l >> 4) * 4;
#pragma unroll
  for (int mt = 0; mt < 4; ++mt)
#pragma unroll
    for (int nt = 0; nt < 4; ++nt) {
      const int n = n0 + wn * 64 + nt * 16 + fr;
      const float bv = bias[n];
      const size_t mb = (size_t)(m0 + wm * 64 + mt * 16 + r0);
#pragma unroll
      for (int j = 0; j < 4; ++j) C[(mb + j) * 256 + n] = acc[mt][nt][j] + bv;
    }
}

// LDS pointer with per-row XOR swizzle (float index d at byte 4d ^ ((d>>5&7)<<4));
// bijective per 1 KiB row; kills the fixed-h 8-way read conflict.
__device__ __forceinline__ float* ldsP(float* base, int row, int d) {
  return (float*)((char*)base + row * 1024 + ((4 * d) ^ (((d >> 5) & 7) << 4)));
}

// One block per (b, nb). ONE barrier. Block-node (kc=16) folded analytically:
// dot(q,k16) = mean_t dot(q,K[t]);  comb16*V16 = sum_t (comb16/16)*V[t].
// efeat/mask staged coalesced into LDS. Output hi|lo overlays the Q buffer.
__global__ __launch_bounds__(256, 4) void attn_v4(
    const float* __restrict__ Qb, const float* __restrict__ Kb,
    const float* __restrict__ Vb, const int* __restrict__ amask,
    const float* __restrict__ efeat, const float* __restrict__ Wgate,
    const float* __restrict__ bgate, short* __restrict__ AO2) {
  __shared__ float Ks[16 * 256];   // swizzled, 16 KiB
  __shared__ float Vs[16 * 256];   // swizzled, 16 KiB
  __shared__ float4 Es[LQ * KCNT]; // edge feats, 4.25 KiB
  __shared__ int Ms[LQ * KCNT];    // mask, 1.06 KiB

  const int tid = threadIdx.x, g = blockIdx.x;
  const int b = g >> 11, nb = g & (NB - 1);
  const size_t tok0 = (size_t)(b * N_SEQ + nb * LQ);

  // stage 16 leaf K,V rows (coalesced float4 -> swizzled LDS)
#pragma unroll
  for (int i = 0; i < 4; ++i) {
    const int f = tid + i * 256;
    const int t = f >> 6, c4 = (f & 63) * 4;
    *(float4*)ldsP(Ks, t, c4) = *(const float4*)(Kb + (tok0 + t) * 256 + c4);
    *(float4*)ldsP(Vs, t, c4) = *(const float4*)(Vb + (tok0 + t) * 256 + c4);
  }
  // stage efeat (272 float4) and mask (272 int), coalesced
  {
    const float4* esrc = (const float4*)(efeat + (size_t)nb * LQ * KCNT * 4);
    const int* msrc = amask + (size_t)nb * LQ * KCNT;
    Es[tid] = esrc[tid];
    Ms[tid] = msrc[tid];
    if (tid < LQ * KCNT - 256) {
      Es[256 + tid] = esrc[256 + tid];
      Ms[256 + tid] = msrc[256 + tid];
    }
  }
  __syncthreads();

  // fused phase: thread (q = tid>>4, h = (tid>>1)&7, half = tid&1)
  const int q = tid >> 4, h = (tid >> 1) & 7, half = tid & 1;
  const int d0 = h * HD + half * 16;

  float qh[16];
  {
    const float* qp = Qb + (tok0 + q) * 256 + d0;
#pragma unroll
    for (int j = 0; j < 4; ++j) {
      float4 v = *(const float4*)(qp + j * 4);
      qh[j * 4] = v.x; qh[j * 4 + 1] = v.y;
      qh[j * 4 + 2] = v.z; qh[j * 4 + 3] = v.w;
    }
  }
  const float wg0 = Wgate[h * 4], wg1 = Wgate[h * 4 + 1];
  const float wg2 = Wgate[h * 4 + 2], wg3 = Wgate[h * 4 + 3];
  const float bg = bgate[h];

  float sc[16], gt[16];
  float rawsum = 0.f;
  unsigned vis = 0;
  float mx = -1e30f;
#pragma unroll
  for (int kc = 0; kc < 16; ++kc) {
    float dot = 0.f;
#pragma unroll
    for (int j = 0; j < 4; ++j) {
      float4 kv = *(const float4*)ldsP(Ks, kc, d0 + j * 4);
      dot += qh[j * 4] * kv.x + qh[j * 4 + 1] * kv.y +
             qh[j * 4 + 2] * kv.z + qh[j * 4 + 3] * kv.w;
    }
    dot += __shfl_xor(dot, 1);  // combine the two 16-dim halves
    rawsum += dot;
    float e0, e1, e2, e3;
    if (kc == q) { e0 = e1 = e2 = 0.f; e3 = 1.f; }
    else { float4 e = Es[q * KCNT + kc]; e0 = e.x; e1 = e.y; e2 = e.z; e3 = e.w; }
    const int m = Ms[q * KCNT + kc];
    const float s = dot * SCALE_F + e3;
    sc[kc] = s;
    if (m) { vis |= (1u << kc); mx = fmaxf(mx, s); }
    gt[kc] = m ? (e0 * wg0 + e1 * wg1 + e2 * wg2 + e3 * wg3 + bg) : 0.f;
  }
  // block-node column (kc=16): e = unit, k16 = mean of leaf k rows
  const float s16 = rawsum * 0.0625f * SCALE_F + 1.0f;
  const int m16 = Ms[q * KCNT + 16];
  const float gt16 = m16 ? (wg3 + bg) : 0.f;
  if (m16) mx = fmaxf(mx, s16);

  float den = 0.f;
#pragma unroll
  for (int kc = 0; kc < 16; ++kc) {
    const float pv = (vis & (1u << kc)) ? __expf(sc[kc] - mx) : 0.f;
    sc[kc] = pv;
    den += pv;
  }
  const float p16 = m16 ? __expf(s16 - mx) : 0.f;
  den += p16;
  const float inv = 1.f / den;
  const float cb16 = (p16 * inv + gt16) * 0.0625f;  // folded into leaf coefs
#pragma unroll
  for (int kc = 0; kc < 16; ++kc) sc[kc] = sc[kc] * inv + gt[kc] + cb16;

  float o[16] = {};
#pragma unroll
  for (int kc = 0; kc < 16; ++kc) {
    const float c = sc[kc];
#pragma unroll
    for (int j = 0; j < 4; ++j) {
      float4 vv = *(const float4*)ldsP(Vs, kc, d0 + j * 4);
      o[j * 4] += c * vv.x;
      o[j * 4 + 1] += c * vv.y;
      o[j * 4 + 2] += c * vv.z;
      o[j * 4 + 3] += c * vv.w;
    }
  }
  // hi|lo bf16 output overlays the Q buffer; writers == readers of row tok0+q
  // (same wave, reads precede writes in program order) -> race-free.
  short* ao = AO2 + (tok0 + q) * 512 + d0;
  sv8 hi, lo;
#pragma unroll
  for (int e = 0; e < 8; ++e) {
    const short hb = f2bf(o[e]);
    hi[e] = hb;
    lo[e] = f2bf(o[e] - bf2f(hb));
  }
  *(sv8*)ao = hi;
  *(sv8*)&ao[256] = lo;
#pragma unroll
  for (int e = 0; e < 8; ++e) {
    const short hb = f2bf(o[8 + e]);
    hi[e] = hb;
    lo[e] = f2bf(o[8 + e] - bf2f(hb));
  }
  *(sv8*)&ao[8] = hi;
  *(sv8*)&ao[264] = lo;
}

extern "C" void kernel_launch(void* const* d_in, const int* in_sizes, int n_in,
                              void* d_out, int out_size, void* d_ws, size_t ws_size,
                              hipStream_t stream) {
  const float* x = (const float*)d_in[0];
  const int* amask = (const int*)d_in[1];
  const float* efeat = (const float*)d_in[2];
  const float* Wqkv = (const float*)d_in[3];
  const float* bqkv = (const float*)d_in[4];
  const float* Wproj = (const float*)d_in[5];
  const float* bproj = (const float*)d_in[6];
  const float* Wgate = (const float*)d_in[7];
  const float* bgate = (const float*)d_in[8];
  float* out = (float*)d_out;

  char* ws = (char*)d_ws;
  const size_t QSZ = (size_t)M_ROWS * 256 * 4;  // 64 MiB
  const size_t W2Q_SZ = (size_t)768 * 512 * 2;
  const size_t W2P_SZ = (size_t)256 * 512 * 2;

  if (ws_size >= 3 * QSZ + W2Q_SZ + W2P_SZ) {
    short* X2 = (short*)ws;
    float* Qb = (float*)(ws + QSZ);
    float* Kb = (float*)(ws + 2 * QSZ);
    short* W2Q = (short*)(ws + 3 * QSZ);
    short* W2P = (short*)(ws + 3 * QSZ + W2Q_SZ);
    float* Vb = out;
    split256<<<dim3(M_ROWS * 64 / 256), 256, 0, stream>>>(x, X2, M_ROWS * 64);
    split256<<<dim3(768 * 64 / 256), 256, 0, stream>>>(Wqkv, W2Q, 768 * 64);
    split256<<<dim3(256 * 64 / 256), 256, 0, stream>>>(Wproj, W2P, 256 * 64);
    gemm_pre_qkv<<<dim3(6 * 512), 256, 0, stream>>>(X2, W2Q, bqkv, Qb, Kb, Vb);
    attn_v4<<<dim3(B_SZ * NB), 256, 0, stream>>>(Qb, Kb, Vb, amask, efeat,
                                                 Wgate, bgate, (short*)Qb);
    gemm_pre_out<<<dim3(2 * 512), 256, 0, stream>>>((const short*)Qb, W2P,
                                                    bproj, out);
  } else {
    if (ws_size < 2 * QSZ) return;
    float* Qb = (float*)ws;
    float* Kb = (float*)(ws + QSZ);
    float* Vb = out;
    gemm_qkv<<<dim3(M_ROWS / 128, 6), 256, 0, stream>>>(x, Wqkv, bqkv, Qb, Kb, Vb);
    attn_v4<<<dim3(B_SZ * NB), 256, 0, stream>>>(Qb, Kb, Vb, amask, efeat,
                                                 Wgate, bgate, (short*)Qb);
    gemm_out<<<dim3(M_ROWS / 128, 2), 256, 0, stream>>>((const short*)Qb, Wproj,
                                                        bproj, out);
  }
}

// Round 9
// 265.890 us; speedup vs baseline: 1.1683x; 1.1223x over previous
//
#include <hip/hip_runtime.h>
#include <cstdint>
#include <cstddef>

#define B_SZ 2
#define N_SEQ 32768
#define NB 2048
#define HD 32
#define LQ 16
#define KCNT 17
#define M_ROWS 65536
#define SCALE_F 0.17677669529663687f /* 32^-0.5 */

typedef __attribute__((ext_vector_type(8))) short sv8;
typedef __attribute__((ext_vector_type(4))) short sv4;
typedef __attribute__((ext_vector_type(4))) float f4;

__device__ __forceinline__ short f2bf(float f) {
  unsigned u = __builtin_bit_cast(unsigned, f);
  u = (u + 0x7FFFu + ((u >> 16) & 1u)) >> 16;
  return (short)u;
}
__device__ __forceinline__ float bf2f(short s) {
  unsigned u = ((unsigned)(unsigned short)s) << 16;
  return __builtin_bit_cast(float, u);
}
__device__ __forceinline__ void split8(const float* __restrict__ p, sv8& hi, sv8& lo) {
  float4 f0 = *(const float4*)p, f1 = *(const float4*)(p + 4);
  float fv[8] = {f0.x, f0.y, f0.z, f0.w, f1.x, f1.y, f1.z, f1.w};
#pragma unroll
  for (int j = 0; j < 8; ++j) {
    short h = f2bf(fv[j]);
    hi[j] = h;
    lo[j] = f2bf(fv[j] - bf2f(h));
  }
}
__device__ __forceinline__ void gload16(const void* g, void* l) {
  __builtin_amdgcn_global_load_lds(
      (const __attribute__((address_space(1))) unsigned int*)g,
      (__attribute__((address_space(3))) unsigned int*)l, 16, 0, 0);
}
__device__ __forceinline__ f4 mfma16(sv8 a, sv8 b, f4 c) {
  return __builtin_amdgcn_mfma_f32_16x16x32_bf16(a, b, c, 0, 0, 0);
}

// fp32 [rows][256] -> bf16 hi|lo [rows][512]
__global__ __launch_bounds__(256) void split256(const float* __restrict__ src,
                                                short* __restrict__ dst, int n4) {
  int i = blockIdx.x * 256 + threadIdx.x;
  if (i >= n4) return;
  float4 v = ((const float4*)src)[i];
  size_t row = (size_t)(i >> 6);
  int c = (i & 63) * 4;
  float fv[4] = {v.x, v.y, v.z, v.w};
  sv4 hi, lo;
#pragma unroll
  for (int j = 0; j < 4; ++j) {
    short h = f2bf(fv[j]);
    hi[j] = h;
    lo[j] = f2bf(fv[j] - bf2f(h));
  }
  *(sv4*)&dst[row * 512 + c] = hi;
  *(sv4*)&dst[row * 512 + 256 + c] = lo;
}

// ---- pre-split GEMM, k-chunked: 8 chunks, each stages Ahi/Alo/Bhi/Blo (32 KB,
// single buffer) then runs all 3 split-terms = 48 MFMA per barrier pair.
// Bijective XCD-chunked 1-D grid swizzle keeps an M-panel's N-tile siblings on
// one XCD (A fetched ~once; verified FETCH 304->51 MB in round 8).
#define GEMM_PRE_BODY(NT)                                                      \
  __shared__ __align__(16) short Ah[128][32];                                  \
  __shared__ __align__(16) short Al[128][32];                                  \
  __shared__ __align__(16) short Bh[128][32];                                  \
  __shared__ __align__(16) short Bl[128][32];                                  \
  const int tid = threadIdx.x;                                                 \
  const int w = tid >> 6, l = tid & 63;                                        \
  const int wm = w >> 1, wn = w & 1;                                           \
  const int bid = blockIdx.x;                                                  \
  const int chunk = (NT * 512) >> 3;                                           \
  const int lbid = (bid & 7) * chunk + (bid >> 3);                             \
  const int nti = lbid % (NT), mti = lbid / (NT);                              \
  const int m0 = mti * 128, n0 = nti * 128;                                    \
  const int lr = l >> 2;                                                       \
  const int lc = (l & 3) * 8;                                                  \
  const int fr = l & 15, kg = (l >> 4) * 8;                                    \
  f4 acc[4][4] = {};                                                           \
  for (int s = 0; s < 8; ++s) {                                                \
    const int sk = s * 32;                                                     \
    _Pragma("unroll") for (int i = 0; i < 2; ++i) {                            \
      const int row = w * 32 + i * 16;                                         \
      const size_t ra = (size_t)(m0 + row + lr) * 512 + sk + lc;               \
      const size_t rb = (size_t)(n0 + row + lr) * 512 + sk + lc;               \
      gload16(A2 + ra, (void*)&Ah[row][0]);                                    \
      gload16(A2 + ra + 256, (void*)&Al[row][0]);                              \
      gload16(B2 + rb, (void*)&Bh[row][0]);                                    \
      gload16(B2 + rb + 256, (void*)&Bl[row][0]);                              \
    }                                                                          \
    __syncthreads();                                                           \
    sv8 fa[4], fb[4];                                                          \
    _Pragma("unroll") for (int t = 0; t < 4; ++t) {                            \
      fa[t] = *(const sv8*)&Ah[wm * 64 + t * 16 + fr][kg];                     \
      fb[t] = *(const sv8*)&Bh[wn * 64 + t * 16 + fr][kg];                     \
    }                                                                          \
    _Pragma("unroll") for (int mt = 0; mt < 4; ++mt)                           \
      _Pragma("unroll") for (int nt = 0; nt < 4; ++nt)                         \
        acc[mt][nt] = mfma16(fa[mt], fb[nt], acc[mt][nt]);                     \
    _Pragma("unroll") for (int t = 0; t < 4; ++t)                              \
      fb[t] = *(const sv8*)&Bl[wn * 64 + t * 16 + fr][kg];                     \
    _Pragma("unroll") for (int mt = 0; mt < 4; ++mt)                           \
      _Pragma("unroll") for (int nt = 0; nt < 4; ++nt)                         \
        acc[mt][nt] = mfma16(fa[mt], fb[nt], acc[mt][nt]);                     \
    _Pragma("unroll") for (int t = 0; t < 4; ++t) {                            \
      fa[t] = *(const sv8*)&Al[wm * 64 + t * 16 + fr][kg];                     \
      fb[t] = *(const sv8*)&Bh[wn * 64 + t * 16 + fr][kg];                     \
    }                                                                          \
    _Pragma("unroll") for (int mt = 0; mt < 4; ++mt)                           \
      _Pragma("unroll") for (int nt = 0; nt < 4; ++nt)                         \
        acc[mt][nt] = mfma16(fa[mt], fb[nt], acc[mt][nt]);                     \
    __syncthreads();                                                           \
  }

__global__ __launch_bounds__(256) void gemm_pre_qkv(
    const short* __restrict__ A2, const short* __restrict__ B2,
    const float* __restrict__ bias, float* __restrict__ Qb,
    float* __restrict__ Kb, float* __restrict__ Vb) {
  GEMM_PRE_BODY(6)
  float* dst = (nti < 2) ? Qb : ((nti < 4) ? Kb : Vb);
  const int r0 = (l >> 4) * 4;
#pragma unroll
  for (int mt = 0; mt < 4; ++mt)
#pragma unroll
    for (int nt = 0; nt < 4; ++nt) {
      const int n = n0 + wn * 64 + nt * 16 + fr;
      const float bv = bias[n];
      const int nn = n & 255;
      const size_t mb = (size_t)(m0 + wm * 64 + mt * 16 + r0);
#pragma unroll
      for (int j = 0; j < 4; ++j) dst[(mb + j) * 256 + nn] = acc[mt][nt][j] + bv;
    }
}

__global__ __launch_bounds__(256) void gemm_pre_out(
    const short* __restrict__ A2, const short* __restrict__ B2,
    const float* __restrict__ bias, float* __restrict__ C) {
  GEMM_PRE_BODY(2)
  const int r0 = (l >> 4) * 4;
#pragma unroll
  for (int mt = 0; mt < 4; ++mt)
#pragma unroll
    for (int nt = 0; nt < 4; ++nt) {
      const int n = n0 + wn * 64 + nt * 16 + fr;
      const float bv = bias[n];
      const size_t mb = (size_t)(m0 + wm * 64 + mt * 16 + r0);
#pragma unroll
      for (int j = 0; j < 4; ++j) C[(mb + j) * 256 + n] = acc[mt][nt][j] + bv;
    }
}

// ---- fallback on-the-fly-split GEMMs (proven round 4) ----
__global__ __launch_bounds__(256) void gemm_qkv(
    const float* __restrict__ X, const float* __restrict__ W,
    const float* __restrict__ bias, float* __restrict__ Qb,
    float* __restrict__ Kb, float* __restrict__ Vb) {
  const int tid = threadIdx.x, w = tid >> 6, l = tid & 63;
  const int wm = w >> 1, wn = w & 1;
  const int m0 = blockIdx.x * 128, n0 = blockIdx.y * 128;
  const int fr = l & 15, kg = (l >> 4) * 8;
  f4 acc[4][4] = {};
  for (int s = 0; s < 8; ++s) {
    const int k0 = s * 32 + kg;
    sv8 ah[4], al[4], bh[4], bl[4];
#pragma unroll
    for (int t = 0; t < 4; ++t) {
      split8(X + (size_t)(m0 + wm * 64 + t * 16 + fr) * 256 + k0, ah[t], al[t]);
      split8(W + (size_t)(n0 + wn * 64 + t * 16 + fr) * 256 + k0, bh[t], bl[t]);
    }
#pragma unroll
    for (int mt = 0; mt < 4; ++mt)
#pragma unroll
      for (int nt = 0; nt < 4; ++nt) {
        f4 a0 = acc[mt][nt];
        a0 = mfma16(ah[mt], bh[nt], a0);
        a0 = mfma16(al[mt], bh[nt], a0);
        a0 = mfma16(ah[mt], bl[nt], a0);
        acc[mt][nt] = a0;
      }
  }
  float* dst = (blockIdx.y < 2) ? Qb : ((blockIdx.y < 4) ? Kb : Vb);
  const int r0 = (l >> 4) * 4;
#pragma unroll
  for (int mt = 0; mt < 4; ++mt)
#pragma unroll
    for (int nt = 0; nt < 4; ++nt) {
      const int n = n0 + wn * 64 + nt * 16 + fr;
      const float bv = bias[n];
      const int nn = n & 255;
      const size_t mb = (size_t)(m0 + wm * 64 + mt * 16 + r0);
#pragma unroll
      for (int j = 0; j < 4; ++j) dst[(mb + j) * 256 + nn] = acc[mt][nt][j] + bv;
    }
}

__global__ __launch_bounds__(256) void gemm_out(
    const short* __restrict__ A2, const float* __restrict__ W,
    const float* __restrict__ bias, float* __restrict__ C) {
  const int tid = threadIdx.x, w = tid >> 6, l = tid & 63;
  const int wm = w >> 1, wn = w & 1;
  const int m0 = blockIdx.x * 128, n0 = blockIdx.y * 128;
  const int fr = l & 15, kg = (l >> 4) * 8;
  f4 acc[4][4] = {};
  for (int s = 0; s < 8; ++s) {
    const int k0 = s * 32 + kg;
    sv8 ah[4], al[4], bh[4], bl[4];
#pragma unroll
    for (int t = 0; t < 4; ++t) {
      const short* ap = A2 + (size_t)(m0 + wm * 64 + t * 16 + fr) * 512 + k0;
      ah[t] = *(const sv8*)ap;
      al[t] = *(const sv8*)(ap + 256);
      split8(W + (size_t)(n0 + wn * 64 + t * 16 + fr) * 256 + k0, bh[t], bl[t]);
    }
#pragma unroll
    for (int mt = 0; mt < 4; ++mt)
#pragma unroll
      for (int nt = 0; nt < 4; ++nt) {
        f4 a0 = acc[mt][nt];
        a0 = mfma16(ah[mt], bh[nt], a0);
        a0 = mfma16(al[mt], bh[nt], a0);
        a0 = mfma16(ah[mt], bl[nt], a0);
        acc[mt][nt] = a0;
      }
  }
  const int r0 = (l >> 4) * 4;
#pragma unroll
  for (int mt = 0; mt < 4; ++mt)
#pragma unroll
    for (int nt = 0; nt < 4; ++nt) {
      const int n = n0 + wn * 64 + nt * 16 + fr;
      const float bv = bias[n];
      const size_t mb = (size_t)(m0 + wm * 64 + mt * 16 + r0);
#pragma unroll
      for (int j = 0; j < 4; ++j) C[(mb + j) * 256 + n] = acc[mt][nt][j] + bv;
    }
}

// LDS pointer with per-row XOR swizzle (float index d at byte 4d ^ ((d>>5&7)<<4));
// bijective per 1 KiB row; kills the fixed-h 8-way read conflict.
__device__ __forceinline__ float* ldsP(float* base, int row, int d) {
  return (float*)((char*)base + row * 1024 + ((4 * d) ^ (((d >> 5) & 7) << 4)));
}

// One block per (b, nb). ONE barrier. Block-node (kc=16) folded analytically:
// dot(q,k16) = mean_t dot(q,K[t]);  comb16*V16 = sum_t (comb16/16)*V[t].
// efeat/mask staged coalesced into LDS. Output hi|lo overlays the Q buffer.
__global__ __launch_bounds__(256, 4) void attn_v4(
    const float* __restrict__ Qb, const float* __restrict__ Kb,
    const float* __restrict__ Vb, const int* __restrict__ amask,
    const float* __restrict__ efeat, const float* __restrict__ Wgate,
    const float* __restrict__ bgate, short* __restrict__ AO2) {
  __shared__ float Ks[16 * 256];   // swizzled, 16 KiB
  __shared__ float Vs[16 * 256];   // swizzled, 16 KiB
  __shared__ float4 Es[LQ * KCNT]; // edge feats, 4.25 KiB
  __shared__ int Ms[LQ * KCNT];    // mask, 1.06 KiB

  const int tid = threadIdx.x, g = blockIdx.x;
  const int b = g >> 11, nb = g & (NB - 1);
  const size_t tok0 = (size_t)(b * N_SEQ + nb * LQ);

  // stage 16 leaf K,V rows (coalesced float4 -> swizzled LDS)
#pragma unroll
  for (int i = 0; i < 4; ++i) {
    const int f = tid + i * 256;
    const int t = f >> 6, c4 = (f & 63) * 4;
    *(float4*)ldsP(Ks, t, c4) = *(const float4*)(Kb + (tok0 + t) * 256 + c4);
    *(float4*)ldsP(Vs, t, c4) = *(const float4*)(Vb + (tok0 + t) * 256 + c4);
  }
  // stage efeat (272 float4) and mask (272 int), coalesced
  {
    const float4* esrc = (const float4*)(efeat + (size_t)nb * LQ * KCNT * 4);
    const int* msrc = amask + (size_t)nb * LQ * KCNT;
    Es[tid] = esrc[tid];
    Ms[tid] = msrc[tid];
    if (tid < LQ * KCNT - 256) {
      Es[256 + tid] = esrc[256 + tid];
      Ms[256 + tid] = msrc[256 + tid];
    }
  }
  __syncthreads();

  // fused phase: thread (q = tid>>4, h = (tid>>1)&7, half = tid&1)
  const int q = tid >> 4, h = (tid >> 1) & 7, half = tid & 1;
  const int d0 = h * HD + half * 16;

  float qh[16];
  {
    const float* qp = Qb + (tok0 + q) * 256 + d0;
#pragma unroll
    for (int j = 0; j < 4; ++j) {
      float4 v = *(const float4*)(qp + j * 4);
      qh[j * 4] = v.x; qh[j * 4 + 1] = v.y;
      qh[j * 4 + 2] = v.z; qh[j * 4 + 3] = v.w;
    }
  }
  const float wg0 = Wgate[h * 4], wg1 = Wgate[h * 4 + 1];
  const float wg2 = Wgate[h * 4 + 2], wg3 = Wgate[h * 4 + 3];
  const float bg = bgate[h];

  float sc[16], gt[16];
  float rawsum = 0.f;
  unsigned vis = 0;
  float mx = -1e30f;
#pragma unroll
  for (int kc = 0; kc < 16; ++kc) {
    float dot = 0.f;
#pragma unroll
    for (int j = 0; j < 4; ++j) {
      float4 kv = *(const float4*)ldsP(Ks, kc, d0 + j * 4);
      dot += qh[j * 4] * kv.x + qh[j * 4 + 1] * kv.y +
             qh[j * 4 + 2] * kv.z + qh[j * 4 + 3] * kv.w;
    }
    dot += __shfl_xor(dot, 1);  // combine the two 16-dim halves
    rawsum += dot;
    float e0, e1, e2, e3;
    if (kc == q) { e0 = e1 = e2 = 0.f; e3 = 1.f; }
    else { float4 e = Es[q * KCNT + kc]; e0 = e.x; e1 = e.y; e2 = e.z; e3 = e.w; }
    const int m = Ms[q * KCNT + kc];
    const float s = dot * SCALE_F + e3;
    sc[kc] = s;
    if (m) { vis |= (1u << kc); mx = fmaxf(mx, s); }
    gt[kc] = m ? (e0 * wg0 + e1 * wg1 + e2 * wg2 + e3 * wg3 + bg) : 0.f;
  }
  // block-node column (kc=16): e = unit, k16 = mean of leaf k rows
  const float s16 = rawsum * 0.0625f * SCALE_F + 1.0f;
  const int m16 = Ms[q * KCNT + 16];
  const float gt16 = m16 ? (wg3 + bg) : 0.f;
  if (m16) mx = fmaxf(mx, s16);

  float den = 0.f;
#pragma unroll
  for (int kc = 0; kc < 16; ++kc) {
    const float pv = (vis & (1u << kc)) ? __expf(sc[kc] - mx) : 0.f;
    sc[kc] = pv;
    den += pv;
  }
  const float p16 = m16 ? __expf(s16 - mx) : 0.f;
  den += p16;
  const float inv = 1.f / den;
  const float cb16 = (p16 * inv + gt16) * 0.0625f;  // folded into leaf coefs
#pragma unroll
  for (int kc = 0; kc < 16; ++kc) sc[kc] = sc[kc] * inv + gt[kc] + cb16;

  float o[16] = {};
#pragma unroll
  for (int kc = 0; kc < 16; ++kc) {
    const float c = sc[kc];
#pragma unroll
    for (int j = 0; j < 4; ++j) {
      float4 vv = *(const float4*)ldsP(Vs, kc, d0 + j * 4);
      o[j * 4] += c * vv.x;
      o[j * 4 + 1] += c * vv.y;
      o[j * 4 + 2] += c * vv.z;
      o[j * 4 + 3] += c * vv.w;
    }
  }
  // hi|lo bf16 output overlays the Q buffer; writers == readers of row tok0+q
  // (same wave, reads precede writes in program order) -> race-free.
  short* ao = AO2 + (tok0 + q) * 512 + d0;
  sv8 hi, lo;
#pragma unroll
  for (int e = 0; e < 8; ++e) {
    const short hb = f2bf(o[e]);
    hi[e] = hb;
    lo[e] = f2bf(o[e] - bf2f(hb));
  }
  *(sv8*)ao = hi;
  *(sv8*)&ao[256] = lo;
#pragma unroll
  for (int e = 0; e < 8; ++e) {
    const short hb = f2bf(o[8 + e]);
    hi[e] = hb;
    lo[e] = f2bf(o[8 + e] - bf2f(hb));
  }
  *(sv8*)&ao[8] = hi;
  *(sv8*)&ao[264] = lo;
}

extern "C" void kernel_launch(void* const* d_in, const int* in_sizes, int n_in,
                              void* d_out, int out_size, void* d_ws, size_t ws_size,
                              hipStream_t stream) {
  const float* x = (const float*)d_in[0];
  const int* amask = (const int*)d_in[1];
  const float* efeat = (const float*)d_in[2];
  const float* Wqkv = (const float*)d_in[3];
  const float* bqkv = (const float*)d_in[4];
  const float* Wproj = (const float*)d_in[5];
  const float* bproj = (const float*)d_in[6];
  const float* Wgate = (const float*)d_in[7];
  const float* bgate = (const float*)d_in[8];
  float* out = (float*)d_out;

  char* ws = (char*)d_ws;
  const size_t QSZ = (size_t)M_ROWS * 256 * 4;  // 64 MiB
  const size_t W2Q_SZ = (size_t)768 * 512 * 2;
  const size_t W2P_SZ = (size_t)256 * 512 * 2;

  if (ws_size >= 3 * QSZ + W2Q_SZ + W2P_SZ) {
    short* X2 = (short*)ws;
    float* Qb = (float*)(ws + QSZ);
    float* Kb = (float*)(ws + 2 * QSZ);
    short* W2Q = (short*)(ws + 3 * QSZ);
    short* W2P = (short*)(ws + 3 * QSZ + W2Q_SZ);
    float* Vb = out;
    split256<<<dim3(M_ROWS * 64 / 256), 256, 0, stream>>>(x, X2, M_ROWS * 64);
    split256<<<dim3(768 * 64 / 256), 256, 0, stream>>>(Wqkv, W2Q, 768 * 64);
    split256<<<dim3(256 * 64 / 256), 256, 0, stream>>>(Wproj, W2P, 256 * 64);
    gemm_pre_qkv<<<dim3(6 * 512), 256, 0, stream>>>(X2, W2Q, bqkv, Qb, Kb, Vb);
    attn_v4<<<dim3(B_SZ * NB), 256, 0, stream>>>(Qb, Kb, Vb, amask, efeat,
                                                 Wgate, bgate, (short*)Qb);
    gemm_pre_out<<<dim3(2 * 512), 256, 0, stream>>>((const short*)Qb, W2P,
                                                    bproj, out);
  } else {
    if (ws_size < 2 * QSZ) return;
    float* Qb = (float*)ws;
    float* Kb = (float*)(ws + QSZ);
    float* Vb = out;
    gemm_qkv<<<dim3(M_ROWS / 128, 6), 256, 0, stream>>>(x, Wqkv, bqkv, Qb, Kb, Vb);
    attn_v4<<<dim3(B_SZ * NB), 256, 0, stream>>>(Qb, Kb, Vb, amask, efeat,
                                                 Wgate, bgate, (short*)Qb);
    gemm_out<<<dim3(M_ROWS / 128, 2), 256, 0, stream>>>((const short*)Qb, Wproj,
                                                        bproj, out);
  }
}

// Round 10
// 232.986 us; speedup vs baseline: 1.3333x; 1.1412x over previous
//
#include <hip/hip_runtime.h>
#include <cstdint>
#include <cstddef>

#define B_SZ 2
#define N_SEQ 32768
#define NB 2048
#define HD 32
#define LQ 16
#define KCNT 17
#define M_ROWS 65536
#define SCALE_F 0.17677669529663687f /* 32^-0.5 */

typedef __attribute__((ext_vector_type(8))) short sv8;
typedef __attribute__((ext_vector_type(4))) short sv4;
typedef __attribute__((ext_vector_type(4))) float f4;

__device__ __forceinline__ short f2bf(float f) {
  unsigned u = __builtin_bit_cast(unsigned, f);
  u = (u + 0x7FFFu + ((u >> 16) & 1u)) >> 16;
  return (short)u;
}
__device__ __forceinline__ float bf2f(short s) {
  unsigned u = ((unsigned)(unsigned short)s) << 16;
  return __builtin_bit_cast(float, u);
}
__device__ __forceinline__ void split8(const float* __restrict__ p, sv8& hi, sv8& lo) {
  float4 f0 = *(const float4*)p, f1 = *(const float4*)(p + 4);
  float fv[8] = {f0.x, f0.y, f0.z, f0.w, f1.x, f1.y, f1.z, f1.w};
#pragma unroll
  for (int j = 0; j < 8; ++j) {
    short h = f2bf(fv[j]);
    hi[j] = h;
    lo[j] = f2bf(fv[j] - bf2f(h));
  }
}
__device__ __forceinline__ void gload16(const void* g, void* l) {
  __builtin_amdgcn_global_load_lds(
      (const __attribute__((address_space(1))) unsigned int*)g,
      (__attribute__((address_space(3))) unsigned int*)l, 16, 0, 0);
}
__device__ __forceinline__ f4 mfma16(sv8 a, sv8 b, f4 c) {
  return __builtin_amdgcn_mfma_f32_16x16x32_bf16(a, b, c, 0, 0, 0);
}

// fp32 [rows][256] -> bf16 hi|lo [rows][512]
__global__ __launch_bounds__(256) void split256(const float* __restrict__ src,
                                                short* __restrict__ dst, int n4) {
  int i = blockIdx.x * 256 + threadIdx.x;
  if (i >= n4) return;
  float4 v = ((const float4*)src)[i];
  size_t row = (size_t)(i >> 6);
  int c = (i & 63) * 4;
  float fv[4] = {v.x, v.y, v.z, v.w};
  sv4 hi, lo;
#pragma unroll
  for (int j = 0; j < 4; ++j) {
    short h = f2bf(fv[j]);
    hi[j] = h;
    lo[j] = f2bf(fv[j] - bf2f(h));
  }
  *(sv4*)&dst[row * 512 + c] = hi;
  *(sv4*)&dst[row * 512 + 256 + c] = lo;
}

// ---- pre-split GEMM, 2-term (C = (Ah+Al)*Bh, i.e. bf16-rounded weights),
// k-chunked (32-wide) + double-buffered: prefetch chunk s+1 while computing s.
// LDS 48 KB -> 3 blocks/CU. Bijective XCD-chunked 1-D grid swizzle keeps an
// M-panel's N-tile siblings on one XCD (verified FETCH 304->44 MB).
#define GEMM_PRE_BODY(NT)                                                      \
  __shared__ __align__(16) short Ah[2][128][32];                               \
  __shared__ __align__(16) short Al[2][128][32];                               \
  __shared__ __align__(16) short Bh[2][128][32];                               \
  const int tid = threadIdx.x;                                                 \
  const int w = tid >> 6, l = tid & 63;                                        \
  const int wm = w >> 1, wn = w & 1;                                           \
  const int bid = blockIdx.x;                                                  \
  const int chunk = (NT * 512) >> 3;                                           \
  const int lbid = (bid & 7) * chunk + (bid >> 3);                             \
  const int nti = lbid % (NT), mti = lbid / (NT);                              \
  const int m0 = mti * 128, n0 = nti * 128;                                    \
  const int lr = l >> 2;                                                       \
  const int lc = (l & 3) * 8;                                                  \
  const int fr = l & 15, kg = (l >> 4) * 8;                                    \
  f4 acc[4][4] = {};                                                           \
  _Pragma("unroll") for (int i = 0; i < 2; ++i) {                              \
    const int row = w * 32 + i * 16;                                           \
    const size_t ra = (size_t)(m0 + row + lr) * 512 + lc;                      \
    const size_t rb = (size_t)(n0 + row + lr) * 512 + lc;                      \
    gload16(A2 + ra, (void*)&Ah[0][row][0]);                                   \
    gload16(A2 + ra + 256, (void*)&Al[0][row][0]);                             \
    gload16(B2 + rb, (void*)&Bh[0][row][0]);                                   \
  }                                                                            \
  __syncthreads();                                                             \
  int cur = 0;                                                                 \
  for (int s = 0; s < 8; ++s) {                                                \
    if (s < 7) {                                                               \
      const int sk = (s + 1) * 32;                                             \
      _Pragma("unroll") for (int i = 0; i < 2; ++i) {                          \
        const int row = w * 32 + i * 16;                                       \
        const size_t ra = (size_t)(m0 + row + lr) * 512 + sk + lc;             \
        const size_t rb = (size_t)(n0 + row + lr) * 512 + sk + lc;             \
        gload16(A2 + ra, (void*)&Ah[cur ^ 1][row][0]);                         \
        gload16(A2 + ra + 256, (void*)&Al[cur ^ 1][row][0]);                   \
        gload16(B2 + rb, (void*)&Bh[cur ^ 1][row][0]);                         \
      }                                                                        \
    }                                                                          \
    sv8 fa[4], fb[4];                                                          \
    _Pragma("unroll") for (int t = 0; t < 4; ++t) {                            \
      fa[t] = *(const sv8*)&Ah[cur][wm * 64 + t * 16 + fr][kg];                \
      fb[t] = *(const sv8*)&Bh[cur][wn * 64 + t * 16 + fr][kg];                \
    }                                                                          \
    _Pragma("unroll") for (int mt = 0; mt < 4; ++mt)                           \
      _Pragma("unroll") for (int nt = 0; nt < 4; ++nt)                         \
        acc[mt][nt] = mfma16(fa[mt], fb[nt], acc[mt][nt]);                     \
    _Pragma("unroll") for (int t = 0; t < 4; ++t)                              \
      fa[t] = *(const sv8*)&Al[cur][wm * 64 + t * 16 + fr][kg];                \
    _Pragma("unroll") for (int mt = 0; mt < 4; ++mt)                           \
      _Pragma("unroll") for (int nt = 0; nt < 4; ++nt)                         \
        acc[mt][nt] = mfma16(fa[mt], fb[nt], acc[mt][nt]);                     \
    __syncthreads();                                                           \
    cur ^= 1;                                                                  \
  }

__global__ __launch_bounds__(256) void gemm_pre_qkv(
    const short* __restrict__ A2, const short* __restrict__ B2,
    const float* __restrict__ bias, float* __restrict__ Qb,
    float* __restrict__ Kb, float* __restrict__ Vb) {
  GEMM_PRE_BODY(6)
  float* dst = (nti < 2) ? Qb : ((nti < 4) ? Kb : Vb);
  const int r0 = (l >> 4) * 4;
#pragma unroll
  for (int mt = 0; mt < 4; ++mt)
#pragma unroll
    for (int nt = 0; nt < 4; ++nt) {
      const int n = n0 + wn * 64 + nt * 16 + fr;
      const float bv = bias[n];
      const int nn = n & 255;
      const size_t mb = (size_t)(m0 + wm * 64 + mt * 16 + r0);
#pragma unroll
      for (int j = 0; j < 4; ++j) dst[(mb + j) * 256 + nn] = acc[mt][nt][j] + bv;
    }
}

__global__ __launch_bounds__(256) void gemm_pre_out(
    const short* __restrict__ A2, const short* __restrict__ B2,
    const float* __restrict__ bias, float* __restrict__ C) {
  GEMM_PRE_BODY(2)
  const int r0 = (l >> 4) * 4;
#pragma unroll
  for (int mt = 0; mt < 4; ++mt)
#pragma unroll
    for (int nt = 0; nt < 4; ++nt) {
      const int n = n0 + wn * 64 + nt * 16 + fr;
      const float bv = bias[n];
      const size_t mb = (size_t)(m0 + wm * 64 + mt * 16 + r0);
#pragma unroll
      for (int j = 0; j < 4; ++j) C[(mb + j) * 256 + n] = acc[mt][nt][j] + bv;
    }
}

// ---- fallback on-the-fly-split GEMMs (proven round 4) ----
__global__ __launch_bounds__(256) void gemm_qkv(
    const float* __restrict__ X, const float* __restrict__ W,
    const float* __restrict__ bias, float* __restrict__ Qb,
    float* __restrict__ Kb, float* __restrict__ Vb) {
  const int tid = threadIdx.x, w = tid >> 6, l = tid & 63;
  const int wm = w >> 1, wn = w & 1;
  const int m0 = blockIdx.x * 128, n0 = blockIdx.y * 128;
  const int fr = l & 15, kg = (l >> 4) * 8;
  f4 acc[4][4] = {};
  for (int s = 0; s < 8; ++s) {
    const int k0 = s * 32 + kg;
    sv8 ah[4], al[4], bh[4], bl[4];
#pragma unroll
    for (int t = 0; t < 4; ++t) {
      split8(X + (size_t)(m0 + wm * 64 + t * 16 + fr) * 256 + k0, ah[t], al[t]);
      split8(W + (size_t)(n0 + wn * 64 + t * 16 + fr) * 256 + k0, bh[t], bl[t]);
    }
#pragma unroll
    for (int mt = 0; mt < 4; ++mt)
#pragma unroll
      for (int nt = 0; nt < 4; ++nt) {
        f4 a0 = acc[mt][nt];
        a0 = mfma16(ah[mt], bh[nt], a0);
        a0 = mfma16(al[mt], bh[nt], a0);
        a0 = mfma16(ah[mt], bl[nt], a0);
        acc[mt][nt] = a0;
      }
  }
  float* dst = (blockIdx.y < 2) ? Qb : ((blockIdx.y < 4) ? Kb : Vb);
  const int r0 = (l >> 4) * 4;
#pragma unroll
  for (int mt = 0; mt < 4; ++mt)
#pragma unroll
    for (int nt = 0; nt < 4; ++nt) {
      const int n = n0 + wn * 64 + nt * 16 + fr;
      const float bv = bias[n];
      const int nn = n & 255;
      const size_t mb = (size_t)(m0 + wm * 64 + mt * 16 + r0);
#pragma unroll
      for (int j = 0; j < 4; ++j) dst[(mb + j) * 256 + nn] = acc[mt][nt][j] + bv;
    }
}

__global__ __launch_bounds__(256) void gemm_out(
    const short* __restrict__ A2, const float* __restrict__ W,
    const float* __restrict__ bias, float* __restrict__ C) {
  const int tid = threadIdx.x, w = tid >> 6, l = tid & 63;
  const int wm = w >> 1, wn = w & 1;
  const int m0 = blockIdx.x * 128, n0 = blockIdx.y * 128;
  const int fr = l & 15, kg = (l >> 4) * 8;
  f4 acc[4][4] = {};
  for (int s = 0; s < 8; ++s) {
    const int k0 = s * 32 + kg;
    sv8 ah[4], al[4], bh[4], bl[4];
#pragma unroll
    for (int t = 0; t < 4; ++t) {
      const short* ap = A2 + (size_t)(m0 + wm * 64 + t * 16 + fr) * 512 + k0;
      ah[t] = *(const sv8*)ap;
      al[t] = *(const sv8*)(ap + 256);
      split8(W + (size_t)(n0 + wn * 64 + t * 16 + fr) * 256 + k0, bh[t], bl[t]);
    }
#pragma unroll
    for (int mt = 0; mt < 4; ++mt)
#pragma unroll
      for (int nt = 0; nt < 4; ++nt) {
        f4 a0 = acc[mt][nt];
        a0 = mfma16(ah[mt], bh[nt], a0);
        a0 = mfma16(al[mt], bh[nt], a0);
        a0 = mfma16(ah[mt], bl[nt], a0);
        acc[mt][nt] = a0;
      }
  }
  const int r0 = (l >> 4) * 4;
#pragma unroll
  for (int mt = 0; mt < 4; ++mt)
#pragma unroll
    for (int nt = 0; nt < 4; ++nt) {
      const int n = n0 + wn * 64 + nt * 16 + fr;
      const float bv = bias[n];
      const size_t mb = (size_t)(m0 + wm * 64 + mt * 16 + r0);
#pragma unroll
      for (int j = 0; j < 4; ++j) C[(mb + j) * 256 + n] = acc[mt][nt][j] + bv;
    }
}

// LDS pointer with per-row XOR swizzle (float index d at byte 4d ^ ((d>>5&7)<<4));
// bijective per 1 KiB row; kills the fixed-h 8-way read conflict.
__device__ __forceinline__ float* ldsP(float* base, int row, int d) {
  return (float*)((char*)base + row * 1024 + ((4 * d) ^ (((d >> 5) & 7) << 4)));
}

// One block per (b, nb). ONE barrier. Block-node (kc=16) folded analytically:
// dot(q,k16) = mean_t dot(q,K[t]);  comb16*V16 = sum_t (comb16/16)*V[t].
// efeat/mask staged coalesced into LDS. Output hi|lo overlays the Q buffer.
__global__ __launch_bounds__(256, 4) void attn_v4(
    const float* __restrict__ Qb, const float* __restrict__ Kb,
    const float* __restrict__ Vb, const int* __restrict__ amask,
    const float* __restrict__ efeat, const float* __restrict__ Wgate,
    const float* __restrict__ bgate, short* __restrict__ AO2) {
  __shared__ float Ks[16 * 256];   // swizzled, 16 KiB
  __shared__ float Vs[16 * 256];   // swizzled, 16 KiB
  __shared__ float4 Es[LQ * KCNT]; // edge feats, 4.25 KiB
  __shared__ int Ms[LQ * KCNT];    // mask, 1.06 KiB

  const int tid = threadIdx.x, g = blockIdx.x;
  const int b = g >> 11, nb = g & (NB - 1);
  const size_t tok0 = (size_t)(b * N_SEQ + nb * LQ);

  // stage 16 leaf K,V rows (coalesced float4 -> swizzled LDS)
#pragma unroll
  for (int i = 0; i < 4; ++i) {
    const int f = tid + i * 256;
    const int t = f >> 6, c4 = (f & 63) * 4;
    *(float4*)ldsP(Ks, t, c4) = *(const float4*)(Kb + (tok0 + t) * 256 + c4);
    *(float4*)ldsP(Vs, t, c4) = *(const float4*)(Vb + (tok0 + t) * 256 + c4);
  }
  // stage efeat (272 float4) and mask (272 int), coalesced
  {
    const float4* esrc = (const float4*)(efeat + (size_t)nb * LQ * KCNT * 4);
    const int* msrc = amask + (size_t)nb * LQ * KCNT;
    Es[tid] = esrc[tid];
    Ms[tid] = msrc[tid];
    if (tid < LQ * KCNT - 256) {
      Es[256 + tid] = esrc[256 + tid];
      Ms[256 + tid] = msrc[256 + tid];
    }
  }
  __syncthreads();

  // fused phase: thread (q = tid>>4, h = (tid>>1)&7, half = tid&1)
  const int q = tid >> 4, h = (tid >> 1) & 7, half = tid & 1;
  const int d0 = h * HD + half * 16;

  float qh[16];
  {
    const float* qp = Qb + (tok0 + q) * 256 + d0;
#pragma unroll
    for (int j = 0; j < 4; ++j) {
      float4 v = *(const float4*)(qp + j * 4);
      qh[j * 4] = v.x; qh[j * 4 + 1] = v.y;
      qh[j * 4 + 2] = v.z; qh[j * 4 + 3] = v.w;
    }
  }
  const float wg0 = Wgate[h * 4], wg1 = Wgate[h * 4 + 1];
  const float wg2 = Wgate[h * 4 + 2], wg3 = Wgate[h * 4 + 3];
  const float bg = bgate[h];

  float sc[16], gt[16];
  float rawsum = 0.f;
  unsigned vis = 0;
  float mx = -1e30f;
#pragma unroll
  for (int kc = 0; kc < 16; ++kc) {
    float dot = 0.f;
#pragma unroll
    for (int j = 0; j < 4; ++j) {
      float4 kv = *(const float4*)ldsP(Ks, kc, d0 + j * 4);
      dot += qh[j * 4] * kv.x + qh[j * 4 + 1] * kv.y +
             qh[j * 4 + 2] * kv.z + qh[j * 4 + 3] * kv.w;
    }
    dot += __shfl_xor(dot, 1);  // combine the two 16-dim halves
    rawsum += dot;
    float e0, e1, e2, e3;
    if (kc == q) { e0 = e1 = e2 = 0.f; e3 = 1.f; }
    else { float4 e = Es[q * KCNT + kc]; e0 = e.x; e1 = e.y; e2 = e.z; e3 = e.w; }
    const int m = Ms[q * KCNT + kc];
    const float s = dot * SCALE_F + e3;
    sc[kc] = s;
    if (m) { vis |= (1u << kc); mx = fmaxf(mx, s); }
    gt[kc] = m ? (e0 * wg0 + e1 * wg1 + e2 * wg2 + e3 * wg3 + bg) : 0.f;
  }
  // block-node column (kc=16): e = unit, k16 = mean of leaf k rows
  const float s16 = rawsum * 0.0625f * SCALE_F + 1.0f;
  const int m16 = Ms[q * KCNT + 16];
  const float gt16 = m16 ? (wg3 + bg) : 0.f;
  if (m16) mx = fmaxf(mx, s16);

  float den = 0.f;
#pragma unroll
  for (int kc = 0; kc < 16; ++kc) {
    const float pv = (vis & (1u << kc)) ? __expf(sc[kc] - mx) : 0.f;
    sc[kc] = pv;
    den += pv;
  }
  const float p16 = m16 ? __expf(s16 - mx) : 0.f;
  den += p16;
  const float inv = 1.f / den;
  const float cb16 = (p16 * inv + gt16) * 0.0625f;  // folded into leaf coefs
#pragma unroll
  for (int kc = 0; kc < 16; ++kc) sc[kc] = sc[kc] * inv + gt[kc] + cb16;

  float o[16] = {};
#pragma unroll
  for (int kc = 0; kc < 16; ++kc) {
    const float c = sc[kc];
#pragma unroll
    for (int j = 0; j < 4; ++j) {
      float4 vv = *(const float4*)ldsP(Vs, kc, d0 + j * 4);
      o[j * 4] += c * vv.x;
      o[j * 4 + 1] += c * vv.y;
      o[j * 4 + 2] += c * vv.z;
      o[j * 4 + 3] += c * vv.w;
    }
  }
  // hi|lo bf16 output overlays the Q buffer; writers == readers of row tok0+q
  // (same wave, reads precede writes in program order) -> race-free.
  short* ao = AO2 + (tok0 + q) * 512 + d0;
  sv8 hi, lo;
#pragma unroll
  for (int e = 0; e < 8; ++e) {
    const short hb = f2bf(o[e]);
    hi[e] = hb;
    lo[e] = f2bf(o[e] - bf2f(hb));
  }
  *(sv8*)ao = hi;
  *(sv8*)&ao[256] = lo;
#pragma unroll
  for (int e = 0; e < 8; ++e) {
    const short hb = f2bf(o[8 + e]);
    hi[e] = hb;
    lo[e] = f2bf(o[8 + e] - bf2f(hb));
  }
  *(sv8*)&ao[8] = hi;
  *(sv8*)&ao[264] = lo;
}

extern "C" void kernel_launch(void* const* d_in, const int* in_sizes, int n_in,
                              void* d_out, int out_size, void* d_ws, size_t ws_size,
                              hipStream_t stream) {
  const float* x = (const float*)d_in[0];
  const int* amask = (const int*)d_in[1];
  const float* efeat = (const float*)d_in[2];
  const float* Wqkv = (const float*)d_in[3];
  const float* bqkv = (const float*)d_in[4];
  const float* Wproj = (const float*)d_in[5];
  const float* bproj = (const float*)d_in[6];
  const float* Wgate = (const float*)d_in[7];
  const float* bgate = (const float*)d_in[8];
  float* out = (float*)d_out;

  char* ws = (char*)d_ws;
  const size_t QSZ = (size_t)M_ROWS * 256 * 4;  // 64 MiB
  const size_t W2Q_SZ = (size_t)768 * 512 * 2;
  const size_t W2P_SZ = (size_t)256 * 512 * 2;

  if (ws_size >= 3 * QSZ + W2Q_SZ + W2P_SZ) {
    short* X2 = (short*)ws;
    float* Qb = (float*)(ws + QSZ);
    float* Kb = (float*)(ws + 2 * QSZ);
    short* W2Q = (short*)(ws + 3 * QSZ);
    short* W2P = (short*)(ws + 3 * QSZ + W2Q_SZ);
    float* Vb = out;
    split256<<<dim3(M_ROWS * 64 / 256), 256, 0, stream>>>(x, X2, M_ROWS * 64);
    split256<<<dim3(768 * 64 / 256), 256, 0, stream>>>(Wqkv, W2Q, 768 * 64);
    split256<<<dim3(256 * 64 / 256), 256, 0, stream>>>(Wproj, W2P, 256 * 64);
    gemm_pre_qkv<<<dim3(6 * 512), 256, 0, stream>>>(X2, W2Q, bqkv, Qb, Kb, Vb);
    attn_v4<<<dim3(B_SZ * NB), 256, 0, stream>>>(Qb, Kb, Vb, amask, efeat,
                                                 Wgate, bgate, (short*)Qb);
    gemm_pre_out<<<dim3(2 * 512), 256, 0, stream>>>((const short*)Qb, W2P,
                                                    bproj, out);
  } else {
    if (ws_size < 2 * QSZ) return;
    float* Qb = (float*)ws;
    float* Kb = (float*)(ws + QSZ);
    float* Vb = out;
    gemm_qkv<<<dim3(M_ROWS / 128, 6), 256, 0, stream>>>(x, Wqkv, bqkv, Qb, Kb, Vb);
    attn_v4<<<dim3(B_SZ * NB), 256, 0, stream>>>(Qb, Kb, Vb, amask, efeat,
                                                 Wgate, bgate, (short*)Qb);
    gemm_out<<<dim3(M_ROWS / 128, 2), 256, 0, stream>>>((const short*)Qb, Wproj,
                                                        bproj, out);
  }
}

// Round 11
// 232.229 us; speedup vs baseline: 1.3377x; 1.0033x over previous
//
#include <hip/hip_runtime.h>
#include <cstdint>
#include <cstddef>

#define B_SZ 2
#define N_SEQ 32768
#define NB 2048
#define HD 32
#define LQ 16
#define KCNT 17
#define M_ROWS 65536
#define SCALE_F 0.17677669529663687f /* 32^-0.5 */

typedef __attribute__((ext_vector_type(8))) short sv8;
typedef __attribute__((ext_vector_type(4))) short sv4;
typedef __attribute__((ext_vector_type(4))) float f4;

__device__ __forceinline__ short f2bf(float f) {
  unsigned u = __builtin_bit_cast(unsigned, f);
  u = (u + 0x7FFFu + ((u >> 16) & 1u)) >> 16;
  return (short)u;
}
__device__ __forceinline__ float bf2f(short s) {
  unsigned u = ((unsigned)(unsigned short)s) << 16;
  return __builtin_bit_cast(float, u);
}
__device__ __forceinline__ void split8(const float* __restrict__ p, sv8& hi, sv8& lo) {
  float4 f0 = *(const float4*)p, f1 = *(const float4*)(p + 4);
  float fv[8] = {f0.x, f0.y, f0.z, f0.w, f1.x, f1.y, f1.z, f1.w};
#pragma unroll
  for (int j = 0; j < 8; ++j) {
    short h = f2bf(fv[j]);
    hi[j] = h;
    lo[j] = f2bf(fv[j] - bf2f(h));
  }
}
__device__ __forceinline__ void gload16(const void* g, void* l) {
  __builtin_amdgcn_global_load_lds(
      (const __attribute__((address_space(1))) unsigned int*)g,
      (__attribute__((address_space(3))) unsigned int*)l, 16, 0, 0);
}
__device__ __forceinline__ f4 mfma16(sv8 a, sv8 b, f4 c) {
  return __builtin_amdgcn_mfma_f32_16x16x32_bf16(a, b, c, 0, 0, 0);
}

// fp32 [rows][256] -> bf16 hi|lo [rows][512]
__global__ __launch_bounds__(256) void split256(const float* __restrict__ src,
                                                short* __restrict__ dst, int n4) {
  int i = blockIdx.x * 256 + threadIdx.x;
  if (i >= n4) return;
  float4 v = ((const float4*)src)[i];
  size_t row = (size_t)(i >> 6);
  int c = (i & 63) * 4;
  float fv[4] = {v.x, v.y, v.z, v.w};
  sv4 hi, lo;
#pragma unroll
  for (int j = 0; j < 4; ++j) {
    short h = f2bf(fv[j]);
    hi[j] = h;
    lo[j] = f2bf(fv[j] - bf2f(h));
  }
  *(sv4*)&dst[row * 512 + c] = hi;
  *(sv4*)&dst[row * 512 + 256 + c] = lo;
}

// ---- pre-split GEMM, 2-term (C = (Ah+Al)*Bh), k-chunked + double-buffered
// with COUNTED vmcnt + raw s_barrier (T4): prefetch for chunk s+1 stays in
// flight across the barrier; vmcnt(6) waits only the 6 oldest loads (chunk s).
// RAW: vmcnt+B1 (all waves' loads landed). WAR: B2 of previous chunk orders
// all reads of buf[cur^1] before this chunk's prefetch-issue into it.
// Bijective XCD-chunked 1-D grid swizzle (verified FETCH 304->36 MB).
#define GEMM_PRE_BODY(NT)                                                      \
  __shared__ __align__(16) short Ah[2][128][32];                               \
  __shared__ __align__(16) short Al[2][128][32];                               \
  __shared__ __align__(16) short Bh[2][128][32];                               \
  const int tid = threadIdx.x;                                                 \
  const int w = tid >> 6, l = tid & 63;                                        \
  const int wm = w >> 1, wn = w & 1;                                           \
  const int bid = blockIdx.x;                                                  \
  const int chunk = (NT * 512) >> 3;                                           \
  const int lbid = (bid & 7) * chunk + (bid >> 3);                             \
  const int nti = lbid % (NT), mti = lbid / (NT);                              \
  const int m0 = mti * 128, n0 = nti * 128;                                    \
  const int lr = l >> 2;                                                       \
  const int lc = (l & 3) * 8;                                                  \
  const int fr = l & 15, kg = (l >> 4) * 8;                                    \
  f4 acc[4][4] = {};                                                           \
  _Pragma("unroll") for (int i = 0; i < 2; ++i) {                              \
    const int row = w * 32 + i * 16;                                           \
    const size_t ra = (size_t)(m0 + row + lr) * 512 + lc;                      \
    const size_t rb = (size_t)(n0 + row + lr) * 512 + lc;                      \
    gload16(A2 + ra, (void*)&Ah[0][row][0]);                                   \
    gload16(A2 + ra + 256, (void*)&Al[0][row][0]);                             \
    gload16(B2 + rb, (void*)&Bh[0][row][0]);                                   \
  }                                                                            \
  asm volatile("s_waitcnt vmcnt(0)" ::: "memory");                             \
  __builtin_amdgcn_s_barrier();                                                \
  int cur = 0;                                                                 \
  for (int s = 0; s < 8; ++s) {                                                \
    if (s < 7) {                                                               \
      const int sk = (s + 1) * 32;                                             \
      _Pragma("unroll") for (int i = 0; i < 2; ++i) {                          \
        const int row = w * 32 + i * 16;                                       \
        const size_t ra = (size_t)(m0 + row + lr) * 512 + sk + lc;             \
        const size_t rb = (size_t)(n0 + row + lr) * 512 + sk + lc;             \
        gload16(A2 + ra, (void*)&Ah[cur ^ 1][row][0]);                         \
        gload16(A2 + ra + 256, (void*)&Al[cur ^ 1][row][0]);                   \
        gload16(B2 + rb, (void*)&Bh[cur ^ 1][row][0]);                         \
      }                                                                        \
    }                                                                          \
    if (s > 0) {                                                               \
      if (s < 7) asm volatile("s_waitcnt vmcnt(6)" ::: "memory");              \
      else asm volatile("s_waitcnt vmcnt(0)" ::: "memory");                    \
      __builtin_amdgcn_s_barrier();                                            \
    }                                                                          \
    sv8 fa[4], fb[4];                                                          \
    _Pragma("unroll") for (int t = 0; t < 4; ++t) {                            \
      fa[t] = *(const sv8*)&Ah[cur][wm * 64 + t * 16 + fr][kg];                \
      fb[t] = *(const sv8*)&Bh[cur][wn * 64 + t * 16 + fr][kg];                \
    }                                                                          \
    _Pragma("unroll") for (int mt = 0; mt < 4; ++mt)                           \
      _Pragma("unroll") for (int nt = 0; nt < 4; ++nt)                         \
        acc[mt][nt] = mfma16(fa[mt], fb[nt], acc[mt][nt]);                     \
    _Pragma("unroll") for (int t = 0; t < 4; ++t)                              \
      fa[t] = *(const sv8*)&Al[cur][wm * 64 + t * 16 + fr][kg];                \
    _Pragma("unroll") for (int mt = 0; mt < 4; ++mt)                           \
      _Pragma("unroll") for (int nt = 0; nt < 4; ++nt)                         \
        acc[mt][nt] = mfma16(fa[mt], fb[nt], acc[mt][nt]);                     \
    asm volatile("s_waitcnt lgkmcnt(0)" ::: "memory");                         \
    __builtin_amdgcn_s_barrier();                                              \
    cur ^= 1;                                                                  \
  }

__global__ __launch_bounds__(256) void gemm_pre_qkv(
    const short* __restrict__ A2, const short* __restrict__ B2,
    const float* __restrict__ bias, float* __restrict__ Qb,
    float* __restrict__ Kb, float* __restrict__ Vb) {
  GEMM_PRE_BODY(6)
  float* dst = (nti < 2) ? Qb : ((nti < 4) ? Kb : Vb);
  const int r0 = (l >> 4) * 4;
#pragma unroll
  for (int mt = 0; mt < 4; ++mt)
#pragma unroll
    for (int nt = 0; nt < 4; ++nt) {
      const int n = n0 + wn * 64 + nt * 16 + fr;
      const float bv = bias[n];
      const int nn = n & 255;
      const size_t mb = (size_t)(m0 + wm * 64 + mt * 16 + r0);
#pragma unroll
      for (int j = 0; j < 4; ++j) dst[(mb + j) * 256 + nn] = acc[mt][nt][j] + bv;
    }
}

__global__ __launch_bounds__(256) void gemm_pre_out(
    const short* __restrict__ A2, const short* __restrict__ B2,
    const float* __restrict__ bias, float* __restrict__ C) {
  GEMM_PRE_BODY(2)
  const int r0 = (l >> 4) * 4;
#pragma unroll
  for (int mt = 0; mt < 4; ++mt)
#pragma unroll
    for (int nt = 0; nt < 4; ++nt) {
      const int n = n0 + wn * 64 + nt * 16 + fr;
      const float bv = bias[n];
      const size_t mb = (size_t)(m0 + wm * 64 + mt * 16 + r0);
#pragma unroll
      for (int j = 0; j < 4; ++j) C[(mb + j) * 256 + n] = acc[mt][nt][j] + bv;
    }
}

// ---- fallback on-the-fly-split GEMMs (proven round 4) ----
__global__ __launch_bounds__(256) void gemm_qkv(
    const float* __restrict__ X, const float* __restrict__ W,
    const float* __restrict__ bias, float* __restrict__ Qb,
    float* __restrict__ Kb, float* __restrict__ Vb) {
  const int tid = threadIdx.x, w = tid >> 6, l = tid & 63;
  const int wm = w >> 1, wn = w & 1;
  const int m0 = blockIdx.x * 128, n0 = blockIdx.y * 128;
  const int fr = l & 15, kg = (l >> 4) * 8;
  f4 acc[4][4] = {};
  for (int s = 0; s < 8; ++s) {
    const int k0 = s * 32 + kg;
    sv8 ah[4], al[4], bh[4], bl[4];
#pragma unroll
    for (int t = 0; t < 4; ++t) {
      split8(X + (size_t)(m0 + wm * 64 + t * 16 + fr) * 256 + k0, ah[t], al[t]);
      split8(W + (size_t)(n0 + wn * 64 + t * 16 + fr) * 256 + k0, bh[t], bl[t]);
    }
#pragma unroll
    for (int mt = 0; mt < 4; ++mt)
#pragma unroll
      for (int nt = 0; nt < 4; ++nt) {
        f4 a0 = acc[mt][nt];
        a0 = mfma16(ah[mt], bh[nt], a0);
        a0 = mfma16(al[mt], bh[nt], a0);
        a0 = mfma16(ah[mt], bl[nt], a0);
        acc[mt][nt] = a0;
      }
  }
  float* dst = (blockIdx.y < 2) ? Qb : ((blockIdx.y < 4) ? Kb : Vb);
  const int r0 = (l >> 4) * 4;
#pragma unroll
  for (int mt = 0; mt < 4; ++mt)
#pragma unroll
    for (int nt = 0; nt < 4; ++nt) {
      const int n = n0 + wn * 64 + nt * 16 + fr;
      const float bv = bias[n];
      const int nn = n & 255;
      const size_t mb = (size_t)(m0 + wm * 64 + mt * 16 + r0);
#pragma unroll
      for (int j = 0; j < 4; ++j) dst[(mb + j) * 256 + nn] = acc[mt][nt][j] + bv;
    }
}

__global__ __launch_bounds__(256) void gemm_out(
    const short* __restrict__ A2, const float* __restrict__ W,
    const float* __restrict__ bias, float* __restrict__ C) {
  const int tid = threadIdx.x, w = tid >> 6, l = tid & 63;
  const int wm = w >> 1, wn = w & 1;
  const int m0 = blockIdx.x * 128, n0 = blockIdx.y * 128;
  const int fr = l & 15, kg = (l >> 4) * 8;
  f4 acc[4][4] = {};
  for (int s = 0; s < 8; ++s) {
    const int k0 = s * 32 + kg;
    sv8 ah[4], al[4], bh[4], bl[4];
#pragma unroll
    for (int t = 0; t < 4; ++t) {
      const short* ap = A2 + (size_t)(m0 + wm * 64 + t * 16 + fr) * 512 + k0;
      ah[t] = *(const sv8*)ap;
      al[t] = *(const sv8*)(ap + 256);
      split8(W + (size_t)(n0 + wn * 64 + t * 16 + fr) * 256 + k0, bh[t], bl[t]);
    }
#pragma unroll
    for (int mt = 0; mt < 4; ++mt)
#pragma unroll
      for (int nt = 0; nt < 4; ++nt) {
        f4 a0 = acc[mt][nt];
        a0 = mfma16(ah[mt], bh[nt], a0);
        a0 = mfma16(al[mt], bh[nt], a0);
        a0 = mfma16(ah[mt], bl[nt], a0);
        acc[mt][nt] = a0;
      }
  }
  const int r0 = (l >> 4) * 4;
#pragma unroll
  for (int mt = 0; mt < 4; ++mt)
#pragma unroll
    for (int nt = 0; nt < 4; ++nt) {
      const int n = n0 + wn * 64 + nt * 16 + fr;
      const float bv = bias[n];
      const size_t mb = (size_t)(m0 + wm * 64 + mt * 16 + r0);
#pragma unroll
      for (int j = 0; j < 4; ++j) C[(mb + j) * 256 + n] = acc[mt][nt][j] + bv;
    }
}

// LDS pointer with per-row XOR swizzle (float index d at byte 4d ^ ((d>>5&7)<<4));
// bijective per 1 KiB row; kills the fixed-h 8-way read conflict.
__device__ __forceinline__ float* ldsP(float* base, int row, int d) {
  return (float*)((char*)base + row * 1024 + ((4 * d) ^ (((d >> 5) & 7) << 4)));
}

// One block per (b, nb). ONE barrier. Block-node (kc=16) folded analytically:
// dot(q,k16) = mean_t dot(q,K[t]);  comb16*V16 = sum_t (comb16/16)*V[t].
// efeat/mask staged coalesced into LDS. Output hi|lo overlays the Q buffer.
__global__ __launch_bounds__(256, 4) void attn_v4(
    const float* __restrict__ Qb, const float* __restrict__ Kb,
    const float* __restrict__ Vb, const int* __restrict__ amask,
    const float* __restrict__ efeat, const float* __restrict__ Wgate,
    const float* __restrict__ bgate, short* __restrict__ AO2) {
  __shared__ float Ks[16 * 256];   // swizzled, 16 KiB
  __shared__ float Vs[16 * 256];   // swizzled, 16 KiB
  __shared__ float4 Es[LQ * KCNT]; // edge feats, 4.25 KiB
  __shared__ int Ms[LQ * KCNT];    // mask, 1.06 KiB

  const int tid = threadIdx.x, g = blockIdx.x;
  const int b = g >> 11, nb = g & (NB - 1);
  const size_t tok0 = (size_t)(b * N_SEQ + nb * LQ);

  // stage 16 leaf K,V rows (coalesced float4 -> swizzled LDS)
#pragma unroll
  for (int i = 0; i < 4; ++i) {
    const int f = tid + i * 256;
    const int t = f >> 6, c4 = (f & 63) * 4;
    *(float4*)ldsP(Ks, t, c4) = *(const float4*)(Kb + (tok0 + t) * 256 + c4);
    *(float4*)ldsP(Vs, t, c4) = *(const float4*)(Vb + (tok0 + t) * 256 + c4);
  }
  // stage efeat (272 float4) and mask (272 int), coalesced
  {
    const float4* esrc = (const float4*)(efeat + (size_t)nb * LQ * KCNT * 4);
    const int* msrc = amask + (size_t)nb * LQ * KCNT;
    Es[tid] = esrc[tid];
    Ms[tid] = msrc[tid];
    if (tid < LQ * KCNT - 256) {
      Es[256 + tid] = esrc[256 + tid];
      Ms[256 + tid] = msrc[256 + tid];
    }
  }
  __syncthreads();

  // fused phase: thread (q = tid>>4, h = (tid>>1)&7, half = tid&1)
  const int q = tid >> 4, h = (tid >> 1) & 7, half = tid & 1;
  const int d0 = h * HD + half * 16;

  float qh[16];
  {
    const float* qp = Qb + (tok0 + q) * 256 + d0;
#pragma unroll
    for (int j = 0; j < 4; ++j) {
      float4 v = *(const float4*)(qp + j * 4);
      qh[j * 4] = v.x; qh[j * 4 + 1] = v.y;
      qh[j * 4 + 2] = v.z; qh[j * 4 + 3] = v.w;
    }
  }
  const float wg0 = Wgate[h * 4], wg1 = Wgate[h * 4 + 1];
  const float wg2 = Wgate[h * 4 + 2], wg3 = Wgate[h * 4 + 3];
  const float bg = bgate[h];

  float sc[16], gt[16];
  float rawsum = 0.f;
  unsigned vis = 0;
  float mx = -1e30f;
#pragma unroll
  for (int kc = 0; kc < 16; ++kc) {
    float dot = 0.f;
#pragma unroll
    for (int j = 0; j < 4; ++j) {
      float4 kv = *(const float4*)ldsP(Ks, kc, d0 + j * 4);
      dot += qh[j * 4] * kv.x + qh[j * 4 + 1] * kv.y +
             qh[j * 4 + 2] * kv.z + qh[j * 4 + 3] * kv.w;
    }
    dot += __shfl_xor(dot, 1);  // combine the two 16-dim halves
    rawsum += dot;
    float e0, e1, e2, e3;
    if (kc == q) { e0 = e1 = e2 = 0.f; e3 = 1.f; }
    else { float4 e = Es[q * KCNT + kc]; e0 = e.x; e1 = e.y; e2 = e.z; e3 = e.w; }
    const int m = Ms[q * KCNT + kc];
    const float s = dot * SCALE_F + e3;
    sc[kc] = s;
    if (m) { vis |= (1u << kc); mx = fmaxf(mx, s); }
    gt[kc] = m ? (e0 * wg0 + e1 * wg1 + e2 * wg2 + e3 * wg3 + bg) : 0.f;
  }
  // block-node column (kc=16): e = unit, k16 = mean of leaf k rows
  const float s16 = rawsum * 0.0625f * SCALE_F + 1.0f;
  const int m16 = Ms[q * KCNT + 16];
  const float gt16 = m16 ? (wg3 + bg) : 0.f;
  if (m16) mx = fmaxf(mx, s16);

  float den = 0.f;
#pragma unroll
  for (int kc = 0; kc < 16; ++kc) {
    const float pv = (vis & (1u << kc)) ? __expf(sc[kc] - mx) : 0.f;
    sc[kc] = pv;
    den += pv;
  }
  const float p16 = m16 ? __expf(s16 - mx) : 0.f;
  den += p16;
  const float inv = 1.f / den;
  const float cb16 = (p16 * inv + gt16) * 0.0625f;  // folded into leaf coefs
#pragma unroll
  for (int kc = 0; kc < 16; ++kc) sc[kc] = sc[kc] * inv + gt[kc] + cb16;

  float o[16] = {};
#pragma unroll
  for (int kc = 0; kc < 16; ++kc) {
    const float c = sc[kc];
#pragma unroll
    for (int j = 0; j < 4; ++j) {
      float4 vv = *(const float4*)ldsP(Vs, kc, d0 + j * 4);
      o[j * 4] += c * vv.x;
      o[j * 4 + 1] += c * vv.y;
      o[j * 4 + 2] += c * vv.z;
      o[j * 4 + 3] += c * vv.w;
    }
  }
  // hi|lo bf16 output overlays the Q buffer; writers == readers of row tok0+q
  // (same wave, reads precede writes in program order) -> race-free.
  short* ao = AO2 + (tok0 + q) * 512 + d0;
  sv8 hi, lo;
#pragma unroll
  for (int e = 0; e < 8; ++e) {
    const short hb = f2bf(o[e]);
    hi[e] = hb;
    lo[e] = f2bf(o[e] - bf2f(hb));
  }
  *(sv8*)ao = hi;
  *(sv8*)&ao[256] = lo;
#pragma unroll
  for (int e = 0; e < 8; ++e) {
    const short hb = f2bf(o[8 + e]);
    hi[e] = hb;
    lo[e] = f2bf(o[8 + e] - bf2f(hb));
  }
  *(sv8*)&ao[8] = hi;
  *(sv8*)&ao[264] = lo;
}

extern "C" void kernel_launch(void* const* d_in, const int* in_sizes, int n_in,
                              void* d_out, int out_size, void* d_ws, size_t ws_size,
                              hipStream_t stream) {
  const float* x = (const float*)d_in[0];
  const int* amask = (const int*)d_in[1];
  const float* efeat = (const float*)d_in[2];
  const float* Wqkv = (const float*)d_in[3];
  const float* bqkv = (const float*)d_in[4];
  const float* Wproj = (const float*)d_in[5];
  const float* bproj = (const float*)d_in[6];
  const float* Wgate = (const float*)d_in[7];
  const float* bgate = (const float*)d_in[8];
  float* out = (float*)d_out;

  char* ws = (char*)d_ws;
  const size_t QSZ = (size_t)M_ROWS * 256 * 4;  // 64 MiB
  const size_t W2Q_SZ = (size_t)768 * 512 * 2;
  const size_t W2P_SZ = (size_t)256 * 512 * 2;

  if (ws_size >= 3 * QSZ + W2Q_SZ + W2P_SZ) {
    short* X2 = (short*)ws;
    float* Qb = (float*)(ws + QSZ);
    float* Kb = (float*)(ws + 2 * QSZ);
    short* W2Q = (short*)(ws + 3 * QSZ);
    short* W2P = (short*)(ws + 3 * QSZ + W2Q_SZ);
    float* Vb = out;
    split256<<<dim3(M_ROWS * 64 / 256), 256, 0, stream>>>(x, X2, M_ROWS * 64);
    split256<<<dim3(768 * 64 / 256), 256, 0, stream>>>(Wqkv, W2Q, 768 * 64);
    split256<<<dim3(256 * 64 / 256), 256, 0, stream>>>(Wproj, W2P, 256 * 64);
    gemm_pre_qkv<<<dim3(6 * 512), 256, 0, stream>>>(X2, W2Q, bqkv, Qb, Kb, Vb);
    attn_v4<<<dim3(B_SZ * NB), 256, 0, stream>>>(Qb, Kb, Vb, amask, efeat,
                                                 Wgate, bgate, (short*)Qb);
    gemm_pre_out<<<dim3(2 * 512), 256, 0, stream>>>((const short*)Qb, W2P,
                                                    bproj, out);
  } else {
    if (ws_size < 2 * QSZ) return;
    float* Qb = (float*)ws;
    float* Kb = (float*)(ws + QSZ);
    float* Vb = out;
    gemm_qkv<<<dim3(M_ROWS / 128, 6), 256, 0, stream>>>(x, Wqkv, bqkv, Qb, Kb, Vb);
    attn_v4<<<dim3(B_SZ * NB), 256, 0, stream>>>(Qb, Kb, Vb, amask, efeat,
                                                 Wgate, bgate, (short*)Qb);
    gemm_out<<<dim3(M_ROWS / 128, 2), 256, 0, stream>>>((const short*)Qb, Wproj,
                                                        bproj, out);
  }
}

// Round 12
// 227.044 us; speedup vs baseline: 1.3682x; 1.0228x over previous
//
#include <hip/hip_runtime.h>
#include <cstdint>
#include <cstddef>

#define B_SZ 2
#define N_SEQ 32768
#define NB 2048
#define HD 32
#define LQ 16
#define KCNT 17
#define M_ROWS 65536
#define SCALE_F 0.17677669529663687f /* 32^-0.5 */

typedef __attribute__((ext_vector_type(8))) short sv8;
typedef __attribute__((ext_vector_type(4))) short sv4;
typedef __attribute__((ext_vector_type(4))) float f4;

__device__ __forceinline__ short f2bf(float f) {
  unsigned u = __builtin_bit_cast(unsigned, f);
  u = (u + 0x7FFFu + ((u >> 16) & 1u)) >> 16;
  return (short)u;
}
__device__ __forceinline__ float bf2f(short s) {
  unsigned u = ((unsigned)(unsigned short)s) << 16;
  return __builtin_bit_cast(float, u);
}
__device__ __forceinline__ void split8(const float* __restrict__ p, sv8& hi, sv8& lo) {
  float4 f0 = *(const float4*)p, f1 = *(const float4*)(p + 4);
  float fv[8] = {f0.x, f0.y, f0.z, f0.w, f1.x, f1.y, f1.z, f1.w};
#pragma unroll
  for (int j = 0; j < 8; ++j) {
    short h = f2bf(fv[j]);
    hi[j] = h;
    lo[j] = f2bf(fv[j] - bf2f(h));
  }
}
__device__ __forceinline__ void gload16(const void* g, void* l) {
  __builtin_amdgcn_global_load_lds(
      (const __attribute__((address_space(1))) unsigned int*)g,
      (__attribute__((address_space(3))) unsigned int*)l, 16, 0, 0);
}
__device__ __forceinline__ f4 mfma16(sv8 a, sv8 b, f4 c) {
  return __builtin_amdgcn_mfma_f32_16x16x32_bf16(a, b, c, 0, 0, 0);
}

// fp32 [rows][256] -> bf16 hi|lo [rows][512]
__global__ __launch_bounds__(256) void split256(const float* __restrict__ src,
                                                short* __restrict__ dst, int n4) {
  int i = blockIdx.x * 256 + threadIdx.x;
  if (i >= n4) return;
  float4 v = ((const float4*)src)[i];
  size_t row = (size_t)(i >> 6);
  int c = (i & 63) * 4;
  float fv[4] = {v.x, v.y, v.z, v.w};
  sv4 hi, lo;
#pragma unroll
  for (int j = 0; j < 4; ++j) {
    short h = f2bf(fv[j]);
    hi[j] = h;
    lo[j] = f2bf(fv[j] - bf2f(h));
  }
  *(sv4*)&dst[row * 512 + c] = hi;
  *(sv4*)&dst[row * 512 + 256 + c] = lo;
}

// ---- QKV GEMM: 2-term (C = (Ah+Al)*Bh), k-chunked dbuf, counted vmcnt,
// bijective XCD-chunked swizzle (FETCH verified 304->36 MB). Unchanged.
#define GEMM_PRE_BODY(NT)                                                      \
  __shared__ __align__(16) short Ah[2][128][32];                               \
  __shared__ __align__(16) short Al[2][128][32];                               \
  __shared__ __align__(16) short Bh[2][128][32];                               \
  const int tid = threadIdx.x;                                                 \
  const int w = tid >> 6, l = tid & 63;                                        \
  const int wm = w >> 1, wn = w & 1;                                           \
  const int bid = blockIdx.x;                                                  \
  const int chunk = (NT * 512) >> 3;                                           \
  const int lbid = (bid & 7) * chunk + (bid >> 3);                             \
  const int nti = lbid % (NT), mti = lbid / (NT);                              \
  const int m0 = mti * 128, n0 = nti * 128;                                    \
  const int lr = l >> 2;                                                       \
  const int lc = (l & 3) * 8;                                                  \
  const int fr = l & 15, kg = (l >> 4) * 8;                                    \
  f4 acc[4][4] = {};                                                           \
  _Pragma("unroll") for (int i = 0; i < 2; ++i) {                              \
    const int row = w * 32 + i * 16;                                           \
    const size_t ra = (size_t)(m0 + row + lr) * 512 + lc;                      \
    const size_t rb = (size_t)(n0 + row + lr) * 512 + lc;                      \
    gload16(A2 + ra, (void*)&Ah[0][row][0]);                                   \
    gload16(A2 + ra + 256, (void*)&Al[0][row][0]);                             \
    gload16(B2 + rb, (void*)&Bh[0][row][0]);                                   \
  }                                                                            \
  asm volatile("s_waitcnt vmcnt(0)" ::: "memory");                             \
  __builtin_amdgcn_s_barrier();                                                \
  int cur = 0;                                                                 \
  for (int s = 0; s < 8; ++s) {                                                \
    if (s < 7) {                                                               \
      const int sk = (s + 1) * 32;                                             \
      _Pragma("unroll") for (int i = 0; i < 2; ++i) {                          \
        const int row = w * 32 + i * 16;                                       \
        const size_t ra = (size_t)(m0 + row + lr) * 512 + sk + lc;             \
        const size_t rb = (size_t)(n0 + row + lr) * 512 + sk + lc;             \
        gload16(A2 + ra, (void*)&Ah[cur ^ 1][row][0]);                         \
        gload16(A2 + ra + 256, (void*)&Al[cur ^ 1][row][0]);                   \
        gload16(B2 + rb, (void*)&Bh[cur ^ 1][row][0]);                         \
      }                                                                        \
    }                                                                          \
    if (s > 0) {                                                               \
      if (s < 7) asm volatile("s_waitcnt vmcnt(6)" ::: "memory");              \
      else asm volatile("s_waitcnt vmcnt(0)" ::: "memory");                    \
      __builtin_amdgcn_s_barrier();                                            \
    }                                                                          \
    sv8 fa[4], fb[4];                                                          \
    _Pragma("unroll") for (int t = 0; t < 4; ++t) {                            \
      fa[t] = *(const sv8*)&Ah[cur][wm * 64 + t * 16 + fr][kg];                \
      fb[t] = *(const sv8*)&Bh[cur][wn * 64 + t * 16 + fr][kg];                \
    }                                                                          \
    _Pragma("unroll") for (int mt = 0; mt < 4; ++mt)                           \
      _Pragma("unroll") for (int nt = 0; nt < 4; ++nt)                         \
        acc[mt][nt] = mfma16(fa[mt], fb[nt], acc[mt][nt]);                     \
    _Pragma("unroll") for (int t = 0; t < 4; ++t)                              \
      fa[t] = *(const sv8*)&Al[cur][wm * 64 + t * 16 + fr][kg];                \
    _Pragma("unroll") for (int mt = 0; mt < 4; ++mt)                           \
      _Pragma("unroll") for (int nt = 0; nt < 4; ++nt)                         \
        acc[mt][nt] = mfma16(fa[mt], fb[nt], acc[mt][nt]);                     \
    asm volatile("s_waitcnt lgkmcnt(0)" ::: "memory");                         \
    __builtin_amdgcn_s_barrier();                                              \
    cur ^= 1;                                                                  \
  }

__global__ __launch_bounds__(256) void gemm_pre_qkv(
    const short* __restrict__ A2, const short* __restrict__ B2,
    const float* __restrict__ bias, float* __restrict__ Qb,
    float* __restrict__ Kb, float* __restrict__ Vb) {
  GEMM_PRE_BODY(6)
  float* dst = (nti < 2) ? Qb : ((nti < 4) ? Kb : Vb);
  const int r0 = (l >> 4) * 4;
#pragma unroll
  for (int mt = 0; mt < 4; ++mt)
#pragma unroll
    for (int nt = 0; nt < 4; ++nt) {
      const int n = n0 + wn * 64 + nt * 16 + fr;
      const float bv = bias[n];
      const int nn = n & 255;
      const size_t mb = (size_t)(m0 + wm * 64 + mt * 16 + r0);
#pragma unroll
      for (int j = 0; j < 4; ++j) dst[(mb + j) * 256 + nn] = acc[mt][nt][j] + bv;
    }
}

// ---- proj GEMM: 1-term (C = Ah*Bh), A dense bf16 [M][astride] (hi at offset 0),
// B pre-split [256][512] (hi cols used). k-chunked dbuf, counted vmcnt(4),
// XCD swizzle. LDS 32 KB -> 4 blocks/CU.
__global__ __launch_bounds__(256) void gemm_proj1(
    const short* __restrict__ A1, int astride, const short* __restrict__ B2,
    const float* __restrict__ bias, float* __restrict__ C) {
  __shared__ __align__(16) short Ahs[2][128][32];
  __shared__ __align__(16) short Bhs[2][128][32];
  const int tid = threadIdx.x;
  const int w = tid >> 6, l = tid & 63;
  const int wm = w >> 1, wn = w & 1;
  const int bid = blockIdx.x;
  const int chunk = (2 * 512) >> 3;
  const int lbid = (bid & 7) * chunk + (bid >> 3);
  const int nti = lbid % 2, mti = lbid / 2;
  const int m0 = mti * 128, n0 = nti * 128;
  const int lr = l >> 2;
  const int lc = (l & 3) * 8;
  const int fr = l & 15, kg = (l >> 4) * 8;
  f4 acc[4][4] = {};
#pragma unroll
  for (int i = 0; i < 2; ++i) {
    const int row = w * 32 + i * 16;
    gload16(A1 + (size_t)(m0 + row + lr) * astride + lc, (void*)&Ahs[0][row][0]);
    gload16(B2 + (size_t)(n0 + row + lr) * 512 + lc, (void*)&Bhs[0][row][0]);
  }
  asm volatile("s_waitcnt vmcnt(0)" ::: "memory");
  __builtin_amdgcn_s_barrier();
  int cur = 0;
  for (int s = 0; s < 8; ++s) {
    if (s < 7) {
      const int sk = (s + 1) * 32;
#pragma unroll
      for (int i = 0; i < 2; ++i) {
        const int row = w * 32 + i * 16;
        gload16(A1 + (size_t)(m0 + row + lr) * astride + sk + lc,
                (void*)&Ahs[cur ^ 1][row][0]);
        gload16(B2 + (size_t)(n0 + row + lr) * 512 + sk + lc,
                (void*)&Bhs[cur ^ 1][row][0]);
      }
    }
    if (s > 0) {
      if (s < 7) asm volatile("s_waitcnt vmcnt(4)" ::: "memory");
      else asm volatile("s_waitcnt vmcnt(0)" ::: "memory");
      __builtin_amdgcn_s_barrier();
    }
    sv8 fa[4], fb[4];
#pragma unroll
    for (int t = 0; t < 4; ++t) {
      fa[t] = *(const sv8*)&Ahs[cur][wm * 64 + t * 16 + fr][kg];
      fb[t] = *(const sv8*)&Bhs[cur][wn * 64 + t * 16 + fr][kg];
    }
#pragma unroll
    for (int mt = 0; mt < 4; ++mt)
#pragma unroll
      for (int nt = 0; nt < 4; ++nt)
        acc[mt][nt] = mfma16(fa[mt], fb[nt], acc[mt][nt]);
    asm volatile("s_waitcnt lgkmcnt(0)" ::: "memory");
    __builtin_amdgcn_s_barrier();
    cur ^= 1;
  }
  const int r0 = (l >> 4) * 4;
#pragma unroll
  for (int mt = 0; mt < 4; ++mt)
#pragma unroll
    for (int nt = 0; nt < 4; ++nt) {
      const int n = n0 + wn * 64 + nt * 16 + fr;
      const float bv = bias[n];
      const size_t mb = (size_t)(m0 + wm * 64 + mt * 16 + r0);
#pragma unroll
      for (int j = 0; j < 4; ++j) C[(mb + j) * 256 + n] = acc[mt][nt][j] + bv;
    }
}

// ---- fallback on-the-fly-split QKV GEMM (proven round 4) ----
__global__ __launch_bounds__(256) void gemm_qkv(
    const float* __restrict__ X, const float* __restrict__ W,
    const float* __restrict__ bias, float* __restrict__ Qb,
    float* __restrict__ Kb, float* __restrict__ Vb) {
  const int tid = threadIdx.x, w = tid >> 6, l = tid & 63;
  const int wm = w >> 1, wn = w & 1;
  const int m0 = blockIdx.x * 128, n0 = blockIdx.y * 128;
  const int fr = l & 15, kg = (l >> 4) * 8;
  f4 acc[4][4] = {};
  for (int s = 0; s < 8; ++s) {
    const int k0 = s * 32 + kg;
    sv8 ah[4], al[4], bh[4], bl[4];
#pragma unroll
    for (int t = 0; t < 4; ++t) {
      split8(X + (size_t)(m0 + wm * 64 + t * 16 + fr) * 256 + k0, ah[t], al[t]);
      split8(W + (size_t)(n0 + wn * 64 + t * 16 + fr) * 256 + k0, bh[t], bl[t]);
    }
#pragma unroll
    for (int mt = 0; mt < 4; ++mt)
#pragma unroll
      for (int nt = 0; nt < 4; ++nt) {
        f4 a0 = acc[mt][nt];
        a0 = mfma16(ah[mt], bh[nt], a0);
        a0 = mfma16(al[mt], bh[nt], a0);
        a0 = mfma16(ah[mt], bl[nt], a0);
        acc[mt][nt] = a0;
      }
  }
  float* dst = (blockIdx.y < 2) ? Qb : ((blockIdx.y < 4) ? Kb : Vb);
  const int r0 = (l >> 4) * 4;
#pragma unroll
  for (int mt = 0; mt < 4; ++mt)
#pragma unroll
    for (int nt = 0; nt < 4; ++nt) {
      const int n = n0 + wn * 64 + nt * 16 + fr;
      const float bv = bias[n];
      const int nn = n & 255;
      const size_t mb = (size_t)(m0 + wm * 64 + mt * 16 + r0);
#pragma unroll
      for (int j = 0; j < 4; ++j) dst[(mb + j) * 256 + nn] = acc[mt][nt][j] + bv;
    }
}

// fallback proj GEMM: 1-term, A bf16-hi at stride 512 (overlay layout)
__global__ __launch_bounds__(256) void gemm_out(
    const short* __restrict__ A2, const float* __restrict__ W,
    const float* __restrict__ bias, float* __restrict__ C) {
  const int tid = threadIdx.x, w = tid >> 6, l = tid & 63;
  const int wm = w >> 1, wn = w & 1;
  const int m0 = blockIdx.x * 128, n0 = blockIdx.y * 128;
  const int fr = l & 15, kg = (l >> 4) * 8;
  f4 acc[4][4] = {};
  for (int s = 0; s < 8; ++s) {
    const int k0 = s * 32 + kg;
    sv8 ah[4], bh[4], bl[4];
#pragma unroll
    for (int t = 0; t < 4; ++t) {
      ah[t] = *(const sv8*)(A2 + (size_t)(m0 + wm * 64 + t * 16 + fr) * 512 + k0);
      split8(W + (size_t)(n0 + wn * 64 + t * 16 + fr) * 256 + k0, bh[t], bl[t]);
    }
#pragma unroll
    for (int mt = 0; mt < 4; ++mt)
#pragma unroll
      for (int nt = 0; nt < 4; ++nt)
        acc[mt][nt] = mfma16(ah[mt], bh[nt], acc[mt][nt]);
  }
  const int r0 = (l >> 4) * 4;
#pragma unroll
  for (int mt = 0; mt < 4; ++mt)
#pragma unroll
    for (int nt = 0; nt < 4; ++nt) {
      const int n = n0 + wn * 64 + nt * 16 + fr;
      const float bv = bias[n];
      const size_t mb = (size_t)(m0 + wm * 64 + mt * 16 + r0);
#pragma unroll
      for (int j = 0; j < 4; ++j) C[(mb + j) * 256 + n] = acc[mt][nt][j] + bv;
    }
}

// LDS pointer with per-row XOR swizzle (float index d at byte 4d ^ ((d>>5&7)<<4));
// bijective per 1 KiB row; kills the fixed-h 8-way read conflict.
__device__ __forceinline__ float* ldsP(float* base, int row, int d) {
  return (float*)((char*)base + row * 1024 + ((4 * d) ^ (((d >> 5) & 7) << 4)));
}

// One block per (b, nb). ONE barrier. Block-node (kc=16) folded analytically.
// Output: bf16 HI ONLY, row stride `aostride` shorts (256 = dense buffer,
// 512 = overlay-over-Q layout for the fallback path). Race-free for overlay:
// row tok0+q is read and written only by its own 16 threads (same wave),
// reads precede writes in program order.
__global__ __launch_bounds__(256, 4) void attn_v5(
    const float* __restrict__ Qb, const float* __restrict__ Kb,
    const float* __restrict__ Vb, const int* __restrict__ amask,
    const float* __restrict__ efeat, const float* __restrict__ Wgate,
    const float* __restrict__ bgate, short* __restrict__ AO, int aostride) {
  __shared__ float Ks[16 * 256];   // swizzled, 16 KiB
  __shared__ float Vs[16 * 256];   // swizzled, 16 KiB
  __shared__ float4 Es[LQ * KCNT]; // edge feats, 4.25 KiB
  __shared__ int Ms[LQ * KCNT];    // mask, 1.06 KiB

  const int tid = threadIdx.x, g = blockIdx.x;
  const int b = g >> 11, nb = g & (NB - 1);
  const size_t tok0 = (size_t)(b * N_SEQ + nb * LQ);

#pragma unroll
  for (int i = 0; i < 4; ++i) {
    const int f = tid + i * 256;
    const int t = f >> 6, c4 = (f & 63) * 4;
    *(float4*)ldsP(Ks, t, c4) = *(const float4*)(Kb + (tok0 + t) * 256 + c4);
    *(float4*)ldsP(Vs, t, c4) = *(const float4*)(Vb + (tok0 + t) * 256 + c4);
  }
  {
    const float4* esrc = (const float4*)(efeat + (size_t)nb * LQ * KCNT * 4);
    const int* msrc = amask + (size_t)nb * LQ * KCNT;
    Es[tid] = esrc[tid];
    Ms[tid] = msrc[tid];
    if (tid < LQ * KCNT - 256) {
      Es[256 + tid] = esrc[256 + tid];
      Ms[256 + tid] = msrc[256 + tid];
    }
  }
  __syncthreads();

  const int q = tid >> 4, h = (tid >> 1) & 7, half = tid & 1;
  const int d0 = h * HD + half * 16;

  float qh[16];
  {
    const float* qp = Qb + (tok0 + q) * 256 + d0;
#pragma unroll
    for (int j = 0; j < 4; ++j) {
      float4 v = *(const float4*)(qp + j * 4);
      qh[j * 4] = v.x; qh[j * 4 + 1] = v.y;
      qh[j * 4 + 2] = v.z; qh[j * 4 + 3] = v.w;
    }
  }
  const float wg0 = Wgate[h * 4], wg1 = Wgate[h * 4 + 1];
  const float wg2 = Wgate[h * 4 + 2], wg3 = Wgate[h * 4 + 3];
  const float bg = bgate[h];

  float sc[16], gt[16];
  float rawsum = 0.f;
  unsigned vis = 0;
  float mx = -1e30f;
#pragma unroll
  for (int kc = 0; kc < 16; ++kc) {
    float dot = 0.f;
#pragma unroll
    for (int j = 0; j < 4; ++j) {
      float4 kv = *(const float4*)ldsP(Ks, kc, d0 + j * 4);
      dot += qh[j * 4] * kv.x + qh[j * 4 + 1] * kv.y +
             qh[j * 4 + 2] * kv.z + qh[j * 4 + 3] * kv.w;
    }
    dot += __shfl_xor(dot, 1);
    rawsum += dot;
    float e0, e1, e2, e3;
    if (kc == q) { e0 = e1 = e2 = 0.f; e3 = 1.f; }
    else { float4 e = Es[q * KCNT + kc]; e0 = e.x; e1 = e.y; e2 = e.z; e3 = e.w; }
    const int m = Ms[q * KCNT + kc];
    const float s = dot * SCALE_F + e3;
    sc[kc] = s;
    if (m) { vis |= (1u << kc); mx = fmaxf(mx, s); }
    gt[kc] = m ? (e0 * wg0 + e1 * wg1 + e2 * wg2 + e3 * wg3 + bg) : 0.f;
  }
  const float s16 = rawsum * 0.0625f * SCALE_F + 1.0f;
  const int m16 = Ms[q * KCNT + 16];
  const float gt16 = m16 ? (wg3 + bg) : 0.f;
  if (m16) mx = fmaxf(mx, s16);

  float den = 0.f;
#pragma unroll
  for (int kc = 0; kc < 16; ++kc) {
    const float pv = (vis & (1u << kc)) ? __expf(sc[kc] - mx) : 0.f;
    sc[kc] = pv;
    den += pv;
  }
  const float p16 = m16 ? __expf(s16 - mx) : 0.f;
  den += p16;
  const float inv = 1.f / den;
  const float cb16 = (p16 * inv + gt16) * 0.0625f;
#pragma unroll
  for (int kc = 0; kc < 16; ++kc) sc[kc] = sc[kc] * inv + gt[kc] + cb16;

  float o[16] = {};
#pragma unroll
  for (int kc = 0; kc < 16; ++kc) {
    const float c = sc[kc];
#pragma unroll
    for (int j = 0; j < 4; ++j) {
      float4 vv = *(const float4*)ldsP(Vs, kc, d0 + j * 4);
      o[j * 4] += c * vv.x;
      o[j * 4 + 1] += c * vv.y;
      o[j * 4 + 2] += c * vv.z;
      o[j * 4 + 3] += c * vv.w;
    }
  }
  short* ao = AO + (tok0 + q) * (size_t)aostride + d0;
  sv8 hi;
#pragma unroll
  for (int e = 0; e < 8; ++e) hi[e] = f2bf(o[e]);
  *(sv8*)ao = hi;
#pragma unroll
  for (int e = 0; e < 8; ++e) hi[e] = f2bf(o[8 + e]);
  *(sv8*)&ao[8] = hi;
}

extern "C" void kernel_launch(void* const* d_in, const int* in_sizes, int n_in,
                              void* d_out, int out_size, void* d_ws, size_t ws_size,
                              hipStream_t stream) {
  const float* x = (const float*)d_in[0];
  const int* amask = (const int*)d_in[1];
  const float* efeat = (const float*)d_in[2];
  const float* Wqkv = (const float*)d_in[3];
  const float* bqkv = (const float*)d_in[4];
  const float* Wproj = (const float*)d_in[5];
  const float* bproj = (const float*)d_in[6];
  const float* Wgate = (const float*)d_in[7];
  const float* bgate = (const float*)d_in[8];
  float* out = (float*)d_out;

  char* ws = (char*)d_ws;
  const size_t QSZ = (size_t)M_ROWS * 256 * 4;   // 64 MiB
  const size_t W2Q_SZ = (size_t)768 * 512 * 2;   // 768 KiB
  const size_t W2P_SZ = (size_t)256 * 512 * 2;   // 256 KiB
  const size_t AO_SZ = (size_t)M_ROWS * 256 * 2; // 32 MiB

  if (ws_size >= 3 * QSZ + W2Q_SZ + W2P_SZ + AO_SZ) {
    short* X2 = (short*)ws;
    float* Qb = (float*)(ws + QSZ);
    float* Kb = (float*)(ws + 2 * QSZ);
    short* W2Q = (short*)(ws + 3 * QSZ);
    short* W2P = (short*)(ws + 3 * QSZ + W2Q_SZ);
    short* AOh = (short*)(ws + 3 * QSZ + W2Q_SZ + W2P_SZ);
    float* Vb = out;
    split256<<<dim3(M_ROWS * 64 / 256), 256, 0, stream>>>(x, X2, M_ROWS * 64);
    split256<<<dim3(768 * 64 / 256), 256, 0, stream>>>(Wqkv, W2Q, 768 * 64);
    split256<<<dim3(256 * 64 / 256), 256, 0, stream>>>(Wproj, W2P, 256 * 64);
    gemm_pre_qkv<<<dim3(6 * 512), 256, 0, stream>>>(X2, W2Q, bqkv, Qb, Kb, Vb);
    attn_v5<<<dim3(B_SZ * NB), 256, 0, stream>>>(Qb, Kb, Vb, amask, efeat,
                                                 Wgate, bgate, AOh, 256);
    gemm_proj1<<<dim3(2 * 512), 256, 0, stream>>>(AOh, 256, W2P, bproj, out);
  } else {
    if (ws_size < 2 * QSZ) return;
    float* Qb = (float*)ws;
    float* Kb = (float*)(ws + QSZ);
    float* Vb = out;
    gemm_qkv<<<dim3(M_ROWS / 128, 6), 256, 0, stream>>>(x, Wqkv, bqkv, Qb, Kb, Vb);
    attn_v5<<<dim3(B_SZ * NB), 256, 0, stream>>>(Qb, Kb, Vb, amask, efeat,
                                                 Wgate, bgate, (short*)Qb, 512);
    gemm_out<<<dim3(M_ROWS / 128, 2), 256, 0, stream>>>((const short*)Qb, Wproj,
                                                        bproj, out);
  }
}

// Round 13
// 189.166 us; speedup vs baseline: 1.6422x; 1.2002x over previous
//
#include <hip/hip_runtime.h>
#include <cstdint>
#include <cstddef>

#define B_SZ 2
#define N_SEQ 32768
#define NB 2048
#define HD 32
#define LQ 16
#define KCNT 17
#define M_ROWS 65536
#define SCALE_F 0.17677669529663687f /* 32^-0.5 */

typedef __attribute__((ext_vector_type(8))) short sv8;
typedef __attribute__((ext_vector_type(4))) short sv4;
typedef __attribute__((ext_vector_type(4))) float f4;

__device__ __forceinline__ short f2bf(float f) {
  unsigned u = __builtin_bit_cast(unsigned, f);
  u = (u + 0x7FFFu + ((u >> 16) & 1u)) >> 16;
  return (short)u;
}
__device__ __forceinline__ float bf2f(short s) {
  unsigned u = ((unsigned)(unsigned short)s) << 16;
  return __builtin_bit_cast(float, u);
}
__device__ __forceinline__ void gload16(const void* g, void* l) {
  __builtin_amdgcn_global_load_lds(
      (const __attribute__((address_space(1))) unsigned int*)g,
      (__attribute__((address_space(3))) unsigned int*)l, 16, 0, 0);
}
__device__ __forceinline__ f4 mfma16(sv8 a, sv8 b, f4 c) {
  return __builtin_amdgcn_mfma_f32_16x16x32_bf16(a, b, c, 0, 0, 0);
}

// fp32 [rows][256] -> bf16 hi|lo [rows][512]
__global__ __launch_bounds__(256) void split256(const float* __restrict__ src,
                                                short* __restrict__ dst, int n4) {
  int i = blockIdx.x * 256 + threadIdx.x;
  if (i >= n4) return;
  float4 v = ((const float4*)src)[i];
  size_t row = (size_t)(i >> 6);
  int c = (i & 63) * 4;
  float fv[4] = {v.x, v.y, v.z, v.w};
  sv4 hi, lo;
#pragma unroll
  for (int j = 0; j < 4; ++j) {
    short h = f2bf(fv[j]);
    hi[j] = h;
    lo[j] = f2bf(fv[j] - bf2f(h));
  }
  *(sv4*)&dst[row * 512 + c] = hi;
  *(sv4*)&dst[row * 512 + 256 + c] = lo;
}

// ---- QKV GEMM: 2-term (C = (Ah+Al)*Bh), k-chunked dbuf, counted vmcnt,
// bijective XCD-chunked swizzle (FETCH verified 304->36 MB). Outputs bf16.
__global__ __launch_bounds__(256) void gemm_pre_qkv(
    const short* __restrict__ A2, const short* __restrict__ B2,
    const float* __restrict__ bias, short* __restrict__ Qbf,
    short* __restrict__ Kbf, short* __restrict__ Vbf) {
  __shared__ __align__(16) short Ah[2][128][32];
  __shared__ __align__(16) short Al[2][128][32];
  __shared__ __align__(16) short Bh[2][128][32];
  const int tid = threadIdx.x;
  const int w = tid >> 6, l = tid & 63;
  const int wm = w >> 1, wn = w & 1;
  const int bid = blockIdx.x;
  const int chunk = (6 * 512) >> 3;
  const int lbid = (bid & 7) * chunk + (bid >> 3);
  const int nti = lbid % 6, mti = lbid / 6;
  const int m0 = mti * 128, n0 = nti * 128;
  const int lr = l >> 2;
  const int lc = (l & 3) * 8;
  const int fr = l & 15, kg = (l >> 4) * 8;
  f4 acc[4][4] = {};
#pragma unroll
  for (int i = 0; i < 2; ++i) {
    const int row = w * 32 + i * 16;
    const size_t ra = (size_t)(m0 + row + lr) * 512 + lc;
    const size_t rb = (size_t)(n0 + row + lr) * 512 + lc;
    gload16(A2 + ra, (void*)&Ah[0][row][0]);
    gload16(A2 + ra + 256, (void*)&Al[0][row][0]);
    gload16(B2 + rb, (void*)&Bh[0][row][0]);
  }
  asm volatile("s_waitcnt vmcnt(0)" ::: "memory");
  __builtin_amdgcn_s_barrier();
  int cur = 0;
  for (int s = 0; s < 8; ++s) {
    if (s < 7) {
      const int sk = (s + 1) * 32;
#pragma unroll
      for (int i = 0; i < 2; ++i) {
        const int row = w * 32 + i * 16;
        const size_t ra = (size_t)(m0 + row + lr) * 512 + sk + lc;
        const size_t rb = (size_t)(n0 + row + lr) * 512 + sk + lc;
        gload16(A2 + ra, (void*)&Ah[cur ^ 1][row][0]);
        gload16(A2 + ra + 256, (void*)&Al[cur ^ 1][row][0]);
        gload16(B2 + rb, (void*)&Bh[cur ^ 1][row][0]);
      }
    }
    if (s > 0) {
      if (s < 7) asm volatile("s_waitcnt vmcnt(6)" ::: "memory");
      else asm volatile("s_waitcnt vmcnt(0)" ::: "memory");
      __builtin_amdgcn_s_barrier();
    }
    sv8 fa[4], fb[4];
#pragma unroll
    for (int t = 0; t < 4; ++t) {
      fa[t] = *(const sv8*)&Ah[cur][wm * 64 + t * 16 + fr][kg];
      fb[t] = *(const sv8*)&Bh[cur][wn * 64 + t * 16 + fr][kg];
    }
#pragma unroll
    for (int mt = 0; mt < 4; ++mt)
#pragma unroll
      for (int nt = 0; nt < 4; ++nt)
        acc[mt][nt] = mfma16(fa[mt], fb[nt], acc[mt][nt]);
#pragma unroll
    for (int t = 0; t < 4; ++t)
      fa[t] = *(const sv8*)&Al[cur][wm * 64 + t * 16 + fr][kg];
#pragma unroll
    for (int mt = 0; mt < 4; ++mt)
#pragma unroll
      for (int nt = 0; nt < 4; ++nt)
        acc[mt][nt] = mfma16(fa[mt], fb[nt], acc[mt][nt]);
    asm volatile("s_waitcnt lgkmcnt(0)" ::: "memory");
    __builtin_amdgcn_s_barrier();
    cur ^= 1;
  }
  short* dst = (nti < 2) ? Qbf : ((nti < 4) ? Kbf : Vbf);
  const int r0 = (l >> 4) * 4;
#pragma unroll
  for (int mt = 0; mt < 4; ++mt)
#pragma unroll
    for (int nt = 0; nt < 4; ++nt) {
      const int n = n0 + wn * 64 + nt * 16 + fr;
      const float bv = bias[n];
      const int nn = n & 255;
      const size_t mb = (size_t)(m0 + wm * 64 + mt * 16 + r0);
#pragma unroll
      for (int j = 0; j < 4; ++j)
        dst[(mb + j) * 256 + nn] = f2bf(acc[mt][nt][j] + bv);
    }
}

// ---- proj GEMM: 1-term (C = Ah*Bh), A dense bf16 [M][256],
// B pre-split [256][512] (hi cols). k-chunked dbuf, counted vmcnt(4),
// XCD swizzle. LDS 32 KB -> 4 blocks/CU.
__global__ __launch_bounds__(256) void gemm_proj1(
    const short* __restrict__ A1, const short* __restrict__ B2,
    const float* __restrict__ bias, float* __restrict__ C) {
  __shared__ __align__(16) short Ahs[2][128][32];
  __shared__ __align__(16) short Bhs[2][128][32];
  const int tid = threadIdx.x;
  const int w = tid >> 6, l = tid & 63;
  const int wm = w >> 1, wn = w & 1;
  const int bid = blockIdx.x;
  const int chunk = (2 * 512) >> 3;
  const int lbid = (bid & 7) * chunk + (bid >> 3);
  const int nti = lbid % 2, mti = lbid / 2;
  const int m0 = mti * 128, n0 = nti * 128;
  const int lr = l >> 2;
  const int lc = (l & 3) * 8;
  const int fr = l & 15, kg = (l >> 4) * 8;
  f4 acc[4][4] = {};
#pragma unroll
  for (int i = 0; i < 2; ++i) {
    const int row = w * 32 + i * 16;
    gload16(A1 + (size_t)(m0 + row + lr) * 256 + lc, (void*)&Ahs[0][row][0]);
    gload16(B2 + (size_t)(n0 + row + lr) * 512 + lc, (void*)&Bhs[0][row][0]);
  }
  asm volatile("s_waitcnt vmcnt(0)" ::: "memory");
  __builtin_amdgcn_s_barrier();
  int cur = 0;
  for (int s = 0; s < 8; ++s) {
    if (s < 7) {
      const int sk = (s + 1) * 32;
#pragma unroll
      for (int i = 0; i < 2; ++i) {
        const int row = w * 32 + i * 16;
        gload16(A1 + (size_t)(m0 + row + lr) * 256 + sk + lc,
                (void*)&Ahs[cur ^ 1][row][0]);
        gload16(B2 + (size_t)(n0 + row + lr) * 512 + sk + lc,
                (void*)&Bhs[cur ^ 1][row][0]);
      }
    }
    if (s > 0) {
      if (s < 7) asm volatile("s_waitcnt vmcnt(4)" ::: "memory");
      else asm volatile("s_waitcnt vmcnt(0)" ::: "memory");
      __builtin_amdgcn_s_barrier();
    }
    sv8 fa[4], fb[4];
#pragma unroll
    for (int t = 0; t < 4; ++t) {
      fa[t] = *(const sv8*)&Ahs[cur][wm * 64 + t * 16 + fr][kg];
      fb[t] = *(const sv8*)&Bhs[cur][wn * 64 + t * 16 + fr][kg];
    }
#pragma unroll
    for (int mt = 0; mt < 4; ++mt)
#pragma unroll
      for (int nt = 0; nt < 4; ++nt)
        acc[mt][nt] = mfma16(fa[mt], fb[nt], acc[mt][nt]);
    asm volatile("s_waitcnt lgkmcnt(0)" ::: "memory");
    __builtin_amdgcn_s_barrier();
    cur ^= 1;
  }
  const int r0 = (l >> 4) * 4;
#pragma unroll
  for (int mt = 0; mt < 4; ++mt)
#pragma unroll
    for (int nt = 0; nt < 4; ++nt) {
      const int n = n0 + wn * 64 + nt * 16 + fr;
      const float bv = bias[n];
      const size_t mb = (size_t)(m0 + wm * 64 + mt * 16 + r0);
#pragma unroll
      for (int j = 0; j < 4; ++j) C[(mb + j) * 256 + n] = acc[mt][nt][j] + bv;
    }
}

// LDS pointer with per-row XOR swizzle (float index d at byte 4d ^ ((d>>5&7)<<4));
// bijective per 1 KiB row; kills the fixed-h 8-way read conflict.
__device__ __forceinline__ float* ldsP(float* base, int row, int d) {
  return (float*)((char*)base + row * 1024 + ((4 * d) ^ (((d >> 5) & 7) << 4)));
}

// One block per (b, nb). ONE barrier. Block-node (kc=16) folded analytically.
// Inputs Q/K/V are bf16 [M][256]; staged into fp32 swizzled LDS; fp32 math.
// Output: bf16 hi, dense [M][256].
__global__ __launch_bounds__(256, 4) void attn_v6(
    const short* __restrict__ Qb, const short* __restrict__ Kb,
    const short* __restrict__ Vb, const int* __restrict__ amask,
    const float* __restrict__ efeat, const float* __restrict__ Wgate,
    const float* __restrict__ bgate, short* __restrict__ AO) {
  __shared__ float Ks[16 * 256];   // swizzled, 16 KiB
  __shared__ float Vs[16 * 256];   // swizzled, 16 KiB
  __shared__ float4 Es[LQ * KCNT]; // edge feats, 4.25 KiB
  __shared__ int Ms[LQ * KCNT];    // mask, 1.06 KiB

  const int tid = threadIdx.x, g = blockIdx.x;
  const int b = g >> 11, nb = g & (NB - 1);
  const size_t tok0 = (size_t)(b * N_SEQ + nb * LQ);

  // stage 16 leaf K,V rows: bf16 global (sv8 = 16 B) -> fp32 swizzled LDS
  // (two float4 stores per 8 elems; each 16-B unit gets its own swizzle)
#pragma unroll
  for (int i = 0; i < 2; ++i) {
    const int f = tid + i * 256;  // 0..511
    const int t = f >> 5, c8 = (f & 31) * 8;
    sv8 kv = *(const sv8*)(Kb + (tok0 + t) * 256 + c8);
    sv8 vv = *(const sv8*)(Vb + (tok0 + t) * 256 + c8);
    float4 k0 = {bf2f(kv[0]), bf2f(kv[1]), bf2f(kv[2]), bf2f(kv[3])};
    float4 k1 = {bf2f(kv[4]), bf2f(kv[5]), bf2f(kv[6]), bf2f(kv[7])};
    float4 v0 = {bf2f(vv[0]), bf2f(vv[1]), bf2f(vv[2]), bf2f(vv[3])};
    float4 v1 = {bf2f(vv[4]), bf2f(vv[5]), bf2f(vv[6]), bf2f(vv[7])};
    *(float4*)ldsP(Ks, t, c8) = k0;
    *(float4*)ldsP(Ks, t, c8 + 4) = k1;
    *(float4*)ldsP(Vs, t, c8) = v0;
    *(float4*)ldsP(Vs, t, c8 + 4) = v1;
  }
  // stage efeat (272 float4) and mask (272 int), coalesced
  {
    const float4* esrc = (const float4*)(efeat + (size_t)nb * LQ * KCNT * 4);
    const int* msrc = amask + (size_t)nb * LQ * KCNT;
    Es[tid] = esrc[tid];
    Ms[tid] = msrc[tid];
    if (tid < LQ * KCNT - 256) {
      Es[256 + tid] = esrc[256 + tid];
      Ms[256 + tid] = msrc[256 + tid];
    }
  }
  __syncthreads();

  const int q = tid >> 4, h = (tid >> 1) & 7, half = tid & 1;
  const int d0 = h * HD + half * 16;

  float qh[16];
  {
    const short* qp = Qb + (tok0 + q) * 256 + d0;
    sv8 q0 = *(const sv8*)qp;
    sv8 q1 = *(const sv8*)(qp + 8);
#pragma unroll
    for (int e = 0; e < 8; ++e) {
      qh[e] = bf2f(q0[e]);
      qh[8 + e] = bf2f(q1[e]);
    }
  }
  const float wg0 = Wgate[h * 4], wg1 = Wgate[h * 4 + 1];
  const float wg2 = Wgate[h * 4 + 2], wg3 = Wgate[h * 4 + 3];
  const float bg = bgate[h];

  float sc[16], gt[16];
  float rawsum = 0.f;
  unsigned vis = 0;
  float mx = -1e30f;
#pragma unroll
  for (int kc = 0; kc < 16; ++kc) {
    float dot = 0.f;
#pragma unroll
    for (int j = 0; j < 4; ++j) {
      float4 kv = *(const float4*)ldsP(Ks, kc, d0 + j * 4);
      dot += qh[j * 4] * kv.x + qh[j * 4 + 1] * kv.y +
             qh[j * 4 + 2] * kv.z + qh[j * 4 + 3] * kv.w;
    }
    dot += __shfl_xor(dot, 1);
    rawsum += dot;
    float e0, e1, e2, e3;
    if (kc == q) { e0 = e1 = e2 = 0.f; e3 = 1.f; }
    else { float4 e = Es[q * KCNT + kc]; e0 = e.x; e1 = e.y; e2 = e.z; e3 = e.w; }
    const int m = Ms[q * KCNT + kc];
    const float s = dot * SCALE_F + e3;
    sc[kc] = s;
    if (m) { vis |= (1u << kc); mx = fmaxf(mx, s); }
    gt[kc] = m ? (e0 * wg0 + e1 * wg1 + e2 * wg2 + e3 * wg3 + bg) : 0.f;
  }
  const float s16 = rawsum * 0.0625f * SCALE_F + 1.0f;
  const int m16 = Ms[q * KCNT + 16];
  const float gt16 = m16 ? (wg3 + bg) : 0.f;
  if (m16) mx = fmaxf(mx, s16);

  float den = 0.f;
#pragma unroll
  for (int kc = 0; kc < 16; ++kc) {
    const float pv = (vis & (1u << kc)) ? __expf(sc[kc] - mx) : 0.f;
    sc[kc] = pv;
    den += pv;
  }
  const float p16 = m16 ? __expf(s16 - mx) : 0.f;
  den += p16;
  const float inv = 1.f / den;
  const float cb16 = (p16 * inv + gt16) * 0.0625f;
#pragma unroll
  for (int kc = 0; kc < 16; ++kc) sc[kc] = sc[kc] * inv + gt[kc] + cb16;

  float o[16] = {};
#pragma unroll
  for (int kc = 0; kc < 16; ++kc) {
    const float c = sc[kc];
#pragma unroll
    for (int j = 0; j < 4; ++j) {
      float4 vv = *(const float4*)ldsP(Vs, kc, d0 + j * 4);
      o[j * 4] += c * vv.x;
      o[j * 4 + 1] += c * vv.y;
      o[j * 4 + 2] += c * vv.z;
      o[j * 4 + 3] += c * vv.w;
    }
  }
  short* ao = AO + (tok0 + q) * 256 + d0;
  sv8 hi;
#pragma unroll
  for (int e = 0; e < 8; ++e) hi[e] = f2bf(o[e]);
  *(sv8*)ao = hi;
#pragma unroll
  for (int e = 0; e < 8; ++e) hi[e] = f2bf(o[8 + e]);
  *(sv8*)&ao[8] = hi;
}

extern "C" void kernel_launch(void* const* d_in, const int* in_sizes, int n_in,
                              void* d_out, int out_size, void* d_ws, size_t ws_size,
                              hipStream_t stream) {
  const float* x = (const float*)d_in[0];
  const int* amask = (const int*)d_in[1];
  const float* efeat = (const float*)d_in[2];
  const float* Wqkv = (const float*)d_in[3];
  const float* bqkv = (const float*)d_in[4];
  const float* Wproj = (const float*)d_in[5];
  const float* bproj = (const float*)d_in[6];
  const float* Wgate = (const float*)d_in[7];
  const float* bgate = (const float*)d_in[8];
  float* out = (float*)d_out;

  char* ws = (char*)d_ws;
  const size_t X2_SZ = (size_t)M_ROWS * 512 * 2;  // 64 MiB
  const size_t QB_SZ = (size_t)M_ROWS * 256 * 2;  // 32 MiB each
  const size_t W2Q_SZ = (size_t)768 * 512 * 2;    // 768 KiB
  const size_t W2P_SZ = (size_t)256 * 512 * 2;    // 256 KiB
  // total: 64 + 3*32 + ~1 + 32 = ~193 MiB (ws >= 225 MiB confirmed round 12)
  if (ws_size < X2_SZ + 4 * QB_SZ + W2Q_SZ + W2P_SZ) return;

  short* X2 = (short*)ws;
  short* Qbf = (short*)(ws + X2_SZ);
  short* Kbf = (short*)(ws + X2_SZ + QB_SZ);
  short* Vbf = (short*)(ws + X2_SZ + 2 * QB_SZ);
  short* W2Q = (short*)(ws + X2_SZ + 3 * QB_SZ);
  short* W2P = (short*)(ws + X2_SZ + 3 * QB_SZ + W2Q_SZ);
  short* AOh = (short*)(ws + X2_SZ + 3 * QB_SZ + W2Q_SZ + W2P_SZ);

  split256<<<dim3(M_ROWS * 64 / 256), 256, 0, stream>>>(x, X2, M_ROWS * 64);
  split256<<<dim3(768 * 64 / 256), 256, 0, stream>>>(Wqkv, W2Q, 768 * 64);
  split256<<<dim3(256 * 64 / 256), 256, 0, stream>>>(Wproj, W2P, 256 * 64);
  gemm_pre_qkv<<<dim3(6 * 512), 256, 0, stream>>>(X2, W2Q, bqkv, Qbf, Kbf, Vbf);
  attn_v6<<<dim3(B_SZ * NB), 256, 0, stream>>>(Qbf, Kbf, Vbf, amask, efeat,
                                               Wgate, bgate, AOh);
  gemm_proj1<<<dim3(2 * 512), 256, 0, stream>>>(AOh, W2P, bproj, out);
}

// Round 14
// 164.132 us; speedup vs baseline: 1.8927x; 1.1525x over previous
//
#include <hip/hip_runtime.h>
#include <cstdint>
#include <cstddef>

#define B_SZ 2
#define N_SEQ 32768
#define NB 2048
#define HD 32
#define LQ 16
#define KCNT 17
#define M_ROWS 65536
#define SCALE_F 0.17677669529663687f /* 32^-0.5 */

typedef __attribute__((ext_vector_type(8))) short sv8;
typedef __attribute__((ext_vector_type(4))) short sv4;
typedef __attribute__((ext_vector_type(4))) float f4;

__device__ __forceinline__ short f2bf(float f) {
  unsigned u = __builtin_bit_cast(unsigned, f);
  u = (u + 0x7FFFu + ((u >> 16) & 1u)) >> 16;
  return (short)u;
}
__device__ __forceinline__ float bf2f(short s) {
  unsigned u = ((unsigned)(unsigned short)s) << 16;
  return __builtin_bit_cast(float, u);
}
__device__ __forceinline__ void gload16(const void* g, void* l) {
  __builtin_amdgcn_global_load_lds(
      (const __attribute__((address_space(1))) unsigned int*)g,
      (__attribute__((address_space(3))) unsigned int*)l, 16, 0, 0);
}
__device__ __forceinline__ f4 mfma16(sv8 a, sv8 b, f4 c) {
  return __builtin_amdgcn_mfma_f32_16x16x32_bf16(a, b, c, 0, 0, 0);
}

// fp32 [rows][256] -> bf16 hi|lo [rows][512]  (weights only now)
__global__ __launch_bounds__(256) void split256(const float* __restrict__ src,
                                                short* __restrict__ dst, int n4) {
  int i = blockIdx.x * 256 + threadIdx.x;
  if (i >= n4) return;
  float4 v = ((const float4*)src)[i];
  size_t row = (size_t)(i >> 6);
  int c = (i & 63) * 4;
  float fv[4] = {v.x, v.y, v.z, v.w};
  sv4 hi, lo;
#pragma unroll
  for (int j = 0; j < 4; ++j) {
    short h = f2bf(fv[j]);
    hi[j] = h;
    lo[j] = f2bf(fv[j] - bf2f(h));
  }
  *(sv4*)&dst[row * 512 + c] = hi;
  *(sv4*)&dst[row * 512 + 256 + c] = lo;
}

// fp32 -> dense bf16 (for X)
__global__ __launch_bounds__(256) void cast256(const float* __restrict__ src,
                                               short* __restrict__ dst, int n4) {
  int i = blockIdx.x * 256 + threadIdx.x;
  if (i >= n4) return;
  float4 v = ((const float4*)src)[i];
  sv4 h = {f2bf(v.x), f2bf(v.y), f2bf(v.z), f2bf(v.w)};
  *(sv4*)&dst[(size_t)i * 4] = h;
}

// ---- QKV GEMM, 1-term bf16 (C = A*Bh): A dense bf16 [M][256], B pre-split
// [768][512] (hi half used). k-chunked dbuf, counted vmcnt(4), bijective
// XCD-chunked swizzle. LDS 32 KB -> 4 blocks/CU. Outputs routed bf16.
__global__ __launch_bounds__(256) void gemm_bf_qkv(
    const short* __restrict__ A1, const short* __restrict__ B2,
    const float* __restrict__ bias, short* __restrict__ Qbf,
    short* __restrict__ Kbf, short* __restrict__ Vbf) {
  __shared__ __align__(16) short Ahs[2][128][32];
  __shared__ __align__(16) short Bhs[2][128][32];
  const int tid = threadIdx.x;
  const int w = tid >> 6, l = tid & 63;
  const int wm = w >> 1, wn = w & 1;
  const int bid = blockIdx.x;
  const int chunk = (6 * 512) >> 3;
  const int lbid = (bid & 7) * chunk + (bid >> 3);
  const int nti = lbid % 6, mti = lbid / 6;
  const int m0 = mti * 128, n0 = nti * 128;
  const int lr = l >> 2;
  const int lc = (l & 3) * 8;
  const int fr = l & 15, kg = (l >> 4) * 8;
  f4 acc[4][4] = {};
#pragma unroll
  for (int i = 0; i < 2; ++i) {
    const int row = w * 32 + i * 16;
    gload16(A1 + (size_t)(m0 + row + lr) * 256 + lc, (void*)&Ahs[0][row][0]);
    gload16(B2 + (size_t)(n0 + row + lr) * 512 + lc, (void*)&Bhs[0][row][0]);
  }
  asm volatile("s_waitcnt vmcnt(0)" ::: "memory");
  __builtin_amdgcn_s_barrier();
  int cur = 0;
  for (int s = 0; s < 8; ++s) {
    if (s < 7) {
      const int sk = (s + 1) * 32;
#pragma unroll
      for (int i = 0; i < 2; ++i) {
        const int row = w * 32 + i * 16;
        gload16(A1 + (size_t)(m0 + row + lr) * 256 + sk + lc,
                (void*)&Ahs[cur ^ 1][row][0]);
        gload16(B2 + (size_t)(n0 + row + lr) * 512 + sk + lc,
                (void*)&Bhs[cur ^ 1][row][0]);
      }
    }
    if (s > 0) {
      if (s < 7) asm volatile("s_waitcnt vmcnt(4)" ::: "memory");
      else asm volatile("s_waitcnt vmcnt(0)" ::: "memory");
      __builtin_amdgcn_s_barrier();
    }
    sv8 fa[4], fb[4];
#pragma unroll
    for (int t = 0; t < 4; ++t) {
      fa[t] = *(const sv8*)&Ahs[cur][wm * 64 + t * 16 + fr][kg];
      fb[t] = *(const sv8*)&Bhs[cur][wn * 64 + t * 16 + fr][kg];
    }
#pragma unroll
    for (int mt = 0; mt < 4; ++mt)
#pragma unroll
      for (int nt = 0; nt < 4; ++nt)
        acc[mt][nt] = mfma16(fa[mt], fb[nt], acc[mt][nt]);
    asm volatile("s_waitcnt lgkmcnt(0)" ::: "memory");
    __builtin_amdgcn_s_barrier();
    cur ^= 1;
  }
  short* dst = (nti < 2) ? Qbf : ((nti < 4) ? Kbf : Vbf);
  const int r0 = (l >> 4) * 4;
#pragma unroll
  for (int mt = 0; mt < 4; ++mt)
#pragma unroll
    for (int nt = 0; nt < 4; ++nt) {
      const int n = n0 + wn * 64 + nt * 16 + fr;
      const float bv = bias[n];
      const int nn = n & 255;
      const size_t mb = (size_t)(m0 + wm * 64 + mt * 16 + r0);
#pragma unroll
      for (int j = 0; j < 4; ++j)
        dst[(mb + j) * 256 + nn] = f2bf(acc[mt][nt][j] + bv);
    }
}

// ---- proj GEMM: 1-term (C = Ah*Bh), A dense bf16 [M][256], fp32 out.
__global__ __launch_bounds__(256) void gemm_proj1(
    const short* __restrict__ A1, const short* __restrict__ B2,
    const float* __restrict__ bias, float* __restrict__ C) {
  __shared__ __align__(16) short Ahs[2][128][32];
  __shared__ __align__(16) short Bhs[2][128][32];
  const int tid = threadIdx.x;
  const int w = tid >> 6, l = tid & 63;
  const int wm = w >> 1, wn = w & 1;
  const int bid = blockIdx.x;
  const int chunk = (2 * 512) >> 3;
  const int lbid = (bid & 7) * chunk + (bid >> 3);
  const int nti = lbid % 2, mti = lbid / 2;
  const int m0 = mti * 128, n0 = nti * 128;
  const int lr = l >> 2;
  const int lc = (l & 3) * 8;
  const int fr = l & 15, kg = (l >> 4) * 8;
  f4 acc[4][4] = {};
#pragma unroll
  for (int i = 0; i < 2; ++i) {
    const int row = w * 32 + i * 16;
    gload16(A1 + (size_t)(m0 + row + lr) * 256 + lc, (void*)&Ahs[0][row][0]);
    gload16(B2 + (size_t)(n0 + row + lr) * 512 + lc, (void*)&Bhs[0][row][0]);
  }
  asm volatile("s_waitcnt vmcnt(0)" ::: "memory");
  __builtin_amdgcn_s_barrier();
  int cur = 0;
  for (int s = 0; s < 8; ++s) {
    if (s < 7) {
      const int sk = (s + 1) * 32;
#pragma unroll
      for (int i = 0; i < 2; ++i) {
        const int row = w * 32 + i * 16;
        gload16(A1 + (size_t)(m0 + row + lr) * 256 + sk + lc,
                (void*)&Ahs[cur ^ 1][row][0]);
        gload16(B2 + (size_t)(n0 + row + lr) * 512 + sk + lc,
                (void*)&Bhs[cur ^ 1][row][0]);
      }
    }
    if (s > 0) {
      if (s < 7) asm volatile("s_waitcnt vmcnt(4)" ::: "memory");
      else asm volatile("s_waitcnt vmcnt(0)" ::: "memory");
      __builtin_amdgcn_s_barrier();
    }
    sv8 fa[4], fb[4];
#pragma unroll
    for (int t = 0; t < 4; ++t) {
      fa[t] = *(const sv8*)&Ahs[cur][wm * 64 + t * 16 + fr][kg];
      fb[t] = *(const sv8*)&Bhs[cur][wn * 64 + t * 16 + fr][kg];
    }
#pragma unroll
    for (int mt = 0; mt < 4; ++mt)
#pragma unroll
      for (int nt = 0; nt < 4; ++nt)
        acc[mt][nt] = mfma16(fa[mt], fb[nt], acc[mt][nt]);
    asm volatile("s_waitcnt lgkmcnt(0)" ::: "memory");
    __builtin_amdgcn_s_barrier();
    cur ^= 1;
  }
  const int r0 = (l >> 4) * 4;
#pragma unroll
  for (int mt = 0; mt < 4; ++mt)
#pragma unroll
    for (int nt = 0; nt < 4; ++nt) {
      const int n = n0 + wn * 64 + nt * 16 + fr;
      const float bv = bias[n];
      const size_t mb = (size_t)(m0 + wm * 64 + mt * 16 + r0);
#pragma unroll
      for (int j = 0; j < 4; ++j) C[(mb + j) * 256 + n] = acc[mt][nt][j] + bv;
    }
}

// LDS pointer with per-row XOR swizzle (float index d at byte 4d ^ ((d>>5&7)<<4));
// bijective per 1 KiB row; kills the fixed-h 8-way read conflict.
__device__ __forceinline__ float* ldsP(float* base, int row, int d) {
  return (float*)((char*)base + row * 1024 + ((4 * d) ^ (((d >> 5) & 7) << 4)));
}

// One block per (b, nb). ONE barrier. Block-node (kc=16) folded analytically.
// Q global-load hoisted above the barrier (latency hides under K/V staging).
__global__ __launch_bounds__(256, 4) void attn_v6(
    const short* __restrict__ Qb, const short* __restrict__ Kb,
    const short* __restrict__ Vb, const int* __restrict__ amask,
    const float* __restrict__ efeat, const float* __restrict__ Wgate,
    const float* __restrict__ bgate, short* __restrict__ AO) {
  __shared__ float Ks[16 * 256];   // swizzled, 16 KiB
  __shared__ float Vs[16 * 256];   // swizzled, 16 KiB
  __shared__ float4 Es[LQ * KCNT]; // edge feats, 4.25 KiB
  __shared__ int Ms[LQ * KCNT];    // mask, 1.06 KiB

  const int tid = threadIdx.x, g = blockIdx.x;
  const int b = g >> 11, nb = g & (NB - 1);
  const size_t tok0 = (size_t)(b * N_SEQ + nb * LQ);

  const int q = tid >> 4, h = (tid >> 1) & 7, half = tid & 1;
  const int d0 = h * HD + half * 16;

  // Q load issued FIRST (no LDS dependence) so it completes during staging
  float qh[16];
  {
    const short* qp = Qb + (tok0 + q) * 256 + d0;
    sv8 q0 = *(const sv8*)qp;
    sv8 q1 = *(const sv8*)(qp + 8);
#pragma unroll
    for (int e = 0; e < 8; ++e) {
      qh[e] = bf2f(q0[e]);
      qh[8 + e] = bf2f(q1[e]);
    }
  }

  // stage 16 leaf K,V rows: bf16 global -> fp32 swizzled LDS
#pragma unroll
  for (int i = 0; i < 2; ++i) {
    const int f = tid + i * 256;  // 0..511
    const int t = f >> 5, c8 = (f & 31) * 8;
    sv8 kv = *(const sv8*)(Kb + (tok0 + t) * 256 + c8);
    sv8 vv = *(const sv8*)(Vb + (tok0 + t) * 256 + c8);
    float4 k0 = {bf2f(kv[0]), bf2f(kv[1]), bf2f(kv[2]), bf2f(kv[3])};
    float4 k1 = {bf2f(kv[4]), bf2f(kv[5]), bf2f(kv[6]), bf2f(kv[7])};
    float4 v0 = {bf2f(vv[0]), bf2f(vv[1]), bf2f(vv[2]), bf2f(vv[3])};
    float4 v1 = {bf2f(vv[4]), bf2f(vv[5]), bf2f(vv[6]), bf2f(vv[7])};
    *(float4*)ldsP(Ks, t, c8) = k0;
    *(float4*)ldsP(Ks, t, c8 + 4) = k1;
    *(float4*)ldsP(Vs, t, c8) = v0;
    *(float4*)ldsP(Vs, t, c8 + 4) = v1;
  }
  // stage efeat (272 float4) and mask (272 int), coalesced
  {
    const float4* esrc = (const float4*)(efeat + (size_t)nb * LQ * KCNT * 4);
    const int* msrc = amask + (size_t)nb * LQ * KCNT;
    Es[tid] = esrc[tid];
    Ms[tid] = msrc[tid];
    if (tid < LQ * KCNT - 256) {
      Es[256 + tid] = esrc[256 + tid];
      Ms[256 + tid] = msrc[256 + tid];
    }
  }
  __syncthreads();

  const float wg0 = Wgate[h * 4], wg1 = Wgate[h * 4 + 1];
  const float wg2 = Wgate[h * 4 + 2], wg3 = Wgate[h * 4 + 3];
  const float bg = bgate[h];

  float sc[16], gt[16];
  float rawsum = 0.f;
  unsigned vis = 0;
  float mx = -1e30f;
#pragma unroll
  for (int kc = 0; kc < 16; ++kc) {
    float dot = 0.f;
#pragma unroll
    for (int j = 0; j < 4; ++j) {
      float4 kv = *(const float4*)ldsP(Ks, kc, d0 + j * 4);
      dot += qh[j * 4] * kv.x + qh[j * 4 + 1] * kv.y +
             qh[j * 4 + 2] * kv.z + qh[j * 4 + 3] * kv.w;
    }
    dot += __shfl_xor(dot, 1);
    rawsum += dot;
    float e0, e1, e2, e3;
    if (kc == q) { e0 = e1 = e2 = 0.f; e3 = 1.f; }
    else { float4 e = Es[q * KCNT + kc]; e0 = e.x; e1 = e.y; e2 = e.z; e3 = e.w; }
    const int m = Ms[q * KCNT + kc];
    const float s = dot * SCALE_F + e3;
    sc[kc] = s;
    if (m) { vis |= (1u << kc); mx = fmaxf(mx, s); }
    gt[kc] = m ? (e0 * wg0 + e1 * wg1 + e2 * wg2 + e3 * wg3 + bg) : 0.f;
  }
  const float s16 = rawsum * 0.0625f * SCALE_F + 1.0f;
  const int m16 = Ms[q * KCNT + 16];
  const float gt16 = m16 ? (wg3 + bg) : 0.f;
  if (m16) mx = fmaxf(mx, s16);

  float den = 0.f;
#pragma unroll
  for (int kc = 0; kc < 16; ++kc) {
    const float pv = (vis & (1u << kc)) ? __expf(sc[kc] - mx) : 0.f;
    sc[kc] = pv;
    den += pv;
  }
  const float p16 = m16 ? __expf(s16 - mx) : 0.f;
  den += p16;
  const float inv = 1.f / den;
  const float cb16 = (p16 * inv + gt16) * 0.0625f;
#pragma unroll
  for (int kc = 0; kc < 16; ++kc) sc[kc] = sc[kc] * inv + gt[kc] + cb16;

  float o[16] = {};
#pragma unroll
  for (int kc = 0; kc < 16; ++kc) {
    const float c = sc[kc];
#pragma unroll
    for (int j = 0; j < 4; ++j) {
      float4 vv = *(const float4*)ldsP(Vs, kc, d0 + j * 4);
      o[j * 4] += c * vv.x;
      o[j * 4 + 1] += c * vv.y;
      o[j * 4 + 2] += c * vv.z;
      o[j * 4 + 3] += c * vv.w;
    }
  }
  short* ao = AO + (tok0 + q) * 256 + d0;
  sv8 hi;
#pragma unroll
  for (int e = 0; e < 8; ++e) hi[e] = f2bf(o[e]);
  *(sv8*)ao = hi;
#pragma unroll
  for (int e = 0; e < 8; ++e) hi[e] = f2bf(o[8 + e]);
  *(sv8*)&ao[8] = hi;
}

extern "C" void kernel_launch(void* const* d_in, const int* in_sizes, int n_in,
                              void* d_out, int out_size, void* d_ws, size_t ws_size,
                              hipStream_t stream) {
  const float* x = (const float*)d_in[0];
  const int* amask = (const int*)d_in[1];
  const float* efeat = (const float*)d_in[2];
  const float* Wqkv = (const float*)d_in[3];
  const float* bqkv = (const float*)d_in[4];
  const float* Wproj = (const float*)d_in[5];
  const float* bproj = (const float*)d_in[6];
  const float* Wgate = (const float*)d_in[7];
  const float* bgate = (const float*)d_in[8];
  float* out = (float*)d_out;

  char* ws = (char*)d_ws;
  const size_t QB_SZ = (size_t)M_ROWS * 256 * 2;  // 32 MiB each
  const size_t W2Q_SZ = (size_t)768 * 512 * 2;    // 768 KiB
  const size_t W2P_SZ = (size_t)256 * 512 * 2;    // 256 KiB
  // X1 + Q + K + V + AO = 5*32 MiB + ~1 MiB = ~161 MiB (ws >= 225 MiB known)
  if (ws_size < 5 * QB_SZ + W2Q_SZ + W2P_SZ) return;

  short* X1 = (short*)ws;
  short* Qbf = (short*)(ws + QB_SZ);
  short* Kbf = (short*)(ws + 2 * QB_SZ);
  short* Vbf = (short*)(ws + 3 * QB_SZ);
  short* AOh = (short*)(ws + 4 * QB_SZ);
  short* W2Q = (short*)(ws + 5 * QB_SZ);
  short* W2P = (short*)(ws + 5 * QB_SZ + W2Q_SZ);

  cast256<<<dim3(M_ROWS * 64 / 256), 256, 0, stream>>>(x, X1, M_ROWS * 64);
  split256<<<dim3(768 * 64 / 256), 256, 0, stream>>>(Wqkv, W2Q, 768 * 64);
  split256<<<dim3(256 * 64 / 256), 256, 0, stream>>>(Wproj, W2P, 256 * 64);
  gemm_bf_qkv<<<dim3(6 * 512), 256, 0, stream>>>(X1, W2Q, bqkv, Qbf, Kbf, Vbf);
  attn_v6<<<dim3(B_SZ * NB), 256, 0, stream>>>(Qbf, Kbf, Vbf, amask, efeat,
                                               Wgate, bgate, AOh);
  gemm_proj1<<<dim3(2 * 512), 256, 0, stream>>>(AOh, W2P, bproj, out);
}

// Round 15
// 131.843 us; speedup vs baseline: 2.3562x; 1.2449x over previous
//
#include <hip/hip_runtime.h>
#include <cstdint>
#include <cstddef>

#define B_SZ 2
#define N_SEQ 32768
#define NB 2048
#define HD 32
#define LQ 16
#define KCNT 17
#define M_ROWS 65536
#define SCALE_F 0.17677669529663687f /* 32^-0.5 */

typedef __attribute__((ext_vector_type(8))) short sv8;
typedef __attribute__((ext_vector_type(4))) short sv4;
typedef __attribute__((ext_vector_type(4))) float f4;

__device__ __forceinline__ short f2bf(float f) {
  unsigned u = __builtin_bit_cast(unsigned, f);
  u = (u + 0x7FFFu + ((u >> 16) & 1u)) >> 16;
  return (short)u;
}
__device__ __forceinline__ float bf2f(short s) {
  unsigned u = ((unsigned)(unsigned short)s) << 16;
  return __builtin_bit_cast(float, u);
}
__device__ __forceinline__ void gload16(const void* g, void* l) {
  __builtin_amdgcn_global_load_lds(
      (const __attribute__((address_space(1))) unsigned int*)g,
      (__attribute__((address_space(3))) unsigned int*)l, 16, 0, 0);
}
__device__ __forceinline__ f4 mfma16(sv8 a, sv8 b, f4 c) {
  return __builtin_amdgcn_mfma_f32_16x16x32_bf16(a, b, c, 0, 0, 0);
}

// fp32 [rows][256] -> bf16 hi|lo [rows][512]  (weights only)
__global__ __launch_bounds__(256) void split256(const float* __restrict__ src,
                                                short* __restrict__ dst, int n4) {
  int i = blockIdx.x * 256 + threadIdx.x;
  if (i >= n4) return;
  float4 v = ((const float4*)src)[i];
  size_t row = (size_t)(i >> 6);
  int c = (i & 63) * 4;
  float fv[4] = {v.x, v.y, v.z, v.w};
  sv4 hi, lo;
#pragma unroll
  for (int j = 0; j < 4; ++j) {
    short h = f2bf(fv[j]);
    hi[j] = h;
    lo[j] = f2bf(fv[j] - bf2f(h));
  }
  *(sv4*)&dst[row * 512 + c] = hi;
  *(sv4*)&dst[row * 512 + 256 + c] = lo;
}

// fp32 -> dense bf16 (for X)
__global__ __launch_bounds__(256) void cast256(const float* __restrict__ src,
                                               short* __restrict__ dst, int n4) {
  int i = blockIdx.x * 256 + threadIdx.x;
  if (i >= n4) return;
  float4 v = ((const float4*)src)[i];
  sv4 h = {f2bf(v.x), f2bf(v.y), f2bf(v.z), f2bf(v.w)};
  *(sv4*)&dst[(size_t)i * 4] = h;
}

// ---- QKV GEMM, 1-term bf16 (unchanged from round 14) ----
__global__ __launch_bounds__(256) void gemm_bf_qkv(
    const short* __restrict__ A1, const short* __restrict__ B2,
    const float* __restrict__ bias, short* __restrict__ Qbf,
    short* __restrict__ Kbf, short* __restrict__ Vbf) {
  __shared__ __align__(16) short Ahs[2][128][32];
  __shared__ __align__(16) short Bhs[2][128][32];
  const int tid = threadIdx.x;
  const int w = tid >> 6, l = tid & 63;
  const int wm = w >> 1, wn = w & 1;
  const int bid = blockIdx.x;
  const int chunk = (6 * 512) >> 3;
  const int lbid = (bid & 7) * chunk + (bid >> 3);
  const int nti = lbid % 6, mti = lbid / 6;
  const int m0 = mti * 128, n0 = nti * 128;
  const int lr = l >> 2;
  const int lc = (l & 3) * 8;
  const int fr = l & 15, kg = (l >> 4) * 8;
  f4 acc[4][4] = {};
#pragma unroll
  for (int i = 0; i < 2; ++i) {
    const int row = w * 32 + i * 16;
    gload16(A1 + (size_t)(m0 + row + lr) * 256 + lc, (void*)&Ahs[0][row][0]);
    gload16(B2 + (size_t)(n0 + row + lr) * 512 + lc, (void*)&Bhs[0][row][0]);
  }
  asm volatile("s_waitcnt vmcnt(0)" ::: "memory");
  __builtin_amdgcn_s_barrier();
  int cur = 0;
  for (int s = 0; s < 8; ++s) {
    if (s < 7) {
      const int sk = (s + 1) * 32;
#pragma unroll
      for (int i = 0; i < 2; ++i) {
        const int row = w * 32 + i * 16;
        gload16(A1 + (size_t)(m0 + row + lr) * 256 + sk + lc,
                (void*)&Ahs[cur ^ 1][row][0]);
        gload16(B2 + (size_t)(n0 + row + lr) * 512 + sk + lc,
                (void*)&Bhs[cur ^ 1][row][0]);
      }
    }
    if (s > 0) {
      if (s < 7) asm volatile("s_waitcnt vmcnt(4)" ::: "memory");
      else asm volatile("s_waitcnt vmcnt(0)" ::: "memory");
      __builtin_amdgcn_s_barrier();
    }
    sv8 fa[4], fb[4];
#pragma unroll
    for (int t = 0; t < 4; ++t) {
      fa[t] = *(const sv8*)&Ahs[cur][wm * 64 + t * 16 + fr][kg];
      fb[t] = *(const sv8*)&Bhs[cur][wn * 64 + t * 16 + fr][kg];
    }
#pragma unroll
    for (int mt = 0; mt < 4; ++mt)
#pragma unroll
      for (int nt = 0; nt < 4; ++nt)
        acc[mt][nt] = mfma16(fa[mt], fb[nt], acc[mt][nt]);
    asm volatile("s_waitcnt lgkmcnt(0)" ::: "memory");
    __builtin_amdgcn_s_barrier();
    cur ^= 1;
  }
  short* dst = (nti < 2) ? Qbf : ((nti < 4) ? Kbf : Vbf);
  const int r0 = (l >> 4) * 4;
#pragma unroll
  for (int mt = 0; mt < 4; ++mt)
#pragma unroll
    for (int nt = 0; nt < 4; ++nt) {
      const int n = n0 + wn * 64 + nt * 16 + fr;
      const float bv = bias[n];
      const int nn = n & 255;
      const size_t mb = (size_t)(m0 + wm * 64 + mt * 16 + r0);
#pragma unroll
      for (int j = 0; j < 4; ++j)
        dst[(mb + j) * 256 + nn] = f2bf(acc[mt][nt][j] + bv);
    }
}

// ---- proj GEMM (unchanged from round 14) ----
__global__ __launch_bounds__(256) void gemm_proj1(
    const short* __restrict__ A1, const short* __restrict__ B2,
    const float* __restrict__ bias, float* __restrict__ C) {
  __shared__ __align__(16) short Ahs[2][128][32];
  __shared__ __align__(16) short Bhs[2][128][32];
  const int tid = threadIdx.x;
  const int w = tid >> 6, l = tid & 63;
  const int wm = w >> 1, wn = w & 1;
  const int bid = blockIdx.x;
  const int chunk = (2 * 512) >> 3;
  const int lbid = (bid & 7) * chunk + (bid >> 3);
  const int nti = lbid % 2, mti = lbid / 2;
  const int m0 = mti * 128, n0 = nti * 128;
  const int lr = l >> 2;
  const int lc = (l & 3) * 8;
  const int fr = l & 15, kg = (l >> 4) * 8;
  f4 acc[4][4] = {};
#pragma unroll
  for (int i = 0; i < 2; ++i) {
    const int row = w * 32 + i * 16;
    gload16(A1 + (size_t)(m0 + row + lr) * 256 + lc, (void*)&Ahs[0][row][0]);
    gload16(B2 + (size_t)(n0 + row + lr) * 512 + lc, (void*)&Bhs[0][row][0]);
  }
  asm volatile("s_waitcnt vmcnt(0)" ::: "memory");
  __builtin_amdgcn_s_barrier();
  int cur = 0;
  for (int s = 0; s < 8; ++s) {
    if (s < 7) {
      const int sk = (s + 1) * 32;
#pragma unroll
      for (int i = 0; i < 2; ++i) {
        const int row = w * 32 + i * 16;
        gload16(A1 + (size_t)(m0 + row + lr) * 256 + sk + lc,
                (void*)&Ahs[cur ^ 1][row][0]);
        gload16(B2 + (size_t)(n0 + row + lr) * 512 + sk + lc,
                (void*)&Bhs[cur ^ 1][row][0]);
      }
    }
    if (s > 0) {
      if (s < 7) asm volatile("s_waitcnt vmcnt(4)" ::: "memory");
      else asm volatile("s_waitcnt vmcnt(0)" ::: "memory");
      __builtin_amdgcn_s_barrier();
    }
    sv8 fa[4], fb[4];
#pragma unroll
    for (int t = 0; t < 4; ++t) {
      fa[t] = *(const sv8*)&Ahs[cur][wm * 64 + t * 16 + fr][kg];
      fb[t] = *(const sv8*)&Bhs[cur][wn * 64 + t * 16 + fr][kg];
    }
#pragma unroll
    for (int mt = 0; mt < 4; ++mt)
#pragma unroll
      for (int nt = 0; nt < 4; ++nt)
        acc[mt][nt] = mfma16(fa[mt], fb[nt], acc[mt][nt]);
    asm volatile("s_waitcnt lgkmcnt(0)" ::: "memory");
    __builtin_amdgcn_s_barrier();
    cur ^= 1;
  }
  const int r0 = (l >> 4) * 4;
#pragma unroll
  for (int mt = 0; mt < 4; ++mt)
#pragma unroll
    for (int nt = 0; nt < 4; ++nt) {
      const int n = n0 + wn * 64 + nt * 16 + fr;
      const float bv = bias[n];
      const size_t mb = (size_t)(m0 + wm * 64 + mt * 16 + r0);
#pragma unroll
      for (int j = 0; j < 4; ++j) C[(mb + j) * 256 + n] = acc[mt][nt][j] + bv;
    }
}

// ---- attn_v7: MFMA attention. One block per (b,nb), 4 waves x 2 heads.
// Scores (swapped): S^T[kc][q] = mfma(A=K-rows, B=Q-rows)  [1 MFMA/head]
//   D-layout: lane holds q = l&15, kc_j = (l>>4)*4+j  (j=0..3).
// Softmax in-register: row reductions via shfl_xor(16/32); block-node kc=16
//   folded analytically (s16 = rowsum/16*SCALE+1; cb16 added to leaf coefs).
// P -> PV A-frag via 8 __shfl (src = ((kc>>2)<<4)|q, elem = kc&3).
// PV: D2[q][d] = mfma(A=P, B=V-cols), K-dim 16->32 zero-padded (V rows 16..31
//   zeroed in LDS: 0 x garbage = NaN hazard). 2 MFMA/head.
// O staged to LDS then coalesced sv8 write-out.
__global__ __launch_bounds__(256, 4) void attn_v7(
    const short* __restrict__ Qb, const short* __restrict__ Kb,
    const short* __restrict__ Vb, const int* __restrict__ amask,
    const float* __restrict__ efeat, const float* __restrict__ Wgate,
    const float* __restrict__ bgate, short* __restrict__ AO) {
  __shared__ __align__(16) short Kl[16 * 264];  // 8.25 KiB, 264-short rows
  __shared__ __align__(16) short Vl[32 * 264];  // 16.5 KiB (rows 16..31 zero)
  __shared__ __align__(16) short Ol[16 * 264];  // 8.25 KiB
  __shared__ float4 Es[LQ * KCNT];              // 4.25 KiB
  __shared__ int Ms[LQ * KCNT];                 // 1.06 KiB

  const int tid = threadIdx.x, g = blockIdx.x;
  const int b = g >> 11, nb = g & (NB - 1);
  const size_t tok0 = (size_t)(b * N_SEQ + nb * LQ);
  const int w = tid >> 6, l = tid & 63;
  const int ln = l & 15, lg = l >> 4;
  const f4 fzero = {0.f, 0.f, 0.f, 0.f};

  // Q fragments for this wave's two heads (global, hoisted above barrier):
  // B-frag: lane supplies Q[q=ln][d = h*32 + lg*8 + e]
  sv8 qf[2];
#pragma unroll
  for (int hh = 0; hh < 2; ++hh) {
    const int h = w * 2 + hh;
    qf[hh] = *(const sv8*)(Qb + (tok0 + ln) * 256 + h * 32 + lg * 8);
  }

  // stage K, V rows (bf16 row-major, stride 264 shorts)
#pragma unroll
  for (int i = 0; i < 2; ++i) {
    const int f = tid + i * 256;
    const int t = f >> 5, c8 = (f & 31) * 8;
    *(sv8*)&Kl[t * 264 + c8] = *(const sv8*)(Kb + (tok0 + t) * 256 + c8);
    *(sv8*)&Vl[t * 264 + c8] = *(const sv8*)(Vb + (tok0 + t) * 256 + c8);
  }
  {  // zero V pad rows 16..31 (528 sv8 units)
    const sv8 z = {};
    for (int z8 = tid; z8 < 528; z8 += 256) *(sv8*)&Vl[4224 + z8 * 8] = z;
  }
  {  // stage efeat (272 float4) and mask (272 int), coalesced
    const float4* esrc = (const float4*)(efeat + (size_t)nb * LQ * KCNT * 4);
    const int* msrc = amask + (size_t)nb * LQ * KCNT;
    Es[tid] = esrc[tid];
    Ms[tid] = msrc[tid];
    if (tid < LQ * KCNT - 256) {
      Es[256 + tid] = esrc[256 + tid];
      Ms[256 + tid] = msrc[256 + tid];
    }
  }
  __syncthreads();

  const int q = ln;
#pragma unroll
  for (int hh = 0; hh < 2; ++hh) {
    const int h = w * 2 + hh;
    // scores: A-frag = K rows (m=kc=ln, k-slice lg*8 within the 32-d head)
    sv8 ka = *(const sv8*)&Kl[ln * 264 + h * 32 + lg * 8];
    f4 sr = mfma16(ka, qf[hh], fzero);  // lane: S[kc=lg*4+j][q=ln]

    const float wg0 = Wgate[h * 4], wg1 = Wgate[h * 4 + 1];
    const float wg2 = Wgate[h * 4 + 2], wg3 = Wgate[h * 4 + 3];
    const float bg = bgate[h];

    float rs = sr[0] + sr[1] + sr[2] + sr[3];
    rs += __shfl_xor(rs, 16);
    rs += __shfl_xor(rs, 32);  // full rowsum over kc per q

    float s_[4], gt_[4];
    int vis_[4];
#pragma unroll
    for (int j = 0; j < 4; ++j) {
      const int kc = lg * 4 + j;
      float e0, e1, e2, e3;
      if (kc == q) { e0 = e1 = e2 = 0.f; e3 = 1.f; }
      else { float4 e = Es[q * KCNT + kc]; e0 = e.x; e1 = e.y; e2 = e.z; e3 = e.w; }
      const int m = Ms[q * KCNT + kc];
      vis_[j] = m;
      s_[j] = sr[j] * SCALE_F + e3;
      gt_[j] = m ? (e0 * wg0 + e1 * wg1 + e2 * wg2 + e3 * wg3 + bg) : 0.f;
    }
    const int m16 = Ms[q * KCNT + 16];
    const float s16 = rs * 0.0625f * SCALE_F + 1.0f;

    float mx = -1e30f;
#pragma unroll
    for (int j = 0; j < 4; ++j)
      if (vis_[j]) mx = fmaxf(mx, s_[j]);
    mx = fmaxf(mx, __shfl_xor(mx, 16));
    mx = fmaxf(mx, __shfl_xor(mx, 32));
    if (m16) mx = fmaxf(mx, s16);

    float p_[4], den = 0.f;
#pragma unroll
    for (int j = 0; j < 4; ++j) {
      p_[j] = vis_[j] ? __expf(s_[j] - mx) : 0.f;
      den += p_[j];
    }
    den += __shfl_xor(den, 16);
    den += __shfl_xor(den, 32);
    const float p16 = m16 ? __expf(s16 - mx) : 0.f;
    den += p16;
    const float inv = 1.f / den;
    const float gt16 = m16 ? (wg3 + bg) : 0.f;
    const float cb16 = (p16 * inv + gt16) * 0.0625f;
    float pc[4];
#pragma unroll
    for (int j = 0; j < 4; ++j) pc[j] = p_[j] * inv + gt_[j] + cb16;

    // redistribute P into PV A-frag: lane wants P[q=ln][kc=lg*8+e]
    sv8 pa;
#pragma unroll
    for (int e = 0; e < 8; ++e) {
      const int kc = lg * 8 + e;
      const int src = ((kc >> 2) << 4) | q;     // source lane of P[kc][q]
      const float v0 = __shfl(pc[e & 3], src);  // e&3 == kc&3 (compile-time)
      pa[e] = (kc < 16) ? f2bf(v0) : (short)0;  // zero A-pads kc>=16
    }

    // PV: B-frag = V columns (n=d=h*32+t*16+ln, k=kc=lg*8+e); rows>=16 zeroed
#pragma unroll
    for (int t = 0; t < 2; ++t) {
      sv8 vb;
#pragma unroll
      for (int e = 0; e < 8; ++e)
        vb[e] = Vl[(lg * 8 + e) * 264 + h * 32 + t * 16 + ln];
      f4 oacc = mfma16(pa, vb, fzero);  // lane: O[q=lg*4+j][d=..+ln]
#pragma unroll
      for (int j = 0; j < 4; ++j)
        Ol[(lg * 4 + j) * 264 + h * 32 + t * 16 + ln] = f2bf(oacc[j]);
    }
  }
  __syncthreads();

  // coalesced write-out
#pragma unroll
  for (int i = 0; i < 2; ++i) {
    const int f = tid + i * 256;
    const int t = f >> 5, c8 = (f & 31) * 8;
    *(sv8*)(AO + (tok0 + t) * 256 + c8) = *(const sv8*)&Ol[t * 264 + c8];
  }
}

extern "C" void kernel_launch(void* const* d_in, const int* in_sizes, int n_in,
                              void* d_out, int out_size, void* d_ws, size_t ws_size,
                              hipStream_t stream) {
  const float* x = (const float*)d_in[0];
  const int* amask = (const int*)d_in[1];
  const float* efeat = (const float*)d_in[2];
  const float* Wqkv = (const float*)d_in[3];
  const float* bqkv = (const float*)d_in[4];
  const float* Wproj = (const float*)d_in[5];
  const float* bproj = (const float*)d_in[6];
  const float* Wgate = (const float*)d_in[7];
  const float* bgate = (const float*)d_in[8];
  float* out = (float*)d_out;

  char* ws = (char*)d_ws;
  const size_t QB_SZ = (size_t)M_ROWS * 256 * 2;  // 32 MiB each
  const size_t W2Q_SZ = (size_t)768 * 512 * 2;    // 768 KiB
  const size_t W2P_SZ = (size_t)256 * 512 * 2;    // 256 KiB
  if (ws_size < 5 * QB_SZ + W2Q_SZ + W2P_SZ) return;

  short* X1 = (short*)ws;
  short* Qbf = (short*)(ws + QB_SZ);
  short* Kbf = (short*)(ws + 2 * QB_SZ);
  short* Vbf = (short*)(ws + 3 * QB_SZ);
  short* AOh = (short*)(ws + 4 * QB_SZ);
  short* W2Q = (short*)(ws + 5 * QB_SZ);
  short* W2P = (short*)(ws + 5 * QB_SZ + W2Q_SZ);

  cast256<<<dim3(M_ROWS * 64 / 256), 256, 0, stream>>>(x, X1, M_ROWS * 64);
  split256<<<dim3(768 * 64 / 256), 256, 0, stream>>>(Wqkv, W2Q, 768 * 64);
  split256<<<dim3(256 * 64 / 256), 256, 0, stream>>>(Wproj, W2P, 256 * 64);
  gemm_bf_qkv<<<dim3(6 * 512), 256, 0, stream>>>(X1, W2Q, bqkv, Qbf, Kbf, Vbf);
  attn_v7<<<dim3(B_SZ * NB), 256, 0, stream>>>(Qbf, Kbf, Vbf, amask, efeat,
                                               Wgate, bgate, AOh);
  gemm_proj1<<<dim3(2 * 512), 256, 0, stream>>>(AOh, W2P, bproj, out);
}

// Round 16
// 125.404 us; speedup vs baseline: 2.4772x; 1.0513x over previous
//
#include <hip/hip_runtime.h>
#include <cstdint>
#include <cstddef>

#define B_SZ 2
#define N_SEQ 32768
#define NB 2048
#define HD 32
#define LQ 16
#define KCNT 17
#define M_ROWS 65536
#define SCALE_F 0.17677669529663687f /* 32^-0.5 */

typedef __attribute__((ext_vector_type(8))) short sv8;
typedef __attribute__((ext_vector_type(4))) short sv4;
typedef __attribute__((ext_vector_type(4))) float f4;

__device__ __forceinline__ short f2bf(float f) {
  unsigned u = __builtin_bit_cast(unsigned, f);
  u = (u + 0x7FFFu + ((u >> 16) & 1u)) >> 16;
  return (short)u;
}
__device__ __forceinline__ float bf2f(short s) {
  unsigned u = ((unsigned)(unsigned short)s) << 16;
  return __builtin_bit_cast(float, u);
}
__device__ __forceinline__ void gload16(const void* g, void* l) {
  __builtin_amdgcn_global_load_lds(
      (const __attribute__((address_space(1))) unsigned int*)g,
      (__attribute__((address_space(3))) unsigned int*)l, 16, 0, 0);
}
__device__ __forceinline__ f4 mfma16(sv8 a, sv8 b, f4 c) {
  return __builtin_amdgcn_mfma_f32_16x16x32_bf16(a, b, c, 0, 0, 0);
}

// fused prep: cast X (4194304 f4), Wqkv (49152 f4), Wproj (16384 f4) to bf16
__global__ __launch_bounds__(256) void cast_all(
    const float* __restrict__ x, const float* __restrict__ wq,
    const float* __restrict__ wp, short* __restrict__ X1,
    short* __restrict__ W1, short* __restrict__ WP1) {
  const int i = blockIdx.x * 256 + threadIdx.x;
  const float* src;
  short* dst;
  int off;
  if (i < 4194304) { src = x; dst = X1; off = i; }
  else if (i < 4194304 + 49152) { src = wq; dst = W1; off = i - 4194304; }
  else if (i < 4194304 + 49152 + 16384) { src = wp; dst = WP1; off = i - 4194304 - 49152; }
  else return;
  float4 v = ((const float4*)src)[off];
  sv4 h = {f2bf(v.x), f2bf(v.y), f2bf(v.z), f2bf(v.w)};
  *(sv4*)&dst[(size_t)off * 4] = h;
}

// ---- bf16 GEMM core: 128x128 tile, K=256 in 8 chunks of 32; 3-buffer
// 2-deep prefetch; ONE barrier per chunk. Hazards:
//  RAW: vmcnt(4) waits chunk s's 4 loads (s+1's stay in flight); barrier
//       makes it block-wide.
//  WAR: lgkmcnt(0) before the barrier completes each wave's ds_reads of
//       buf[(s-1)%3]; the issue into that buffer (chunk s+2) follows the
//       barrier in program order of every wave.
// Bijective XCD-chunked swizzle (A-panel FETCH verified 304->20 MB).
#define GEMM3_CORE(NT)                                                         \
  __shared__ __align__(16) short Ahs[3][128][32];                              \
  __shared__ __align__(16) short Bhs[3][128][32];                              \
  const int tid = threadIdx.x;                                                 \
  const int w = tid >> 6, l = tid & 63;                                        \
  const int wm = w >> 1, wn = w & 1;                                           \
  const int bid = blockIdx.x;                                                  \
  const int chunk = (NT * 512) >> 3;                                           \
  const int lbid = (bid & 7) * chunk + (bid >> 3);                             \
  const int nti = lbid % (NT), mti = lbid / (NT);                              \
  const int m0 = mti * 128, n0 = nti * 128;                                    \
  const int lr = l >> 2, lc = (l & 3) * 8;                                     \
  const int fr = l & 15, kg = (l >> 4) * 8;                                    \
  f4 acc[4][4] = {};                                                           \
  _Pragma("unroll") for (int p = 0; p < 2; ++p) {                              \
    _Pragma("unroll") for (int i = 0; i < 2; ++i) {                            \
      const int row = w * 32 + i * 16;                                         \
      gload16(A1 + (size_t)(m0 + row + lr) * 256 + p * 32 + lc,                \
              (void*)&Ahs[p][row][0]);                                         \
      gload16(B1 + (size_t)(n0 + row + lr) * 256 + p * 32 + lc,                \
              (void*)&Bhs[p][row][0]);                                         \
    }                                                                          \
  }                                                                            \
  for (int s = 0; s < 8; ++s) {                                                \
    if (s < 7) asm volatile("s_waitcnt vmcnt(4) lgkmcnt(0)" ::: "memory");     \
    else asm volatile("s_waitcnt vmcnt(0) lgkmcnt(0)" ::: "memory");           \
    __builtin_amdgcn_s_barrier();                                              \
    if (s + 2 < 8) {                                                           \
      const int sk = (s + 2) * 32;                                             \
      const int bsel = (s + 2) % 3;                                            \
      _Pragma("unroll") for (int i = 0; i < 2; ++i) {                          \
        const int row = w * 32 + i * 16;                                       \
        gload16(A1 + (size_t)(m0 + row + lr) * 256 + sk + lc,                  \
                (void*)&Ahs[bsel][row][0]);                                    \
        gload16(B1 + (size_t)(n0 + row + lr) * 256 + sk + lc,                  \
                (void*)&Bhs[bsel][row][0]);                                    \
      }                                                                        \
    }                                                                          \
    const int cb = s % 3;                                                      \
    sv8 fa[4], fb[4];                                                          \
    _Pragma("unroll") for (int t = 0; t < 4; ++t) {                            \
      fa[t] = *(const sv8*)&Ahs[cb][wm * 64 + t * 16 + fr][kg];                \
      fb[t] = *(const sv8*)&Bhs[cb][wn * 64 + t * 16 + fr][kg];                \
    }                                                                          \
    _Pragma("unroll") for (int mt = 0; mt < 4; ++mt)                           \
      _Pragma("unroll") for (int nt2 = 0; nt2 < 4; ++nt2)                      \
        acc[mt][nt2] = mfma16(fa[mt], fb[nt2], acc[mt][nt2]);                  \
  }

// QKV: A = X1 bf16 [M][256], B = W1 bf16 [768][256]; outputs routed bf16.
__global__ __launch_bounds__(256) void gemm_bf_qkv(
    const short* __restrict__ A1, const short* __restrict__ B1,
    const float* __restrict__ bias, short* __restrict__ Qbf,
    short* __restrict__ Kbf, short* __restrict__ Vbf) {
  GEMM3_CORE(6)
  short* dst = (nti < 2) ? Qbf : ((nti < 4) ? Kbf : Vbf);
  const int r0 = (l >> 4) * 4;
#pragma unroll
  for (int mt = 0; mt < 4; ++mt)
#pragma unroll
    for (int nt2 = 0; nt2 < 4; ++nt2) {
      const int n = n0 + wn * 64 + nt2 * 16 + fr;
      const float bv = bias[n];
      const int nn = n & 255;
      const size_t mb = (size_t)(m0 + wm * 64 + mt * 16 + r0);
#pragma unroll
      for (int j = 0; j < 4; ++j)
        dst[(mb + j) * 256 + nn] = f2bf(acc[mt][nt2][j] + bv);
    }
}

// proj: A = attn-out bf16 [M][256], B = WP1 bf16 [256][256]; fp32 out.
__global__ __launch_bounds__(256) void gemm_proj1(
    const short* __restrict__ A1, const short* __restrict__ B1,
    const float* __restrict__ bias, float* __restrict__ C) {
  GEMM3_CORE(2)
  const int r0 = (l >> 4) * 4;
#pragma unroll
  for (int mt = 0; mt < 4; ++mt)
#pragma unroll
    for (int nt2 = 0; nt2 < 4; ++nt2) {
      const int n = n0 + wn * 64 + nt2 * 16 + fr;
      const float bv = bias[n];
      const size_t mb = (size_t)(m0 + wm * 64 + mt * 16 + r0);
#pragma unroll
      for (int j = 0; j < 4; ++j) C[(mb + j) * 256 + n] = acc[mt][nt2][j] + bv;
    }
}

// ---- attn_v7: MFMA attention (unchanged from round 15) ----
__global__ __launch_bounds__(256, 4) void attn_v7(
    const short* __restrict__ Qb, const short* __restrict__ Kb,
    const short* __restrict__ Vb, const int* __restrict__ amask,
    const float* __restrict__ efeat, const float* __restrict__ Wgate,
    const float* __restrict__ bgate, short* __restrict__ AO) {
  __shared__ __align__(16) short Kl[16 * 264];
  __shared__ __align__(16) short Vl[32 * 264];
  __shared__ __align__(16) short Ol[16 * 264];
  __shared__ float4 Es[LQ * KCNT];
  __shared__ int Ms[LQ * KCNT];

  const int tid = threadIdx.x, g = blockIdx.x;
  const int b = g >> 11, nb = g & (NB - 1);
  const size_t tok0 = (size_t)(b * N_SEQ + nb * LQ);
  const int w = tid >> 6, l = tid & 63;
  const int ln = l & 15, lg = l >> 4;
  const f4 fzero = {0.f, 0.f, 0.f, 0.f};

  sv8 qf[2];
#pragma unroll
  for (int hh = 0; hh < 2; ++hh) {
    const int h = w * 2 + hh;
    qf[hh] = *(const sv8*)(Qb + (tok0 + ln) * 256 + h * 32 + lg * 8);
  }

#pragma unroll
  for (int i = 0; i < 2; ++i) {
    const int f = tid + i * 256;
    const int t = f >> 5, c8 = (f & 31) * 8;
    *(sv8*)&Kl[t * 264 + c8] = *(const sv8*)(Kb + (tok0 + t) * 256 + c8);
    *(sv8*)&Vl[t * 264 + c8] = *(const sv8*)(Vb + (tok0 + t) * 256 + c8);
  }
  {
    const sv8 z = {};
    for (int z8 = tid; z8 < 528; z8 += 256) *(sv8*)&Vl[4224 + z8 * 8] = z;
  }
  {
    const float4* esrc = (const float4*)(efeat + (size_t)nb * LQ * KCNT * 4);
    const int* msrc = amask + (size_t)nb * LQ * KCNT;
    Es[tid] = esrc[tid];
    Ms[tid] = msrc[tid];
    if (tid < LQ * KCNT - 256) {
      Es[256 + tid] = esrc[256 + tid];
      Ms[256 + tid] = msrc[256 + tid];
    }
  }
  __syncthreads();

  const int q = ln;
#pragma unroll
  for (int hh = 0; hh < 2; ++hh) {
    const int h = w * 2 + hh;
    sv8 ka = *(const sv8*)&Kl[ln * 264 + h * 32 + lg * 8];
    f4 sr = mfma16(ka, qf[hh], fzero);

    const float wg0 = Wgate[h * 4], wg1 = Wgate[h * 4 + 1];
    const float wg2 = Wgate[h * 4 + 2], wg3 = Wgate[h * 4 + 3];
    const float bg = bgate[h];

    float rs = sr[0] + sr[1] + sr[2] + sr[3];
    rs += __shfl_xor(rs, 16);
    rs += __shfl_xor(rs, 32);

    float s_[4], gt_[4];
    int vis_[4];
#pragma unroll
    for (int j = 0; j < 4; ++j) {
      const int kc = lg * 4 + j;
      float e0, e1, e2, e3;
      if (kc == q) { e0 = e1 = e2 = 0.f; e3 = 1.f; }
      else { float4 e = Es[q * KCNT + kc]; e0 = e.x; e1 = e.y; e2 = e.z; e3 = e.w; }
      const int m = Ms[q * KCNT + kc];
      vis_[j] = m;
      s_[j] = sr[j] * SCALE_F + e3;
      gt_[j] = m ? (e0 * wg0 + e1 * wg1 + e2 * wg2 + e3 * wg3 + bg) : 0.f;
    }
    const int m16 = Ms[q * KCNT + 16];
    const float s16 = rs * 0.0625f * SCALE_F + 1.0f;

    float mx = -1e30f;
#pragma unroll
    for (int j = 0; j < 4; ++j)
      if (vis_[j]) mx = fmaxf(mx, s_[j]);
    mx = fmaxf(mx, __shfl_xor(mx, 16));
    mx = fmaxf(mx, __shfl_xor(mx, 32));
    if (m16) mx = fmaxf(mx, s16);

    float p_[4], den = 0.f;
#pragma unroll
    for (int j = 0; j < 4; ++j) {
      p_[j] = vis_[j] ? __expf(s_[j] - mx) : 0.f;
      den += p_[j];
    }
    den += __shfl_xor(den, 16);
    den += __shfl_xor(den, 32);
    const float p16 = m16 ? __expf(s16 - mx) : 0.f;
    den += p16;
    const float inv = 1.f / den;
    const float gt16 = m16 ? (wg3 + bg) : 0.f;
    const float cb16 = (p16 * inv + gt16) * 0.0625f;
    float pc[4];
#pragma unroll
    for (int j = 0; j < 4; ++j) pc[j] = p_[j] * inv + gt_[j] + cb16;

    sv8 pa;
#pragma unroll
    for (int e = 0; e < 8; ++e) {
      const int kc = lg * 8 + e;
      const int src = ((kc >> 2) << 4) | q;
      const float v0 = __shfl(pc[e & 3], src);
      pa[e] = (kc < 16) ? f2bf(v0) : (short)0;
    }

#pragma unroll
    for (int t = 0; t < 2; ++t) {
      sv8 vb;
#pragma unroll
      for (int e = 0; e < 8; ++e)
        vb[e] = Vl[(lg * 8 + e) * 264 + h * 32 + t * 16 + ln];
      f4 oacc = mfma16(pa, vb, fzero);
#pragma unroll
      for (int j = 0; j < 4; ++j)
        Ol[(lg * 4 + j) * 264 + h * 32 + t * 16 + ln] = f2bf(oacc[j]);
    }
  }
  __syncthreads();

#pragma unroll
  for (int i = 0; i < 2; ++i) {
    const int f = tid + i * 256;
    const int t = f >> 5, c8 = (f & 31) * 8;
    *(sv8*)(AO + (tok0 + t) * 256 + c8) = *(const sv8*)&Ol[t * 264 + c8];
  }
}

extern "C" void kernel_launch(void* const* d_in, const int* in_sizes, int n_in,
                              void* d_out, int out_size, void* d_ws, size_t ws_size,
                              hipStream_t stream) {
  const float* x = (const float*)d_in[0];
  const int* amask = (const int*)d_in[1];
  const float* efeat = (const float*)d_in[2];
  const float* Wqkv = (const float*)d_in[3];
  const float* bqkv = (const float*)d_in[4];
  const float* Wproj = (const float*)d_in[5];
  const float* bproj = (const float*)d_in[6];
  const float* Wgate = (const float*)d_in[7];
  const float* bgate = (const float*)d_in[8];
  float* out = (float*)d_out;

  char* ws = (char*)d_ws;
  const size_t QB_SZ = (size_t)M_ROWS * 256 * 2;  // 32 MiB each
  const size_t W1_SZ = (size_t)768 * 256 * 2;     // 384 KiB
  const size_t WP1_SZ = (size_t)256 * 256 * 2;    // 128 KiB
  if (ws_size < 5 * QB_SZ + W1_SZ + WP1_SZ) return;

  short* X1 = (short*)ws;
  short* Qbf = (short*)(ws + QB_SZ);
  short* Kbf = (short*)(ws + 2 * QB_SZ);
  short* Vbf = (short*)(ws + 3 * QB_SZ);
  short* AOh = (short*)(ws + 4 * QB_SZ);
  short* W1 = (short*)(ws + 5 * QB_SZ);
  short* WP1 = (short*)(ws + 5 * QB_SZ + W1_SZ);

  const int total_f4 = 4194304 + 49152 + 16384;
  cast_all<<<dim3((total_f4 + 255) / 256), 256, 0, stream>>>(x, Wqkv, Wproj,
                                                             X1, W1, WP1);
  gemm_bf_qkv<<<dim3(6 * 512), 256, 0, stream>>>(X1, W1, bqkv, Qbf, Kbf, Vbf);
  attn_v7<<<dim3(B_SZ * NB), 256, 0, stream>>>(Qbf, Kbf, Vbf, amask, efeat,
                                               Wgate, bgate, AOh);
  gemm_proj1<<<dim3(2 * 512), 256, 0, stream>>>(AOh, WP1, bproj, out);
}